// Round 2
// baseline (8519.078 us; speedup 1.0000x reference)
//
#include <hip/hip_runtime.h>

// GraphGCN forward, fp32 baseline.
// N=50000 nodes, E=1600000 edges, IN=H=128, EA=16, OUT=10.
//
// ws layout (floats): ew[E] | dis[N] | A[N*128] | B[N*128] | S[128]
// total ~58 MB.

#define HD   128
#define EAD  16
#define OUTD 10

static inline int ceil_div(long long a, long long b){ return (int)((a + b - 1) / b); }

// ---------------- edge MLP: ew[e] = softplus(relu(ea@We1+be1)@We2+be2) -------------
__global__ __launch_bounds__(256) void k_edge_mlp(
    const float* __restrict__ edge_attr,
    const float* __restrict__ We1, const float* __restrict__ be1,
    const float* __restrict__ We2, const float* __restrict__ be2,
    float* __restrict__ ew, int E)
{
    int e = blockIdx.x * 256 + threadIdx.x;
    if (e >= E) return;
    float ea[EAD];
    const float4* p = reinterpret_cast<const float4*>(edge_attr + (size_t)e * EAD);
#pragma unroll
    for (int i = 0; i < 4; ++i) {
        float4 v = p[i];
        ea[4*i+0] = v.x; ea[4*i+1] = v.y; ea[4*i+2] = v.z; ea[4*i+3] = v.w;
    }
    float acc = be2[0];
    // process hidden dim in chunks of 32 to bound VGPR use; all weight
    // indices are wave-uniform -> scalar (s_load) traffic.
    for (int cb = 0; cb < HD; cb += 32) {
        float h[32];
#pragma unroll
        for (int j = 0; j < 32; ++j) h[j] = be1[cb + j];
#pragma unroll
        for (int k = 0; k < EAD; ++k) {
            float a = ea[k];
#pragma unroll
            for (int j = 0; j < 32; ++j)
                h[j] = fmaf(a, We1[k * HD + cb + j], h[j]);
        }
#pragma unroll
        for (int j = 0; j < 32; ++j)
            acc = fmaf(fmaxf(h[j], 0.0f), We2[cb + j], acc);
    }
    // numerically stable softplus
    float sp = fmaxf(acc, 0.0f) + log1pf(expf(-fabsf(acc)));
    ew[e] = sp;
}

// ---------------- degree / normalization ----------------
__global__ __launch_bounds__(256) void k_init_deg(float* __restrict__ deg, int N)
{
    int i = blockIdx.x * 256 + threadIdx.x;
    if (i < N) deg[i] = 1.0f;   // self-loop weight
}

__global__ __launch_bounds__(256) void k_deg_accum(
    const int* __restrict__ dst, const float* __restrict__ ew,
    float* __restrict__ deg, int E)
{
    int e = blockIdx.x * 256 + threadIdx.x;
    if (e < E) atomicAdd(&deg[dst[e]], ew[e]);
}

__global__ __launch_bounds__(256) void k_dis(float* __restrict__ deg, int N)
{
    int i = blockIdx.x * 256 + threadIdx.x;
    if (i < N) deg[i] = rsqrtf(fmaxf(deg[i], 1e-12f));
}

__global__ __launch_bounds__(256) void k_norm(
    const int* __restrict__ src, const int* __restrict__ dst,
    const float* __restrict__ dis, float* __restrict__ ew, int E)
{
    int e = blockIdx.x * 256 + threadIdx.x;
    if (e < E) ew[e] = dis[src[e]] * ew[e] * dis[dst[e]];
}

// ---------------- dense GEMM: Y = (relu?)X @ W  (X:[N,128], W:[128,128]) --------
template <bool RELU_IN>
__global__ __launch_bounds__(256) void k_gemm(
    const float* __restrict__ X, const float* __restrict__ W,
    float* __restrict__ Y, int N)
{
    __shared__ float xs[8][HD];
    int rb = blockIdx.x * 8;
    int t  = threadIdx.x;
    {
        int r  = t >> 5;          // 0..7
        int c4 = (t & 31) * 4;
        int row = rb + r;
        float4 v = make_float4(0.f, 0.f, 0.f, 0.f);
        if (row < N) v = *reinterpret_cast<const float4*>(X + (size_t)row * HD + c4);
        if (RELU_IN) {
            v.x = fmaxf(v.x, 0.f); v.y = fmaxf(v.y, 0.f);
            v.z = fmaxf(v.z, 0.f); v.w = fmaxf(v.w, 0.f);
        }
        *reinterpret_cast<float4*>(&xs[r][c4]) = v;
    }
    __syncthreads();
    int r  = t >> 5;
    int c4 = (t & 31) * 4;
    int row = rb + r;
    if (row >= N) return;
    float4 acc = make_float4(0.f, 0.f, 0.f, 0.f);
#pragma unroll 8
    for (int k = 0; k < HD; ++k) {
        float xv = xs[r][k];
        float4 wv = *reinterpret_cast<const float4*>(W + k * HD + c4);
        acc.x = fmaf(xv, wv.x, acc.x);
        acc.y = fmaf(xv, wv.y, acc.y);
        acc.z = fmaf(xv, wv.z, acc.z);
        acc.w = fmaf(xv, wv.w, acc.w);
    }
    *reinterpret_cast<float4*>(Y + (size_t)row * HD + c4) = acc;
}

// ---------------- agg init: agg[n] = b + dis[n]^2 * lin[n]  (self-loop + bias) ---
__global__ __launch_bounds__(256) void k_init_agg(
    const float* __restrict__ lin, const float* __restrict__ dis,
    const float* __restrict__ b, float* __restrict__ agg, int N)
{
    int idx = blockIdx.x * 256 + threadIdx.x;   // one float4 per thread
    int total = N * (HD / 4);
    if (idx >= total) return;
    int n  = idx >> 5;            // / 32
    int c4 = (idx & 31) * 4;
    float d = dis[n];
    float s = d * d;
    float4 lv = *reinterpret_cast<const float4*>(lin + (size_t)n * HD + c4);
    float4 bv = *reinterpret_cast<const float4*>(b + c4);
    float4 o;
    o.x = fmaf(s, lv.x, bv.x);
    o.y = fmaf(s, lv.y, bv.y);
    o.z = fmaf(s, lv.z, bv.z);
    o.w = fmaf(s, lv.w, bv.w);
    *reinterpret_cast<float4*>(agg + (size_t)n * HD + c4) = o;
}

// ---------------- scatter: agg[dst] += norm * lin[src], 32 lanes/edge -----------
__global__ __launch_bounds__(256) void k_scatter(
    const int* __restrict__ src, const int* __restrict__ dst,
    const float* __restrict__ nrm, const float* __restrict__ lin,
    float* __restrict__ agg, int E)
{
    int gid = blockIdx.x * 256 + threadIdx.x;
    int e = gid >> 5;
    if (e >= E) return;
    int lane = gid & 31;
    int s = src[e], d = dst[e];
    float w = nrm[e];
    float4 v = *(reinterpret_cast<const float4*>(lin + (size_t)s * HD) + lane);
    float* ap = agg + (size_t)d * HD + lane * 4;
    atomicAdd(ap + 0, w * v.x);
    atomicAdd(ap + 1, w * v.y);
    atomicAdd(ap + 2, w * v.z);
    atomicAdd(ap + 3, w * v.w);
}

// ---------------- mean pool (with relu on input) into S[128] (sum, not mean) ----
__global__ __launch_bounds__(128) void k_pool(
    const float* __restrict__ h, float* __restrict__ S, int N)
{
    int c = threadIdx.x;              // 0..127
    int r0 = blockIdx.x * 64;
    int r1 = r0 + 64; if (r1 > N) r1 = N;
    float acc = 0.f;
    for (int r = r0; r < r1; ++r)
        acc += fmaxf(h[(size_t)r * HD + c], 0.f);
    atomicAdd(&S[c], acc);
}

// ---------------- head: out = (S/N) @ Wh + bh ----------------
__global__ __launch_bounds__(64) void k_head(
    const float* __restrict__ S, const float* __restrict__ Wh,
    const float* __restrict__ bh, float* __restrict__ out, float invN)
{
    int o = threadIdx.x;
    if (o >= OUTD) return;
    float acc = 0.f;
    for (int k = 0; k < HD; ++k)
        acc = fmaf(S[k], Wh[k * OUTD + o], acc);
    out[o] = fmaf(acc, invN, bh[o]);
}

extern "C" void kernel_launch(void* const* d_in, const int* in_sizes, int n_in,
                              void* d_out, int out_size, void* d_ws, size_t ws_size,
                              hipStream_t stream)
{
    const float* x         = (const float*)d_in[0];
    const int*   ei        = (const int*)  d_in[1];
    const float* edge_attr = (const float*)d_in[2];
    const float* We1       = (const float*)d_in[3];
    const float* be1       = (const float*)d_in[4];
    const float* We2       = (const float*)d_in[5];
    const float* be2       = (const float*)d_in[6];
    const float* W1        = (const float*)d_in[7];
    const float* b1        = (const float*)d_in[8];
    const float* W2        = (const float*)d_in[9];
    const float* b2        = (const float*)d_in[10];
    const float* W3        = (const float*)d_in[11];
    const float* b3        = (const float*)d_in[12];
    const float* Wh        = (const float*)d_in[13];
    const float* bh        = (const float*)d_in[14];

    const int N = in_sizes[0] / HD;
    const int E = in_sizes[2] / EAD;
    const int* srcp = ei;
    const int* dstp = ei + E;

    // workspace partition
    char* w = (char*)d_ws;
    float* ew  = (float*)w;  w += (size_t)E * sizeof(float);
    float* dis = (float*)w;  w += (size_t)N * sizeof(float);
    float* A   = (float*)w;  w += (size_t)N * HD * sizeof(float);
    float* B   = (float*)w;  w += (size_t)N * HD * sizeof(float);
    float* S   = (float*)w;  w += HD * sizeof(float);

    const int gE   = ceil_div(E, 256);
    const int gN   = ceil_div(N, 256);
    const int gNC  = ceil_div((long long)N * (HD / 4), 256);
    const int gSc  = ceil_div((long long)E * 32, 256);
    const int gGem = ceil_div(N, 8);

    // edge weights
    k_edge_mlp<<<gE, 256, 0, stream>>>(edge_attr, We1, be1, We2, be2, ew, E);

    // degrees -> dis, edge norms (stored back into ew)
    k_init_deg <<<gN, 256, 0, stream>>>(dis, N);
    k_deg_accum<<<gE, 256, 0, stream>>>(dstp, ew, dis, E);
    k_dis      <<<gN, 256, 0, stream>>>(dis, N);
    k_norm     <<<gE, 256, 0, stream>>>(srcp, dstp, dis, ew, E);

    // layer 1
    k_gemm<false><<<gGem, 256, 0, stream>>>(x, W1, A, N);
    k_init_agg   <<<gNC, 256, 0, stream>>>(A, dis, b1, B, N);
    k_scatter    <<<gSc, 256, 0, stream>>>(srcp, dstp, ew, A, B, E);

    // layer 2 (relu fused into GEMM input load)
    k_gemm<true> <<<gGem, 256, 0, stream>>>(B, W2, A, N);
    k_init_agg   <<<gNC, 256, 0, stream>>>(A, dis, b2, B, N);
    k_scatter    <<<gSc, 256, 0, stream>>>(srcp, dstp, ew, A, B, E);

    // layer 3
    k_gemm<true> <<<gGem, 256, 0, stream>>>(B, W3, A, N);
    k_init_agg   <<<gNC, 256, 0, stream>>>(A, dis, b3, B, N);
    k_scatter    <<<gSc, 256, 0, stream>>>(srcp, dstp, ew, A, B, E);

    // pool (relu fused) + head
    hipMemsetAsync(S, 0, HD * sizeof(float), stream);
    k_pool<<<ceil_div(N, 64), 128, 0, stream>>>(B, S, N);
    k_head<<<1, 64, 0, stream>>>(S, Wh, bh, (float*)d_out, 1.0f / (float)N);
}

// Round 3
// 1362.011 us; speedup vs baseline: 6.2548x; 6.2548x over previous
//
#include <hip/hip_runtime.h>

// GraphGCN forward. Round 2: CSR-gather aggregation (no float atomics).
// N=50000 nodes, E=1600000 edges, IN=H=128, EA=16, OUT=10.
//
// ws layout: ew[E] f32 | dis[N] f32 | A[N*128] f32 | B[N*128] f32 | S[128] f32
//            | cnt[N+1] i32 | rp[N+1] i32 | adj[E] int2
// total ~71 MB.

#define HD   128
#define EAD  16
#define OUTD 10

static inline int ceil_div(long long a, long long b){ return (int)((a + b - 1) / b); }

// ---------------- edge MLP: ew[e] = softplus(relu(ea@We1+be1)@We2+be2) -------------
__global__ __launch_bounds__(256) void k_edge_mlp(
    const float* __restrict__ edge_attr,
    const float* __restrict__ We1, const float* __restrict__ be1,
    const float* __restrict__ We2, const float* __restrict__ be2,
    float* __restrict__ ew, int E)
{
    int e = blockIdx.x * 256 + threadIdx.x;
    if (e >= E) return;
    float ea[EAD];
    const float4* p = reinterpret_cast<const float4*>(edge_attr + (size_t)e * EAD);
#pragma unroll
    for (int i = 0; i < 4; ++i) {
        float4 v = p[i];
        ea[4*i+0] = v.x; ea[4*i+1] = v.y; ea[4*i+2] = v.z; ea[4*i+3] = v.w;
    }
    float acc = be2[0];
    for (int cb = 0; cb < HD; cb += 32) {
        float h[32];
#pragma unroll
        for (int j = 0; j < 32; ++j) h[j] = be1[cb + j];
#pragma unroll
        for (int k = 0; k < EAD; ++k) {
            float a = ea[k];
#pragma unroll
            for (int j = 0; j < 32; ++j)
                h[j] = fmaf(a, We1[k * HD + cb + j], h[j]);
        }
#pragma unroll
        for (int j = 0; j < 32; ++j)
            acc = fmaf(fmaxf(h[j], 0.0f), We2[cb + j], acc);
    }
    float sp = fmaxf(acc, 0.0f) + log1pf(expf(-fabsf(acc)));
    ew[e] = sp;
}

// ---------------- degree / normalization ----------------
__global__ __launch_bounds__(256) void k_init_deg(float* __restrict__ deg, int N)
{
    int i = blockIdx.x * 256 + threadIdx.x;
    if (i < N) deg[i] = 1.0f;   // self-loop weight
}

__global__ __launch_bounds__(256) void k_deg_accum(
    const int* __restrict__ dst, const float* __restrict__ ew,
    float* __restrict__ deg, int E)
{
    int e = blockIdx.x * 256 + threadIdx.x;
    if (e < E) atomicAdd(&deg[dst[e]], ew[e]);
}

__global__ __launch_bounds__(256) void k_dis(float* __restrict__ deg, int N)
{
    int i = blockIdx.x * 256 + threadIdx.x;
    if (i < N) deg[i] = rsqrtf(fmaxf(deg[i], 1e-12f));
}

__global__ __launch_bounds__(256) void k_norm(
    const int* __restrict__ src, const int* __restrict__ dst,
    const float* __restrict__ dis, float* __restrict__ ew, int E)
{
    int e = blockIdx.x * 256 + threadIdx.x;
    if (e < E) ew[e] = dis[src[e]] * ew[e] * dis[dst[e]];
}

// ---------------- CSR build ----------------
__global__ __launch_bounds__(256) void k_zero_cnt(int* __restrict__ cnt, int Np1)
{
    int i = blockIdx.x * 256 + threadIdx.x;
    if (i < Np1) cnt[i] = 0;
}

__global__ __launch_bounds__(256) void k_count(
    const int* __restrict__ dst, int* __restrict__ cnt, int E)
{
    int e = blockIdx.x * 256 + threadIdx.x;
    if (e < E) atomicAdd(&cnt[dst[e]], 1);
}

// single-block exclusive scan: rp[0..N], rp[N] = total
__global__ __launch_bounds__(256) void k_scan(
    const int* __restrict__ cnt, int* __restrict__ rp, int N)
{
    __shared__ int sh[256];
    __shared__ int carry_s;
    if (threadIdx.x == 0) carry_s = 0;
    __syncthreads();
    for (int base = 0; base < N; base += 256) {
        int i = base + threadIdx.x;
        int v = (i < N) ? cnt[i] : 0;
        sh[threadIdx.x] = v;
        __syncthreads();
        for (int off = 1; off < 256; off <<= 1) {
            int t = (threadIdx.x >= off) ? sh[threadIdx.x - off] : 0;
            __syncthreads();
            sh[threadIdx.x] += t;
            __syncthreads();
        }
        int carry = carry_s;
        if (i < N) rp[i] = carry + sh[threadIdx.x] - v;   // exclusive
        __syncthreads();
        if (threadIdx.x == 255) carry_s = carry + sh[255];
        __syncthreads();
    }
    if (threadIdx.x == 0) rp[N] = carry_s;
}

// cursor <- rp (first N entries)
__global__ __launch_bounds__(256) void k_copy_rp(
    const int* __restrict__ rp, int* __restrict__ cur, int N)
{
    int i = blockIdx.x * 256 + threadIdx.x;
    if (i < N) cur[i] = rp[i];
}

__global__ __launch_bounds__(256) void k_fill(
    const int* __restrict__ src, const int* __restrict__ dst,
    const float* __restrict__ nrm, int* __restrict__ cur,
    int2* __restrict__ adj, int E)
{
    int e = blockIdx.x * 256 + threadIdx.x;
    if (e >= E) return;
    int d = dst[e];
    int pos = atomicAdd(&cur[d], 1);
    adj[pos] = make_int2(src[e], __float_as_int(nrm[e]));
}

// ---------------- dense GEMM: Y = (relu?)X @ W  (X:[N,128], W:[128,128]) --------
template <bool RELU_IN>
__global__ __launch_bounds__(256) void k_gemm(
    const float* __restrict__ X, const float* __restrict__ W,
    float* __restrict__ Y, int N)
{
    __shared__ float xs[8][HD];
    int rb = blockIdx.x * 8;
    int t  = threadIdx.x;
    {
        int r  = t >> 5;
        int c4 = (t & 31) * 4;
        int row = rb + r;
        float4 v = make_float4(0.f, 0.f, 0.f, 0.f);
        if (row < N) v = *reinterpret_cast<const float4*>(X + (size_t)row * HD + c4);
        if (RELU_IN) {
            v.x = fmaxf(v.x, 0.f); v.y = fmaxf(v.y, 0.f);
            v.z = fmaxf(v.z, 0.f); v.w = fmaxf(v.w, 0.f);
        }
        *reinterpret_cast<float4*>(&xs[r][c4]) = v;
    }
    __syncthreads();
    int r  = t >> 5;
    int c4 = (t & 31) * 4;
    int row = rb + r;
    if (row >= N) return;
    float4 acc = make_float4(0.f, 0.f, 0.f, 0.f);
#pragma unroll 8
    for (int k = 0; k < HD; ++k) {
        float xv = xs[r][k];
        float4 wv = *reinterpret_cast<const float4*>(W + k * HD + c4);
        acc.x = fmaf(xv, wv.x, acc.x);
        acc.y = fmaf(xv, wv.y, acc.y);
        acc.z = fmaf(xv, wv.z, acc.z);
        acc.w = fmaf(xv, wv.w, acc.w);
    }
    *reinterpret_cast<float4*>(Y + (size_t)row * HD + c4) = acc;
}

// ---------------- gather aggregation: out[n] = b + dis[n]^2*lin[n] + sum_e w*lin[src]
__global__ __launch_bounds__(256) void k_gather(
    const int* __restrict__ rp, const int2* __restrict__ adj,
    const float* __restrict__ lin, const float* __restrict__ dis,
    const float* __restrict__ b, float* __restrict__ out, int N)
{
    int n = blockIdx.x * 8 + (threadIdx.x >> 5);
    if (n >= N) return;
    int lane = threadIdx.x & 31;
    float d  = dis[n];
    float s  = d * d;
    float4 bv = reinterpret_cast<const float4*>(b)[lane];
    float4 lv = *(reinterpret_cast<const float4*>(lin + (size_t)n * HD) + lane);
    float4 acc;
    acc.x = fmaf(s, lv.x, bv.x);
    acc.y = fmaf(s, lv.y, bv.y);
    acc.z = fmaf(s, lv.z, bv.z);
    acc.w = fmaf(s, lv.w, bv.w);
    int beg = rp[n], end = rp[n + 1];
    for (int i = beg; i < end; ++i) {
        int2 e = adj[i];
        float w = __int_as_float(e.y);
        float4 v = *(reinterpret_cast<const float4*>(lin + (size_t)e.x * HD) + lane);
        acc.x = fmaf(w, v.x, acc.x);
        acc.y = fmaf(w, v.y, acc.y);
        acc.z = fmaf(w, v.z, acc.z);
        acc.w = fmaf(w, v.w, acc.w);
    }
    *(reinterpret_cast<float4*>(out + (size_t)n * HD) + lane) = acc;
}

// ---------------- mean pool (relu fused) into S[128] (sum) ----------------
__global__ __launch_bounds__(128) void k_pool(
    const float* __restrict__ h, float* __restrict__ S, int N)
{
    int c = threadIdx.x;
    int r0 = blockIdx.x * 64;
    int r1 = r0 + 64; if (r1 > N) r1 = N;
    float acc = 0.f;
    for (int r = r0; r < r1; ++r)
        acc += fmaxf(h[(size_t)r * HD + c], 0.f);
    atomicAdd(&S[c], acc);
}

// ---------------- head: out = (S/N) @ Wh + bh ----------------
__global__ __launch_bounds__(64) void k_head(
    const float* __restrict__ S, const float* __restrict__ Wh,
    const float* __restrict__ bh, float* __restrict__ out, float invN)
{
    int o = threadIdx.x;
    if (o >= OUTD) return;
    float acc = 0.f;
    for (int k = 0; k < HD; ++k)
        acc = fmaf(S[k], Wh[k * OUTD + o], acc);
    out[o] = fmaf(acc, invN, bh[o]);
}

extern "C" void kernel_launch(void* const* d_in, const int* in_sizes, int n_in,
                              void* d_out, int out_size, void* d_ws, size_t ws_size,
                              hipStream_t stream)
{
    const float* x         = (const float*)d_in[0];
    const int*   ei        = (const int*)  d_in[1];
    const float* edge_attr = (const float*)d_in[2];
    const float* We1       = (const float*)d_in[3];
    const float* be1       = (const float*)d_in[4];
    const float* We2       = (const float*)d_in[5];
    const float* be2       = (const float*)d_in[6];
    const float* W1        = (const float*)d_in[7];
    const float* b1        = (const float*)d_in[8];
    const float* W2        = (const float*)d_in[9];
    const float* b2        = (const float*)d_in[10];
    const float* W3        = (const float*)d_in[11];
    const float* b3        = (const float*)d_in[12];
    const float* Wh        = (const float*)d_in[13];
    const float* bh        = (const float*)d_in[14];

    const int N = in_sizes[0] / HD;
    const int E = in_sizes[2] / EAD;
    const int* srcp = ei;
    const int* dstp = ei + E;

    // workspace partition
    char* w = (char*)d_ws;
    float* ew  = (float*)w;  w += (size_t)E * sizeof(float);
    float* dis = (float*)w;  w += (size_t)N * sizeof(float);
    float* A   = (float*)w;  w += (size_t)N * HD * sizeof(float);
    float* B   = (float*)w;  w += (size_t)N * HD * sizeof(float);
    float* S   = (float*)w;  w += 256 * sizeof(float);
    int*   cnt = (int*)w;    w += (size_t)(N + 2) * sizeof(int);
    int*   rp  = (int*)w;    w += (size_t)(N + 2) * sizeof(int);
    w = (char*)(((uintptr_t)w + 15) & ~(uintptr_t)15);
    int2*  adj = (int2*)w;   w += (size_t)E * sizeof(int2);

    const int gE  = ceil_div(E, 256);
    const int gN  = ceil_div(N, 256);
    const int gGe = ceil_div(N, 8);

    // edge weights
    k_edge_mlp<<<gE, 256, 0, stream>>>(edge_attr, We1, be1, We2, be2, ew, E);

    // degrees -> dis, edge norms (stored back into ew)
    k_init_deg <<<gN, 256, 0, stream>>>(dis, N);
    k_deg_accum<<<gE, 256, 0, stream>>>(dstp, ew, dis, E);
    k_dis      <<<gN, 256, 0, stream>>>(dis, N);
    k_norm     <<<gE, 256, 0, stream>>>(srcp, dstp, dis, ew, E);

    // CSR build (by destination)
    k_zero_cnt<<<ceil_div(N + 1, 256), 256, 0, stream>>>(cnt, N + 1);
    k_count   <<<gE, 256, 0, stream>>>(dstp, cnt, E);
    k_scan    <<<1, 256, 0, stream>>>(cnt, rp, N);
    k_copy_rp <<<gN, 256, 0, stream>>>(rp, cnt, N);     // cnt becomes cursor
    k_fill    <<<gE, 256, 0, stream>>>(srcp, dstp, ew, cnt, adj, E);

    // layer 1
    k_gemm<false><<<gGe, 256, 0, stream>>>(x, W1, A, N);
    k_gather     <<<gGe, 256, 0, stream>>>(rp, adj, A, dis, b1, B, N);

    // layer 2 (relu fused into GEMM input load)
    k_gemm<true> <<<gGe, 256, 0, stream>>>(B, W2, A, N);
    k_gather     <<<gGe, 256, 0, stream>>>(rp, adj, A, dis, b2, B, N);

    // layer 3
    k_gemm<true> <<<gGe, 256, 0, stream>>>(B, W3, A, N);
    k_gather     <<<gGe, 256, 0, stream>>>(rp, adj, A, dis, b3, B, N);

    // pool (relu fused) + head
    hipMemsetAsync(S, 0, HD * sizeof(float), stream);
    k_pool<<<ceil_div(N, 64), 128, 0, stream>>>(B, S, N);
    k_head<<<1, 64, 0, stream>>>(S, Wh, bh, (float*)d_out, 1.0f / (float)N);
}

// Round 4
// 1088.341 us; speedup vs baseline: 7.8276x; 1.2515x over previous
//
#include <hip/hip_runtime.h>

// GraphGCN forward. Round 3: parallel hierarchical scan + fused norm/count.
// N=50000 nodes, E=1600000 edges, IN=H=128, EA=16, OUT=10.
//
// ws layout: ew[E] f32 | dis[N] f32 | A[N*128] f32 | B[N*128] f32 | S f32
//            | cnt[N+2] i32 | rp[N+2] i32 | bsum[256] i32 | adj[E] int2

#define HD   128
#define EAD  16
#define OUTD 10
#define SCAN_CHUNK 2048   // elements per scan block (256 thr x 8)

static inline int ceil_div(long long a, long long b){ return (int)((a + b - 1) / b); }

// ---------------- edge MLP: ew[e] = softplus(relu(ea@We1+be1)@We2+be2) -------------
__global__ __launch_bounds__(256) void k_edge_mlp(
    const float* __restrict__ edge_attr,
    const float* __restrict__ We1, const float* __restrict__ be1,
    const float* __restrict__ We2, const float* __restrict__ be2,
    float* __restrict__ ew, int E)
{
    int e = blockIdx.x * 256 + threadIdx.x;
    if (e >= E) return;
    float ea[EAD];
    const float4* p = reinterpret_cast<const float4*>(edge_attr + (size_t)e * EAD);
#pragma unroll
    for (int i = 0; i < 4; ++i) {
        float4 v = p[i];
        ea[4*i+0] = v.x; ea[4*i+1] = v.y; ea[4*i+2] = v.z; ea[4*i+3] = v.w;
    }
    float acc = be2[0];
    for (int cb = 0; cb < HD; cb += 32) {
        float h[32];
#pragma unroll
        for (int j = 0; j < 32; ++j) h[j] = be1[cb + j];
#pragma unroll
        for (int k = 0; k < EAD; ++k) {
            float a = ea[k];
#pragma unroll
            for (int j = 0; j < 32; ++j)
                h[j] = fmaf(a, We1[k * HD + cb + j], h[j]);
        }
#pragma unroll
        for (int j = 0; j < 32; ++j)
            acc = fmaf(fmaxf(h[j], 0.0f), We2[cb + j], acc);
    }
    float sp = fmaxf(acc, 0.0f) + log1pf(expf(-fabsf(acc)));
    ew[e] = sp;
}

// ---------------- init: deg=1 (self-loop), cnt=0 ----------------
__global__ __launch_bounds__(256) void k_init(
    float* __restrict__ deg, int* __restrict__ cnt, int N)
{
    int i = blockIdx.x * 256 + threadIdx.x;
    if (i < N) { deg[i] = 1.0f; cnt[i] = 0; }
}

// ---------------- fused degree accumulation + edge count ----------------
__global__ __launch_bounds__(256) void k_deg_count(
    const int* __restrict__ dst, const float* __restrict__ ew,
    float* __restrict__ deg, int* __restrict__ cnt, int E)
{
    int e = blockIdx.x * 256 + threadIdx.x;
    if (e >= E) return;
    int d = dst[e];
    atomicAdd(&deg[d], ew[e]);
    atomicAdd(&cnt[d], 1);
}

__global__ __launch_bounds__(256) void k_dis(float* __restrict__ deg, int N)
{
    int i = blockIdx.x * 256 + threadIdx.x;
    if (i < N) deg[i] = rsqrtf(fmaxf(deg[i], 1e-12f));
}

// ---------------- hierarchical exclusive scan ----------------
// stage 1: per-block (2048 elems) local exclusive scan + block sums
__global__ __launch_bounds__(256) void k_scan_local(
    const int* __restrict__ cnt, int* __restrict__ rp,
    int* __restrict__ bsum, int N)
{
    __shared__ int sh[256];
    int t = threadIdx.x;
    int base = blockIdx.x * SCAN_CHUNK + t * 8;
    int v[8];
    int s = 0;
#pragma unroll
    for (int j = 0; j < 8; ++j) {
        int idx = base + j;
        v[j] = (idx < N) ? cnt[idx] : 0;
        s += v[j];
    }
    sh[t] = s;
    __syncthreads();
    for (int off = 1; off < 256; off <<= 1) {
        int add = (t >= off) ? sh[t - off] : 0;
        __syncthreads();
        sh[t] += add;
        __syncthreads();
    }
    int run = sh[t] - s;            // exclusive prefix of this thread's chunk
#pragma unroll
    for (int j = 0; j < 8; ++j) {
        int idx = base + j;
        if (idx < N) rp[idx] = run;
        run += v[j];
    }
    if (t == 255) bsum[blockIdx.x] = sh[255];
}

// stage 2: scan block sums (nb <= 256), write rp[N] = total
__global__ __launch_bounds__(256) void k_scan_bsum(
    int* __restrict__ bsum, int* __restrict__ rp, int N, int nb)
{
    __shared__ int sh[256];
    int t = threadIdx.x;
    int v = (t < nb) ? bsum[t] : 0;
    sh[t] = v;
    __syncthreads();
    for (int off = 1; off < 256; off <<= 1) {
        int add = (t >= off) ? sh[t - off] : 0;
        __syncthreads();
        sh[t] += add;
        __syncthreads();
    }
    if (t < nb) bsum[t] = sh[t] - v;        // exclusive
    if (t == nb - 1) rp[N] = sh[t];          // grand total
}

// stage 3: add block offsets; also emit fill cursor
__global__ __launch_bounds__(256) void k_scan_add(
    int* __restrict__ rp, const int* __restrict__ bsum,
    int* __restrict__ cur, int N)
{
    int i = blockIdx.x * 256 + threadIdx.x;
    if (i >= N) return;
    int r = rp[i] + bsum[i / SCAN_CHUNK];
    rp[i] = r;
    cur[i] = r;
}

// ---------------- fill adjacency (norm computed inline) ----------------
__global__ __launch_bounds__(256) void k_fill(
    const int* __restrict__ src, const int* __restrict__ dst,
    const float* __restrict__ ew, const float* __restrict__ dis,
    int* __restrict__ cur, int2* __restrict__ adj, int E)
{
    int e = blockIdx.x * 256 + threadIdx.x;
    if (e >= E) return;
    int s = src[e], d = dst[e];
    float nrm = dis[s] * ew[e] * dis[d];
    int pos = atomicAdd(&cur[d], 1);
    adj[pos] = make_int2(s, __float_as_int(nrm));
}

// ---------------- dense GEMM: Y = (relu?)X @ W  (X:[N,128], W:[128,128]) --------
template <bool RELU_IN>
__global__ __launch_bounds__(256) void k_gemm(
    const float* __restrict__ X, const float* __restrict__ W,
    float* __restrict__ Y, int N)
{
    __shared__ float xs[8][HD];
    int rb = blockIdx.x * 8;
    int t  = threadIdx.x;
    {
        int r  = t >> 5;
        int c4 = (t & 31) * 4;
        int row = rb + r;
        float4 v = make_float4(0.f, 0.f, 0.f, 0.f);
        if (row < N) v = *reinterpret_cast<const float4*>(X + (size_t)row * HD + c4);
        if (RELU_IN) {
            v.x = fmaxf(v.x, 0.f); v.y = fmaxf(v.y, 0.f);
            v.z = fmaxf(v.z, 0.f); v.w = fmaxf(v.w, 0.f);
        }
        *reinterpret_cast<float4*>(&xs[r][c4]) = v;
    }
    __syncthreads();
    int r  = t >> 5;
    int c4 = (t & 31) * 4;
    int row = rb + r;
    if (row >= N) return;
    float4 acc = make_float4(0.f, 0.f, 0.f, 0.f);
#pragma unroll 8
    for (int k = 0; k < HD; ++k) {
        float xv = xs[r][k];
        float4 wv = *reinterpret_cast<const float4*>(W + k * HD + c4);
        acc.x = fmaf(xv, wv.x, acc.x);
        acc.y = fmaf(xv, wv.y, acc.y);
        acc.z = fmaf(xv, wv.z, acc.z);
        acc.w = fmaf(xv, wv.w, acc.w);
    }
    *reinterpret_cast<float4*>(Y + (size_t)row * HD + c4) = acc;
}

// ---------------- gather aggregation: out[n] = b + dis[n]^2*lin[n] + sum_e w*lin[src]
__global__ __launch_bounds__(256) void k_gather(
    const int* __restrict__ rp, const int2* __restrict__ adj,
    const float* __restrict__ lin, const float* __restrict__ dis,
    const float* __restrict__ b, float* __restrict__ out, int N)
{
    int n = blockIdx.x * 8 + (threadIdx.x >> 5);
    if (n >= N) return;
    int lane = threadIdx.x & 31;
    float d  = dis[n];
    float s  = d * d;
    float4 bv = reinterpret_cast<const float4*>(b)[lane];
    float4 lv = *(reinterpret_cast<const float4*>(lin + (size_t)n * HD) + lane);
    float4 acc;
    acc.x = fmaf(s, lv.x, bv.x);
    acc.y = fmaf(s, lv.y, bv.y);
    acc.z = fmaf(s, lv.z, bv.z);
    acc.w = fmaf(s, lv.w, bv.w);
    int beg = rp[n], end = rp[n + 1];
    for (int i = beg; i < end; ++i) {
        int2 e = adj[i];
        float w = __int_as_float(e.y);
        float4 v = *(reinterpret_cast<const float4*>(lin + (size_t)e.x * HD) + lane);
        acc.x = fmaf(w, v.x, acc.x);
        acc.y = fmaf(w, v.y, acc.y);
        acc.z = fmaf(w, v.z, acc.z);
        acc.w = fmaf(w, v.w, acc.w);
    }
    *(reinterpret_cast<float4*>(out + (size_t)n * HD) + lane) = acc;
}

// ---------------- mean pool (relu fused) into S[128] (sum) ----------------
__global__ __launch_bounds__(128) void k_pool(
    const float* __restrict__ h, float* __restrict__ S, int N)
{
    int c = threadIdx.x;
    int r0 = blockIdx.x * 64;
    int r1 = r0 + 64; if (r1 > N) r1 = N;
    float acc = 0.f;
    for (int r = r0; r < r1; ++r)
        acc += fmaxf(h[(size_t)r * HD + c], 0.f);
    atomicAdd(&S[c], acc);
}

// ---------------- head: out = (S/N) @ Wh + bh ----------------
__global__ __launch_bounds__(64) void k_head(
    const float* __restrict__ S, const float* __restrict__ Wh,
    const float* __restrict__ bh, float* __restrict__ out, float invN)
{
    int o = threadIdx.x;
    if (o >= OUTD) return;
    float acc = 0.f;
    for (int k = 0; k < HD; ++k)
        acc = fmaf(S[k], Wh[k * OUTD + o], acc);
    out[o] = fmaf(acc, invN, bh[o]);
}

extern "C" void kernel_launch(void* const* d_in, const int* in_sizes, int n_in,
                              void* d_out, int out_size, void* d_ws, size_t ws_size,
                              hipStream_t stream)
{
    const float* x         = (const float*)d_in[0];
    const int*   ei        = (const int*)  d_in[1];
    const float* edge_attr = (const float*)d_in[2];
    const float* We1       = (const float*)d_in[3];
    const float* be1       = (const float*)d_in[4];
    const float* We2       = (const float*)d_in[5];
    const float* be2       = (const float*)d_in[6];
    const float* W1        = (const float*)d_in[7];
    const float* b1        = (const float*)d_in[8];
    const float* W2        = (const float*)d_in[9];
    const float* b2        = (const float*)d_in[10];
    const float* W3        = (const float*)d_in[11];
    const float* b3        = (const float*)d_in[12];
    const float* Wh        = (const float*)d_in[13];
    const float* bh        = (const float*)d_in[14];

    const int N = in_sizes[0] / HD;
    const int E = in_sizes[2] / EAD;
    const int* srcp = ei;
    const int* dstp = ei + E;

    // workspace partition
    char* w = (char*)d_ws;
    float* ew  = (float*)w;  w += (size_t)E * sizeof(float);
    float* dis = (float*)w;  w += (size_t)N * sizeof(float);
    float* A   = (float*)w;  w += (size_t)N * HD * sizeof(float);
    float* B   = (float*)w;  w += (size_t)N * HD * sizeof(float);
    float* S   = (float*)w;  w += 256 * sizeof(float);
    int*   cnt = (int*)w;    w += (size_t)(N + 2) * sizeof(int);
    int*   rp  = (int*)w;    w += (size_t)(N + 2) * sizeof(int);
    int*   bsum= (int*)w;    w += 256 * sizeof(int);
    w = (char*)(((uintptr_t)w + 15) & ~(uintptr_t)15);
    int2*  adj = (int2*)w;   w += (size_t)E * sizeof(int2);

    const int gE  = ceil_div(E, 256);
    const int gN  = ceil_div(N, 256);
    const int gGe = ceil_div(N, 8);
    const int nbScan = ceil_div(N, SCAN_CHUNK);   // 25 blocks for N=50k

    // edge weights
    k_edge_mlp<<<gE, 256, 0, stream>>>(edge_attr, We1, be1, We2, be2, ew, E);

    // degrees + edge counts
    k_init     <<<gN, 256, 0, stream>>>(dis, cnt, N);
    k_deg_count<<<gE, 256, 0, stream>>>(dstp, ew, dis, cnt, E);
    k_dis      <<<gN, 256, 0, stream>>>(dis, N);

    // hierarchical exclusive scan: cnt -> rp (and cursor in cnt)
    k_scan_local<<<nbScan, 256, 0, stream>>>(cnt, rp, bsum, N);
    k_scan_bsum <<<1, 256, 0, stream>>>(bsum, rp, N, nbScan);
    k_scan_add  <<<gN, 256, 0, stream>>>(rp, bsum, cnt, N);   // cnt becomes cursor

    // adjacency fill (norm inline)
    k_fill<<<gE, 256, 0, stream>>>(srcp, dstp, ew, dis, cnt, adj, E);

    // layer 1
    k_gemm<false><<<gGe, 256, 0, stream>>>(x, W1, A, N);
    k_gather     <<<gGe, 256, 0, stream>>>(rp, adj, A, dis, b1, B, N);

    // layer 2 (relu fused into GEMM input load)
    k_gemm<true> <<<gGe, 256, 0, stream>>>(B, W2, A, N);
    k_gather     <<<gGe, 256, 0, stream>>>(rp, adj, A, dis, b2, B, N);

    // layer 3
    k_gemm<true> <<<gGe, 256, 0, stream>>>(B, W3, A, N);
    k_gather     <<<gGe, 256, 0, stream>>>(rp, adj, A, dis, b3, B, N);

    // pool (relu fused) + head
    hipMemsetAsync(S, 0, HD * sizeof(float), stream);
    k_pool<<<ceil_div(N, 64), 128, 0, stream>>>(B, S, N);
    k_head<<<1, 64, 0, stream>>>(S, Wh, bh, (float*)d_out, 1.0f / (float)N);
}

// Round 5
// 882.190 us; speedup vs baseline: 9.6567x; 1.2337x over previous
//
#include <hip/hip_runtime.h>

// GraphGCN forward. Round 4: no float atomics (deg via CSR row-sum),
// dis folded into GEMM epilogue, bf16 gather rows, atomic-free pool.
// N=50000 nodes, E=1600000 edges, IN=H=128, EA=16, OUT=10.
//
// ws: ew[E] f32 | dis[N] f32 | B[N*128] f32 | Abf[N*64] u32 (bf16x2)
//     | part[128*128] f32 | cnt[N+2] i32 | rp[N+2] i32 | bsum[256] i32
//     | adj[E] int2                                   (~58 MB total)

#define HD   128
#define EAD  16
#define OUTD 10
#define SCAN_CHUNK 2048

static inline int ceil_div(long long a, long long b){ return (int)((a + b - 1) / b); }

__device__ inline unsigned f2bf(float f) {           // RNE f32 -> bf16
    unsigned u = __float_as_uint(f);
    return (u + 0x7fffu + ((u >> 16) & 1u)) >> 16;
}
__device__ inline float bf_lo(unsigned w) { return __uint_as_float(w << 16); }
__device__ inline float bf_hi(unsigned w) { return __uint_as_float(w & 0xffff0000u); }

// ------------- edge MLP + fused dst count: ew[e]=softplus(mlp(ea)), cnt[dst]++ ----
__global__ __launch_bounds__(256) void k_edge_mlp(
    const float* __restrict__ edge_attr, const int* __restrict__ dst,
    const float* __restrict__ We1, const float* __restrict__ be1,
    const float* __restrict__ We2, const float* __restrict__ be2,
    float* __restrict__ ew, int* __restrict__ cnt, int E)
{
    int e = blockIdx.x * 256 + threadIdx.x;
    if (e >= E) return;
    atomicAdd(&cnt[dst[e]], 1);            // issue early; hides under the MLP
    float ea[EAD];
    const float4* p = reinterpret_cast<const float4*>(edge_attr + (size_t)e * EAD);
#pragma unroll
    for (int i = 0; i < 4; ++i) {
        float4 v = p[i];
        ea[4*i+0] = v.x; ea[4*i+1] = v.y; ea[4*i+2] = v.z; ea[4*i+3] = v.w;
    }
    float acc = be2[0];
    for (int cb = 0; cb < HD; cb += 32) {
        float h[32];
#pragma unroll
        for (int j = 0; j < 32; ++j) h[j] = be1[cb + j];
#pragma unroll
        for (int k = 0; k < EAD; ++k) {
            float a = ea[k];
#pragma unroll
            for (int j = 0; j < 32; ++j)
                h[j] = fmaf(a, We1[k * HD + cb + j], h[j]);
        }
#pragma unroll
        for (int j = 0; j < 32; ++j)
            acc = fmaf(fmaxf(h[j], 0.0f), We2[cb + j], acc);
    }
    ew[e] = fmaxf(acc, 0.0f) + log1pf(expf(-fabsf(acc)));
}

// ---------------- hierarchical exclusive scan ----------------
__global__ __launch_bounds__(256) void k_scan_local(
    const int* __restrict__ cnt, int* __restrict__ rp,
    int* __restrict__ bsum, int N)
{
    __shared__ int sh[256];
    int t = threadIdx.x;
    int base = blockIdx.x * SCAN_CHUNK + t * 8;
    int v[8];
    int s = 0;
#pragma unroll
    for (int j = 0; j < 8; ++j) {
        int idx = base + j;
        v[j] = (idx < N) ? cnt[idx] : 0;
        s += v[j];
    }
    sh[t] = s;
    __syncthreads();
    for (int off = 1; off < 256; off <<= 1) {
        int add = (t >= off) ? sh[t - off] : 0;
        __syncthreads();
        sh[t] += add;
        __syncthreads();
    }
    int run = sh[t] - s;
#pragma unroll
    for (int j = 0; j < 8; ++j) {
        int idx = base + j;
        if (idx < N) rp[idx] = run;
        run += v[j];
    }
    if (t == 255) bsum[blockIdx.x] = sh[255];
}

__global__ __launch_bounds__(256) void k_scan_bsum(
    int* __restrict__ bsum, int* __restrict__ rp, int N, int nb)
{
    __shared__ int sh[256];
    int t = threadIdx.x;
    int v = (t < nb) ? bsum[t] : 0;
    sh[t] = v;
    __syncthreads();
    for (int off = 1; off < 256; off <<= 1) {
        int add = (t >= off) ? sh[t - off] : 0;
        __syncthreads();
        sh[t] += add;
        __syncthreads();
    }
    if (t < nb) bsum[t] = sh[t] - v;
    if (t == nb - 1) rp[N] = sh[t];
}

__global__ __launch_bounds__(256) void k_scan_add(
    int* __restrict__ rp, const int* __restrict__ bsum,
    int* __restrict__ cur, int N)
{
    int i = blockIdx.x * 256 + threadIdx.x;
    if (i >= N) return;
    int r = rp[i] + bsum[i / SCAN_CHUNK];
    rp[i] = r;
    cur[i] = r;
}

// ---------------- fill adjacency with RAW ew ----------------
__global__ __launch_bounds__(256) void k_fill(
    const int* __restrict__ src, const int* __restrict__ dst,
    const float* __restrict__ ew, int* __restrict__ cur,
    int2* __restrict__ adj, int E)
{
    int e = blockIdx.x * 256 + threadIdx.x;
    if (e >= E) return;
    int d = dst[e];
    int pos = atomicAdd(&cur[d], 1);
    adj[pos] = make_int2(src[e], __float_as_int(ew[e]));
}

// ---------------- dis[n] = rsqrt(1 + sum_row ew)  (no atomics) ----------------
__global__ __launch_bounds__(256) void k_row_dis(
    const int* __restrict__ rp, const int2* __restrict__ adj,
    float* __restrict__ dis, int N)
{
    int n = blockIdx.x * 8 + (threadIdx.x >> 5);
    if (n >= N) return;
    int lane = threadIdx.x & 31;
    int beg = rp[n], end = rp[n + 1];
    float s = 0.f;
    for (int i = beg + lane; i < end; i += 32)
        s += __int_as_float(adj[i].y);
#pragma unroll
    for (int off = 16; off; off >>= 1)
        s += __shfl_xor(s, off, 32);
    if (lane == 0) dis[n] = rsqrtf(1.0f + s);
}

// ------- GEMM: Ybf[row] = bf16( dis[row] * (relu?)X[row] @ W ) ----------------
template <bool RELU_IN>
__global__ __launch_bounds__(256) void k_gemm(
    const float* __restrict__ X, const float* __restrict__ W,
    const float* __restrict__ dis, unsigned* __restrict__ Ybf, int N)
{
    __shared__ float xs[8][HD];
    int rb = blockIdx.x * 8;
    int t  = threadIdx.x;
    {
        int r  = t >> 5;
        int c4 = (t & 31) * 4;
        int row = rb + r;
        float4 v = make_float4(0.f, 0.f, 0.f, 0.f);
        if (row < N) v = *reinterpret_cast<const float4*>(X + (size_t)row * HD + c4);
        if (RELU_IN) {
            v.x = fmaxf(v.x, 0.f); v.y = fmaxf(v.y, 0.f);
            v.z = fmaxf(v.z, 0.f); v.w = fmaxf(v.w, 0.f);
        }
        *reinterpret_cast<float4*>(&xs[r][c4]) = v;
    }
    __syncthreads();
    int r  = t >> 5;
    int c4 = (t & 31) * 4;
    int row = rb + r;
    if (row >= N) return;
    float4 acc = make_float4(0.f, 0.f, 0.f, 0.f);
#pragma unroll 8
    for (int k = 0; k < HD; ++k) {
        float xv = xs[r][k];
        float4 wv = *reinterpret_cast<const float4*>(W + k * HD + c4);
        acc.x = fmaf(xv, wv.x, acc.x);
        acc.y = fmaf(xv, wv.y, acc.y);
        acc.z = fmaf(xv, wv.z, acc.z);
        acc.w = fmaf(xv, wv.w, acc.w);
    }
    float dn = dis[row];
    unsigned w0 = f2bf(acc.x * dn) | (f2bf(acc.y * dn) << 16);
    unsigned w1 = f2bf(acc.z * dn) | (f2bf(acc.w * dn) << 16);
    *reinterpret_cast<uint2*>(Ybf + (size_t)row * (HD/2) + (t & 31) * 2) = make_uint2(w0, w1);
}

// --- gather: out[n] = b + dis[n] * ( linbf[n] + sum_row ew * linbf[src] ) ------
__global__ __launch_bounds__(256) void k_gather(
    const int* __restrict__ rp, const int2* __restrict__ adj,
    const unsigned* __restrict__ linbf, const float* __restrict__ dis,
    const float* __restrict__ b, float* __restrict__ out, int N)
{
    int n = blockIdx.x * 8 + (threadIdx.x >> 5);
    if (n >= N) return;
    int lane = threadIdx.x & 31;
    // self term: lin'[n]
    uint2 sw = *reinterpret_cast<const uint2*>(linbf + (size_t)n * (HD/2) + lane * 2);
    float4 acc;
    acc.x = bf_lo(sw.x); acc.y = bf_hi(sw.x);
    acc.z = bf_lo(sw.y); acc.w = bf_hi(sw.y);
    int beg = rp[n], end = rp[n + 1];
    for (int i0 = beg; i0 < end; i0 += 32) {
        int m = end - i0; if (m > 32) m = 32;
        int2 my = make_int2(0, 0);
        if (lane < m) my = adj[i0 + lane];
        for (int j = 0; j < m; ++j) {
            int   sn = __shfl(my.x, j, 32);
            float wg = __int_as_float(__shfl(my.y, j, 32));
            uint2 v = *reinterpret_cast<const uint2*>(linbf + (size_t)sn * (HD/2) + lane * 2);
            acc.x = fmaf(wg, bf_lo(v.x), acc.x);
            acc.y = fmaf(wg, bf_hi(v.x), acc.y);
            acc.z = fmaf(wg, bf_lo(v.y), acc.z);
            acc.w = fmaf(wg, bf_hi(v.y), acc.w);
        }
    }
    float dn = dis[n];
    float4 bv = reinterpret_cast<const float4*>(b)[lane];
    float4 o;
    o.x = fmaf(dn, acc.x, bv.x);
    o.y = fmaf(dn, acc.y, bv.y);
    o.z = fmaf(dn, acc.z, bv.z);
    o.w = fmaf(dn, acc.w, bv.w);
    *(reinterpret_cast<float4*>(out + (size_t)n * HD) + lane) = o;
}

// ---------------- pool partials (relu fused), atomic-free ----------------
__global__ __launch_bounds__(128) void k_pool(
    const float* __restrict__ h, float* __restrict__ part, int N)
{
    int c = threadIdx.x;
    float acc = 0.f;
    for (int r = blockIdx.x; r < N; r += 128)
        acc += fmaxf(h[(size_t)r * HD + c], 0.f);
    part[blockIdx.x * HD + c] = acc;
}

// ---------------- head: out = (colsum(part)/N) @ Wh + bh ----------------
__global__ __launch_bounds__(128) void k_head(
    const float* __restrict__ part, const float* __restrict__ Wh,
    const float* __restrict__ bh, float* __restrict__ out, float invN)
{
    __shared__ float col[HD];
    int t = threadIdx.x;
    float s = 0.f;
    for (int k = 0; k < 128; ++k)
        s += part[k * HD + t];
    col[t] = s * invN;
    __syncthreads();
    if (t < OUTD) {
        float acc = bh[t];
        for (int k = 0; k < HD; ++k)
            acc = fmaf(col[k], Wh[k * OUTD + t], acc);
        out[t] = acc;
    }
}

extern "C" void kernel_launch(void* const* d_in, const int* in_sizes, int n_in,
                              void* d_out, int out_size, void* d_ws, size_t ws_size,
                              hipStream_t stream)
{
    const float* x         = (const float*)d_in[0];
    const int*   ei        = (const int*)  d_in[1];
    const float* edge_attr = (const float*)d_in[2];
    const float* We1       = (const float*)d_in[3];
    const float* be1       = (const float*)d_in[4];
    const float* We2       = (const float*)d_in[5];
    const float* be2       = (const float*)d_in[6];
    const float* W1        = (const float*)d_in[7];
    const float* b1        = (const float*)d_in[8];
    const float* W2        = (const float*)d_in[9];
    const float* b2        = (const float*)d_in[10];
    const float* W3        = (const float*)d_in[11];
    const float* b3        = (const float*)d_in[12];
    const float* Wh        = (const float*)d_in[13];
    const float* bh        = (const float*)d_in[14];

    const int N = in_sizes[0] / HD;
    const int E = in_sizes[2] / EAD;
    const int* srcp = ei;
    const int* dstp = ei + E;

    // workspace partition (all 16B aligned for N,E multiples of 4)
    char* w = (char*)d_ws;
    float*    ew   = (float*)w;    w += (size_t)E * sizeof(float);
    float*    dis  = (float*)w;    w += (size_t)N * sizeof(float);
    float*    B    = (float*)w;    w += (size_t)N * HD * sizeof(float);
    unsigned* Abf  = (unsigned*)w; w += (size_t)N * (HD/2) * sizeof(unsigned);
    float*    part = (float*)w;    w += 128 * HD * sizeof(float);
    int*      cnt  = (int*)w;      w += (size_t)(N + 2) * sizeof(int);
    int*      rp   = (int*)w;      w += (size_t)(N + 2) * sizeof(int);
    int*      bsum = (int*)w;      w += 256 * sizeof(int);
    w = (char*)(((uintptr_t)w + 15) & ~(uintptr_t)15);
    int2*     adj  = (int2*)w;     w += (size_t)E * sizeof(int2);

    const int gE  = ceil_div(E, 256);
    const int gN  = ceil_div(N, 256);
    const int gGe = ceil_div(N, 8);
    const int nbScan = ceil_div(N, SCAN_CHUNK);

    // cnt = 0, then edge MLP with fused dst-count
    hipMemsetAsync(cnt, 0, (size_t)(N + 1) * sizeof(int), stream);
    k_edge_mlp<<<gE, 256, 0, stream>>>(edge_attr, dstp, We1, be1, We2, be2, ew, cnt, E);

    // exclusive scan: cnt -> rp (cursor copy into cnt)
    k_scan_local<<<nbScan, 256, 0, stream>>>(cnt, rp, bsum, N);
    k_scan_bsum <<<1, 256, 0, stream>>>(bsum, rp, N, nbScan);
    k_scan_add  <<<gN, 256, 0, stream>>>(rp, bsum, cnt, N);

    // adjacency fill (raw ew) then degrees from rows
    k_fill   <<<gE, 256, 0, stream>>>(srcp, dstp, ew, cnt, adj, E);
    k_row_dis<<<gGe, 256, 0, stream>>>(rp, adj, dis, N);

    // layer 1
    k_gemm<false><<<gGe, 256, 0, stream>>>(x, W1, dis, Abf, N);
    k_gather     <<<gGe, 256, 0, stream>>>(rp, adj, Abf, dis, b1, B, N);
    // layer 2
    k_gemm<true> <<<gGe, 256, 0, stream>>>(B, W2, dis, Abf, N);
    k_gather     <<<gGe, 256, 0, stream>>>(rp, adj, Abf, dis, b2, B, N);
    // layer 3
    k_gemm<true> <<<gGe, 256, 0, stream>>>(B, W3, dis, Abf, N);
    k_gather     <<<gGe, 256, 0, stream>>>(rp, adj, Abf, dis, b3, B, N);

    // pool + head
    k_pool<<<128, 128, 0, stream>>>(B, part, N);
    k_head<<<1, 128, 0, stream>>>(part, Wh, bh, (float*)d_out, 1.0f / (float)N);
}

// Round 6
// 841.159 us; speedup vs baseline: 10.1278x; 1.0488x over previous
//
#include <hip/hip_runtime.h>

// GraphGCN forward. Round 5: MFMA (32x32x16 bf16) edge MLP.
// N=50000 nodes, E=1600000 edges, IN=H=128, EA=16, OUT=10.
//
// ws: ew[E] f32 | dis[N] f32 | B[N*128] f32 | Abf[N*64] u32 (bf16x2)
//     | part[128*128] f32 | cnt[N+2] i32 | rp[N+2] i32 | bsum[256] i32
//     | adj[E] int2

#define HD   128
#define EAD  16
#define OUTD 10
#define SCAN_CHUNK 2048

typedef short bf16x8 __attribute__((ext_vector_type(8)));
typedef float f32x16 __attribute__((ext_vector_type(16)));

static inline int ceil_div(long long a, long long b){ return (int)((a + b - 1) / b); }

__device__ inline unsigned f2bf(float f) {           // RNE f32 -> bf16
    unsigned u = __float_as_uint(f);
    return (u + 0x7fffu + ((u >> 16) & 1u)) >> 16;
}
__device__ inline float bf_lo(unsigned w) { return __uint_as_float(w << 16); }
__device__ inline float bf_hi(unsigned w) { return __uint_as_float(w & 0xffff0000u); }

// ---------------- edge MLP via MFMA ----------------
// hidden[32e,128] = bf16(ea)[32,16] @ bf16(We1)[16,128] (+be1), relu,
// pre[e] = hidden @ We2 + be2, ew[e] = softplus(pre). Fused cnt[dst]++.
//
// mfma_f32_32x32x16_bf16 layouts (A: M=32 x K=16, B: K=16 x N=32):
//   A: lane l holds A[l&31][4*(l>>5) + (j&3) + 8*(j>>2)], j=0..7
//   B: lane l holds B[4*(l>>5) + (j&3) + 8*(j>>2)][l&31]
//   C/D: col = lane&31, row = (reg&3) + 8*(reg>>2) + 4*(lane>>5)   [m74/m101]
__global__ __launch_bounds__(256) void k_edge_mlp(
    const float* __restrict__ edge_attr, const int* __restrict__ dst,
    const float* __restrict__ We1, const float* __restrict__ be1,
    const float* __restrict__ We2, const float* __restrict__ be2,
    float* __restrict__ ew, int* __restrict__ cnt, int E)
{
    const int lane = threadIdx.x & 63;
    const int half = lane >> 5;          // 0/1
    const int lc   = lane & 31;
    const int wid  = blockIdx.x * 4 + (threadIdx.x >> 6);
    const int nw   = gridDim.x * 4;
    const int G    = (E + 31) >> 5;      // 32-edge groups

    // ---- wave-invariant fragments ----
    bf16x8 bfr[4];
    float  we2v[4], be1v[4];
#pragma unroll
    for (int t = 0; t < 4; ++t) {
#pragma unroll
        for (int j = 0; j < 8; ++j) {
            int krow = 4 * half + (j & 3) + 8 * (j >> 2);
            bfr[t][j] = (short)f2bf(We1[krow * HD + t * 32 + lc]);
        }
        we2v[t] = We2[t * 32 + lc];
        be1v[t] = be1[t * 32 + lc];
    }
    const float be2v = be2[0];

    for (int g = wid; g < G; g += nw) {
        int eb = g << 5;
        // ---- A fragment: 32 edges x 16 attrs ----
        int edge = eb + lc;
        int eload = edge < E ? edge : E - 1;
        const float4* rowp = reinterpret_cast<const float4*>(edge_attr + (size_t)eload * EAD);
        float4 a0 = rowp[half];          // attrs 4*half .. +3
        float4 a1 = rowp[2 + half];      // attrs 8+4*half .. +3
        bf16x8 af;
        af[0] = (short)f2bf(a0.x); af[1] = (short)f2bf(a0.y);
        af[2] = (short)f2bf(a0.z); af[3] = (short)f2bf(a0.w);
        af[4] = (short)f2bf(a1.x); af[5] = (short)f2bf(a1.y);
        af[6] = (short)f2bf(a1.z); af[7] = (short)f2bf(a1.w);

        // ---- 4 MFMAs: hidden cols in 4 blocks of 32 ----
        f32x16 acc0, acc1, acc2, acc3;
#pragma unroll
        for (int i = 0; i < 16; ++i) { acc0[i]=0.f; acc1[i]=0.f; acc2[i]=0.f; acc3[i]=0.f; }
        acc0 = __builtin_amdgcn_mfma_f32_32x32x16_bf16(af, bfr[0], acc0, 0, 0, 0);
        acc1 = __builtin_amdgcn_mfma_f32_32x32x16_bf16(af, bfr[1], acc1, 0, 0, 0);
        acc2 = __builtin_amdgcn_mfma_f32_32x32x16_bf16(af, bfr[2], acc2, 0, 0, 0);
        acc3 = __builtin_amdgcn_mfma_f32_32x32x16_bf16(af, bfr[3], acc3, 0, 0, 0);

        // ---- layer 2: p[r] = sum over this lane's 4 cols of relu(h+be1)*We2 ----
        float p[16];
#pragma unroll
        for (int r = 0; r < 16; ++r) {
            float s;
            s = fmaxf(acc0[r] + be1v[0], 0.f) * we2v[0];
            s = fmaf(fmaxf(acc1[r] + be1v[1], 0.f), we2v[1], s);
            s = fmaf(fmaxf(acc2[r] + be1v[2], 0.f), we2v[2], s);
            s = fmaf(fmaxf(acc3[r] + be1v[3], 0.f), we2v[3], s);
            p[r] = s;
        }
        // ---- reduce across the 32 cols held by the 32 lanes of this half ----
#pragma unroll
        for (int r = 0; r < 16; ++r) {
#pragma unroll
            for (int off = 1; off < 32; off <<= 1)
                p[r] += __shfl_xor(p[r], off, 64);
        }
        // ---- owner lanes (lc<16) finalize one edge-row each ----
        if (lc < 16) {
            int q = lc;
            float mine = p[0];
#pragma unroll
            for (int r = 1; r < 16; ++r) mine = (q == r) ? p[r] : mine;
            int row = (q & 3) + 8 * (q >> 2) + 4 * half;
            int e2 = eb + row;
            if (e2 < E) {
                float v  = mine + be2v;
                float sp = fmaxf(v, 0.f) + log1pf(expf(-fabsf(v)));
                ew[e2] = sp;
                atomicAdd(&cnt[dst[e2]], 1);
            }
        }
    }
}

// ---------------- hierarchical exclusive scan ----------------
__global__ __launch_bounds__(256) void k_scan_local(
    const int* __restrict__ cnt, int* __restrict__ rp,
    int* __restrict__ bsum, int N)
{
    __shared__ int sh[256];
    int t = threadIdx.x;
    int base = blockIdx.x * SCAN_CHUNK + t * 8;
    int v[8];
    int s = 0;
#pragma unroll
    for (int j = 0; j < 8; ++j) {
        int idx = base + j;
        v[j] = (idx < N) ? cnt[idx] : 0;
        s += v[j];
    }
    sh[t] = s;
    __syncthreads();
    for (int off = 1; off < 256; off <<= 1) {
        int add = (t >= off) ? sh[t - off] : 0;
        __syncthreads();
        sh[t] += add;
        __syncthreads();
    }
    int run = sh[t] - s;
#pragma unroll
    for (int j = 0; j < 8; ++j) {
        int idx = base + j;
        if (idx < N) rp[idx] = run;
        run += v[j];
    }
    if (t == 255) bsum[blockIdx.x] = sh[255];
}

__global__ __launch_bounds__(256) void k_scan_bsum(
    int* __restrict__ bsum, int* __restrict__ rp, int N, int nb)
{
    __shared__ int sh[256];
    int t = threadIdx.x;
    int v = (t < nb) ? bsum[t] : 0;
    sh[t] = v;
    __syncthreads();
    for (int off = 1; off < 256; off <<= 1) {
        int add = (t >= off) ? sh[t - off] : 0;
        __syncthreads();
        sh[t] += add;
        __syncthreads();
    }
    if (t < nb) bsum[t] = sh[t] - v;
    if (t == nb - 1) rp[N] = sh[t];
}

__global__ __launch_bounds__(256) void k_scan_add(
    int* __restrict__ rp, const int* __restrict__ bsum,
    int* __restrict__ cur, int N)
{
    int i = blockIdx.x * 256 + threadIdx.x;
    if (i >= N) return;
    int r = rp[i] + bsum[i / SCAN_CHUNK];
    rp[i] = r;
    cur[i] = r;
}

// ---------------- fill adjacency with RAW ew ----------------
__global__ __launch_bounds__(256) void k_fill(
    const int* __restrict__ src, const int* __restrict__ dst,
    const float* __restrict__ ew, int* __restrict__ cur,
    int2* __restrict__ adj, int E)
{
    int e = blockIdx.x * 256 + threadIdx.x;
    if (e >= E) return;
    int d = dst[e];
    int pos = atomicAdd(&cur[d], 1);
    adj[pos] = make_int2(src[e], __float_as_int(ew[e]));
}

// ---------------- dis[n] = rsqrt(1 + sum_row ew)  (no atomics) ----------------
__global__ __launch_bounds__(256) void k_row_dis(
    const int* __restrict__ rp, const int2* __restrict__ adj,
    float* __restrict__ dis, int N)
{
    int n = blockIdx.x * 8 + (threadIdx.x >> 5);
    if (n >= N) return;
    int lane = threadIdx.x & 31;
    int beg = rp[n], end = rp[n + 1];
    float s = 0.f;
    for (int i = beg + lane; i < end; i += 32)
        s += __int_as_float(adj[i].y);
#pragma unroll
    for (int off = 16; off; off >>= 1)
        s += __shfl_xor(s, off, 32);
    if (lane == 0) dis[n] = rsqrtf(1.0f + s);
}

// ------- GEMM: Ybf[row] = bf16( dis[row] * (relu?)X[row] @ W ) ----------------
template <bool RELU_IN>
__global__ __launch_bounds__(256) void k_gemm(
    const float* __restrict__ X, const float* __restrict__ W,
    const float* __restrict__ dis, unsigned* __restrict__ Ybf, int N)
{
    __shared__ float xs[8][HD];
    int rb = blockIdx.x * 8;
    int t  = threadIdx.x;
    {
        int r  = t >> 5;
        int c4 = (t & 31) * 4;
        int row = rb + r;
        float4 v = make_float4(0.f, 0.f, 0.f, 0.f);
        if (row < N) v = *reinterpret_cast<const float4*>(X + (size_t)row * HD + c4);
        if (RELU_IN) {
            v.x = fmaxf(v.x, 0.f); v.y = fmaxf(v.y, 0.f);
            v.z = fmaxf(v.z, 0.f); v.w = fmaxf(v.w, 0.f);
        }
        *reinterpret_cast<float4*>(&xs[r][c4]) = v;
    }
    __syncthreads();
    int r  = t >> 5;
    int c4 = (t & 31) * 4;
    int row = rb + r;
    if (row >= N) return;
    float4 acc = make_float4(0.f, 0.f, 0.f, 0.f);
#pragma unroll 8
    for (int k = 0; k < HD; ++k) {
        float xv = xs[r][k];
        float4 wv = *reinterpret_cast<const float4*>(W + k * HD + c4);
        acc.x = fmaf(xv, wv.x, acc.x);
        acc.y = fmaf(xv, wv.y, acc.y);
        acc.z = fmaf(xv, wv.z, acc.z);
        acc.w = fmaf(xv, wv.w, acc.w);
    }
    float dn = dis[row];
    unsigned w0 = f2bf(acc.x * dn) | (f2bf(acc.y * dn) << 16);
    unsigned w1 = f2bf(acc.z * dn) | (f2bf(acc.w * dn) << 16);
    *reinterpret_cast<uint2*>(Ybf + (size_t)row * (HD/2) + (t & 31) * 2) = make_uint2(w0, w1);
}

// --- gather: out[n] = b + dis[n] * ( linbf[n] + sum_row ew * linbf[src] ) ------
__global__ __launch_bounds__(256) void k_gather(
    const int* __restrict__ rp, const int2* __restrict__ adj,
    const unsigned* __restrict__ linbf, const float* __restrict__ dis,
    const float* __restrict__ b, float* __restrict__ out, int N)
{
    int n = blockIdx.x * 8 + (threadIdx.x >> 5);
    if (n >= N) return;
    int lane = threadIdx.x & 31;
    uint2 sw = *reinterpret_cast<const uint2*>(linbf + (size_t)n * (HD/2) + lane * 2);
    float4 acc;
    acc.x = bf_lo(sw.x); acc.y = bf_hi(sw.x);
    acc.z = bf_lo(sw.y); acc.w = bf_hi(sw.y);
    int beg = rp[n], end = rp[n + 1];
    for (int i0 = beg; i0 < end; i0 += 32) {
        int m = end - i0; if (m > 32) m = 32;
        int2 my = make_int2(0, 0);
        if (lane < m) my = adj[i0 + lane];
        for (int j = 0; j < m; ++j) {
            int   sn = __shfl(my.x, j, 32);
            float wg = __int_as_float(__shfl(my.y, j, 32));
            uint2 v = *reinterpret_cast<const uint2*>(linbf + (size_t)sn * (HD/2) + lane * 2);
            acc.x = fmaf(wg, bf_lo(v.x), acc.x);
            acc.y = fmaf(wg, bf_hi(v.x), acc.y);
            acc.z = fmaf(wg, bf_lo(v.y), acc.z);
            acc.w = fmaf(wg, bf_hi(v.y), acc.w);
        }
    }
    float dn = dis[n];
    float4 bv = reinterpret_cast<const float4*>(b)[lane];
    float4 o;
    o.x = fmaf(dn, acc.x, bv.x);
    o.y = fmaf(dn, acc.y, bv.y);
    o.z = fmaf(dn, acc.z, bv.z);
    o.w = fmaf(dn, acc.w, bv.w);
    *(reinterpret_cast<float4*>(out + (size_t)n * HD) + lane) = o;
}

// ---------------- pool partials (relu fused), atomic-free ----------------
__global__ __launch_bounds__(128) void k_pool(
    const float* __restrict__ h, float* __restrict__ part, int N)
{
    int c = threadIdx.x;
    float acc = 0.f;
    for (int r = blockIdx.x; r < N; r += 128)
        acc += fmaxf(h[(size_t)r * HD + c], 0.f);
    part[blockIdx.x * HD + c] = acc;
}

// ---------------- head: out = (colsum(part)/N) @ Wh + bh ----------------
__global__ __launch_bounds__(128) void k_head(
    const float* __restrict__ part, const float* __restrict__ Wh,
    const float* __restrict__ bh, float* __restrict__ out, float invN)
{
    __shared__ float col[HD];
    int t = threadIdx.x;
    float s = 0.f;
    for (int k = 0; k < 128; ++k)
        s += part[k * HD + t];
    col[t] = s * invN;
    __syncthreads();
    if (t < OUTD) {
        float acc = bh[t];
        for (int k = 0; k < HD; ++k)
            acc = fmaf(col[k], Wh[k * OUTD + t], acc);
        out[t] = acc;
    }
}

extern "C" void kernel_launch(void* const* d_in, const int* in_sizes, int n_in,
                              void* d_out, int out_size, void* d_ws, size_t ws_size,
                              hipStream_t stream)
{
    const float* x         = (const float*)d_in[0];
    const int*   ei        = (const int*)  d_in[1];
    const float* edge_attr = (const float*)d_in[2];
    const float* We1       = (const float*)d_in[3];
    const float* be1       = (const float*)d_in[4];
    const float* We2       = (const float*)d_in[5];
    const float* be2       = (const float*)d_in[6];
    const float* W1        = (const float*)d_in[7];
    const float* b1        = (const float*)d_in[8];
    const float* W2        = (const float*)d_in[9];
    const float* b2        = (const float*)d_in[10];
    const float* W3        = (const float*)d_in[11];
    const float* b3        = (const float*)d_in[12];
    const float* Wh        = (const float*)d_in[13];
    const float* bh        = (const float*)d_in[14];

    const int N = in_sizes[0] / HD;
    const int E = in_sizes[2] / EAD;
    const int* srcp = ei;
    const int* dstp = ei + E;

    // workspace partition
    char* w = (char*)d_ws;
    float*    ew   = (float*)w;    w += (size_t)E * sizeof(float);
    float*    dis  = (float*)w;    w += (size_t)N * sizeof(float);
    float*    B    = (float*)w;    w += (size_t)N * HD * sizeof(float);
    unsigned* Abf  = (unsigned*)w; w += (size_t)N * (HD/2) * sizeof(unsigned);
    float*    part = (float*)w;    w += 128 * HD * sizeof(float);
    int*      cnt  = (int*)w;      w += (size_t)(N + 2) * sizeof(int);
    int*      rp   = (int*)w;      w += (size_t)(N + 2) * sizeof(int);
    int*      bsum = (int*)w;      w += 256 * sizeof(int);
    w = (char*)(((uintptr_t)w + 15) & ~(uintptr_t)15);
    int2*     adj  = (int2*)w;     w += (size_t)E * sizeof(int2);

    const int gE  = ceil_div(E, 256);
    const int gN  = ceil_div(N, 256);
    const int gGe = ceil_div(N, 8);
    const int nbScan = ceil_div(N, SCAN_CHUNK);

    // cnt = 0, then edge MLP (MFMA) with fused dst-count
    hipMemsetAsync(cnt, 0, (size_t)(N + 1) * sizeof(int), stream);
    k_edge_mlp<<<1024, 256, 0, stream>>>(edge_attr, dstp, We1, be1, We2, be2, ew, cnt, E);

    // exclusive scan: cnt -> rp (cursor copy into cnt)
    k_scan_local<<<nbScan, 256, 0, stream>>>(cnt, rp, bsum, N);
    k_scan_bsum <<<1, 256, 0, stream>>>(bsum, rp, N, nbScan);
    k_scan_add  <<<gN, 256, 0, stream>>>(rp, bsum, cnt, N);

    // adjacency fill (raw ew) then degrees from rows
    k_fill   <<<gE, 256, 0, stream>>>(srcp, dstp, ew, cnt, adj, E);
    k_row_dis<<<gGe, 256, 0, stream>>>(rp, adj, dis, N);

    // layer 1
    k_gemm<false><<<gGe, 256, 0, stream>>>(x, W1, dis, Abf, N);
    k_gather     <<<gGe, 256, 0, stream>>>(rp, adj, Abf, dis, b1, B, N);
    // layer 2
    k_gemm<true> <<<gGe, 256, 0, stream>>>(B, W2, dis, Abf, N);
    k_gather     <<<gGe, 256, 0, stream>>>(rp, adj, Abf, dis, b2, B, N);
    // layer 3
    k_gemm<true> <<<gGe, 256, 0, stream>>>(B, W3, dis, Abf, N);
    k_gather     <<<gGe, 256, 0, stream>>>(rp, adj, Abf, dis, b3, B, N);

    // pool + head
    k_pool<<<128, 128, 0, stream>>>(B, part, N);
    k_head<<<1, 128, 0, stream>>>(part, Wh, bh, (float*)d_out, 1.0f / (float)N);
}

// Round 7
// 828.503 us; speedup vs baseline: 10.2825x; 1.0153x over previous
//
#include <hip/hip_runtime.h>

// GraphGCN forward. Round 6: 4-byte packed adjacency (src:16 | f16(ew):16),
// unrolled gather inner loop. MFMA edge MLP from round 5.
// N=50000 nodes, E=1600000 edges, IN=H=128, EA=16, OUT=10.
//
// ws: ew[E] f32 | dis[N] f32 | B[N*128] f32 | Abf[N*64] u32 (bf16x2)
//     | part[128*128] f32 | cnt[N+2] i32 | rp[N+2] i32 | bsum[256] i32
//     | adj[E] u32

#define HD   128
#define EAD  16
#define OUTD 10
#define SCAN_CHUNK 2048

typedef short bf16x8 __attribute__((ext_vector_type(8)));
typedef float f32x16 __attribute__((ext_vector_type(16)));

static inline int ceil_div(long long a, long long b){ return (int)((a + b - 1) / b); }

__device__ inline unsigned f2bf(float f) {           // RNE f32 -> bf16
    unsigned u = __float_as_uint(f);
    return (u + 0x7fffu + ((u >> 16) & 1u)) >> 16;
}
__device__ inline float bf_lo(unsigned w) { return __uint_as_float(w << 16); }
__device__ inline float bf_hi(unsigned w) { return __uint_as_float(w & 0xffff0000u); }

__device__ inline unsigned short f2h(float f) {
    _Float16 h = (_Float16)f;
    return __builtin_bit_cast(unsigned short, h);
}
__device__ inline float h2f(unsigned u) {            // low 16 bits = f16
    _Float16 h = __builtin_bit_cast(_Float16, (unsigned short)(u & 0xffffu));
    return (float)h;
}

// ---------------- edge MLP via MFMA (round 5, unchanged) ----------------
__global__ __launch_bounds__(256) void k_edge_mlp(
    const float* __restrict__ edge_attr, const int* __restrict__ dst,
    const float* __restrict__ We1, const float* __restrict__ be1,
    const float* __restrict__ We2, const float* __restrict__ be2,
    float* __restrict__ ew, int* __restrict__ cnt, int E)
{
    const int lane = threadIdx.x & 63;
    const int half = lane >> 5;
    const int lc   = lane & 31;
    const int wid  = blockIdx.x * 4 + (threadIdx.x >> 6);
    const int nw   = gridDim.x * 4;
    const int G    = (E + 31) >> 5;

    bf16x8 bfr[4];
    float  we2v[4], be1v[4];
#pragma unroll
    for (int t = 0; t < 4; ++t) {
#pragma unroll
        for (int j = 0; j < 8; ++j) {
            int krow = 4 * half + (j & 3) + 8 * (j >> 2);
            bfr[t][j] = (short)f2bf(We1[krow * HD + t * 32 + lc]);
        }
        we2v[t] = We2[t * 32 + lc];
        be1v[t] = be1[t * 32 + lc];
    }
    const float be2v = be2[0];

    for (int g = wid; g < G; g += nw) {
        int eb = g << 5;
        int edge = eb + lc;
        int eload = edge < E ? edge : E - 1;
        const float4* rowp = reinterpret_cast<const float4*>(edge_attr + (size_t)eload * EAD);
        float4 a0 = rowp[half];
        float4 a1 = rowp[2 + half];
        bf16x8 af;
        af[0] = (short)f2bf(a0.x); af[1] = (short)f2bf(a0.y);
        af[2] = (short)f2bf(a0.z); af[3] = (short)f2bf(a0.w);
        af[4] = (short)f2bf(a1.x); af[5] = (short)f2bf(a1.y);
        af[6] = (short)f2bf(a1.z); af[7] = (short)f2bf(a1.w);

        f32x16 acc0, acc1, acc2, acc3;
#pragma unroll
        for (int i = 0; i < 16; ++i) { acc0[i]=0.f; acc1[i]=0.f; acc2[i]=0.f; acc3[i]=0.f; }
        acc0 = __builtin_amdgcn_mfma_f32_32x32x16_bf16(af, bfr[0], acc0, 0, 0, 0);
        acc1 = __builtin_amdgcn_mfma_f32_32x32x16_bf16(af, bfr[1], acc1, 0, 0, 0);
        acc2 = __builtin_amdgcn_mfma_f32_32x32x16_bf16(af, bfr[2], acc2, 0, 0, 0);
        acc3 = __builtin_amdgcn_mfma_f32_32x32x16_bf16(af, bfr[3], acc3, 0, 0, 0);

        float p[16];
#pragma unroll
        for (int r = 0; r < 16; ++r) {
            float s;
            s = fmaxf(acc0[r] + be1v[0], 0.f) * we2v[0];
            s = fmaf(fmaxf(acc1[r] + be1v[1], 0.f), we2v[1], s);
            s = fmaf(fmaxf(acc2[r] + be1v[2], 0.f), we2v[2], s);
            s = fmaf(fmaxf(acc3[r] + be1v[3], 0.f), we2v[3], s);
            p[r] = s;
        }
#pragma unroll
        for (int r = 0; r < 16; ++r) {
#pragma unroll
            for (int off = 1; off < 32; off <<= 1)
                p[r] += __shfl_xor(p[r], off, 64);
        }
        if (lc < 16) {
            int q = lc;
            float mine = p[0];
#pragma unroll
            for (int r = 1; r < 16; ++r) mine = (q == r) ? p[r] : mine;
            int row = (q & 3) + 8 * (q >> 2) + 4 * half;
            int e2 = eb + row;
            if (e2 < E) {
                float v  = mine + be2v;
                float sp = fmaxf(v, 0.f) + log1pf(expf(-fabsf(v)));
                ew[e2] = sp;
                atomicAdd(&cnt[dst[e2]], 1);
            }
        }
    }
}

// ---------------- hierarchical exclusive scan ----------------
__global__ __launch_bounds__(256) void k_scan_local(
    const int* __restrict__ cnt, int* __restrict__ rp,
    int* __restrict__ bsum, int N)
{
    __shared__ int sh[256];
    int t = threadIdx.x;
    int base = blockIdx.x * SCAN_CHUNK + t * 8;
    int v[8];
    int s = 0;
#pragma unroll
    for (int j = 0; j < 8; ++j) {
        int idx = base + j;
        v[j] = (idx < N) ? cnt[idx] : 0;
        s += v[j];
    }
    sh[t] = s;
    __syncthreads();
    for (int off = 1; off < 256; off <<= 1) {
        int add = (t >= off) ? sh[t - off] : 0;
        __syncthreads();
        sh[t] += add;
        __syncthreads();
    }
    int run = sh[t] - s;
#pragma unroll
    for (int j = 0; j < 8; ++j) {
        int idx = base + j;
        if (idx < N) rp[idx] = run;
        run += v[j];
    }
    if (t == 255) bsum[blockIdx.x] = sh[255];
}

__global__ __launch_bounds__(256) void k_scan_bsum(
    int* __restrict__ bsum, int* __restrict__ rp, int N, int nb)
{
    __shared__ int sh[256];
    int t = threadIdx.x;
    int v = (t < nb) ? bsum[t] : 0;
    sh[t] = v;
    __syncthreads();
    for (int off = 1; off < 256; off <<= 1) {
        int add = (t >= off) ? sh[t - off] : 0;
        __syncthreads();
        sh[t] += add;
        __syncthreads();
    }
    if (t < nb) bsum[t] = sh[t] - v;
    if (t == nb - 1) rp[N] = sh[t];
}

__global__ __launch_bounds__(256) void k_scan_add(
    int* __restrict__ rp, const int* __restrict__ bsum,
    int* __restrict__ cur, int N)
{
    int i = blockIdx.x * 256 + threadIdx.x;
    if (i >= N) return;
    int r = rp[i] + bsum[i / SCAN_CHUNK];
    rp[i] = r;
    cur[i] = r;
}

// ---------------- fill adjacency: packed (src:16 | f16(ew):16) ----------------
__global__ __launch_bounds__(256) void k_fill(
    const int* __restrict__ src, const int* __restrict__ dst,
    const float* __restrict__ ew, int* __restrict__ cur,
    unsigned* __restrict__ adj, int E)
{
    int e = blockIdx.x * 256 + threadIdx.x;
    if (e >= E) return;
    int d = dst[e];
    unsigned ent = ((unsigned)src[e] << 16) | (unsigned)f2h(ew[e]);
    int pos = atomicAdd(&cur[d], 1);
    adj[pos] = ent;
}

// ---------------- dis[n] = rsqrt(1 + sum_row ew) ----------------
__global__ __launch_bounds__(256) void k_row_dis(
    const int* __restrict__ rp, const unsigned* __restrict__ adj,
    float* __restrict__ dis, int N)
{
    int n = blockIdx.x * 8 + (threadIdx.x >> 5);
    if (n >= N) return;
    int lane = threadIdx.x & 31;
    int beg = rp[n], end = rp[n + 1];
    float s = 0.f;
    for (int i = beg + lane; i < end; i += 32)
        s += h2f(adj[i]);
#pragma unroll
    for (int off = 16; off; off >>= 1)
        s += __shfl_xor(s, off, 32);
    if (lane == 0) dis[n] = rsqrtf(1.0f + s);
}

// ------- GEMM: Ybf[row] = bf16( dis[row] * (relu?)X[row] @ W ) ----------------
template <bool RELU_IN>
__global__ __launch_bounds__(256) void k_gemm(
    const float* __restrict__ X, const float* __restrict__ W,
    const float* __restrict__ dis, unsigned* __restrict__ Ybf, int N)
{
    __shared__ float xs[8][HD];
    int rb = blockIdx.x * 8;
    int t  = threadIdx.x;
    {
        int r  = t >> 5;
        int c4 = (t & 31) * 4;
        int row = rb + r;
        float4 v = make_float4(0.f, 0.f, 0.f, 0.f);
        if (row < N) v = *reinterpret_cast<const float4*>(X + (size_t)row * HD + c4);
        if (RELU_IN) {
            v.x = fmaxf(v.x, 0.f); v.y = fmaxf(v.y, 0.f);
            v.z = fmaxf(v.z, 0.f); v.w = fmaxf(v.w, 0.f);
        }
        *reinterpret_cast<float4*>(&xs[r][c4]) = v;
    }
    __syncthreads();
    int r  = t >> 5;
    int c4 = (t & 31) * 4;
    int row = rb + r;
    if (row >= N) return;
    float4 acc = make_float4(0.f, 0.f, 0.f, 0.f);
#pragma unroll 8
    for (int k = 0; k < HD; ++k) {
        float xv = xs[r][k];
        float4 wv = *reinterpret_cast<const float4*>(W + k * HD + c4);
        acc.x = fmaf(xv, wv.x, acc.x);
        acc.y = fmaf(xv, wv.y, acc.y);
        acc.z = fmaf(xv, wv.z, acc.z);
        acc.w = fmaf(xv, wv.w, acc.w);
    }
    float dn = dis[row];
    unsigned w0 = f2bf(acc.x * dn) | (f2bf(acc.y * dn) << 16);
    unsigned w1 = f2bf(acc.z * dn) | (f2bf(acc.w * dn) << 16);
    *reinterpret_cast<uint2*>(Ybf + (size_t)row * (HD/2) + (t & 31) * 2) = make_uint2(w0, w1);
}

// --- gather: out[n] = b + dis[n] * ( linbf[n] + sum_row ew * linbf[src] ) ------
__global__ __launch_bounds__(256) void k_gather(
    const int* __restrict__ rp, const unsigned* __restrict__ adj,
    const unsigned* __restrict__ linbf, const float* __restrict__ dis,
    const float* __restrict__ b, float* __restrict__ out, int N)
{
    int n = blockIdx.x * 8 + (threadIdx.x >> 5);
    if (n >= N) return;
    int lane = threadIdx.x & 31;
    uint2 sw = *reinterpret_cast<const uint2*>(linbf + (size_t)n * (HD/2) + lane * 2);
    float4 acc;
    acc.x = bf_lo(sw.x); acc.y = bf_hi(sw.x);
    acc.z = bf_lo(sw.y); acc.w = bf_hi(sw.y);
    int beg = rp[n], end = rp[n + 1];
    for (int i0 = beg; i0 < end; i0 += 32) {
        int m = end - i0; if (m > 32) m = 32;
        unsigned a = 0;
        if (lane < m) a = adj[i0 + lane];
        int j = 0;
        for (; j + 4 <= m; j += 4) {
            unsigned e0 = __shfl(a, j,     32);
            unsigned e1 = __shfl(a, j + 1, 32);
            unsigned e2 = __shfl(a, j + 2, 32);
            unsigned e3 = __shfl(a, j + 3, 32);
            // issue 4 independent random row reads before consuming
            uint2 v0 = *reinterpret_cast<const uint2*>(linbf + (size_t)(e0 >> 16) * (HD/2) + lane * 2);
            uint2 v1 = *reinterpret_cast<const uint2*>(linbf + (size_t)(e1 >> 16) * (HD/2) + lane * 2);
            uint2 v2 = *reinterpret_cast<const uint2*>(linbf + (size_t)(e2 >> 16) * (HD/2) + lane * 2);
            uint2 v3 = *reinterpret_cast<const uint2*>(linbf + (size_t)(e3 >> 16) * (HD/2) + lane * 2);
            float w0 = h2f(e0), w1 = h2f(e1), w2 = h2f(e2), w3 = h2f(e3);
            acc.x = fmaf(w0, bf_lo(v0.x), acc.x);
            acc.y = fmaf(w0, bf_hi(v0.x), acc.y);
            acc.z = fmaf(w0, bf_lo(v0.y), acc.z);
            acc.w = fmaf(w0, bf_hi(v0.y), acc.w);
            acc.x = fmaf(w1, bf_lo(v1.x), acc.x);
            acc.y = fmaf(w1, bf_hi(v1.x), acc.y);
            acc.z = fmaf(w1, bf_lo(v1.y), acc.z);
            acc.w = fmaf(w1, bf_hi(v1.y), acc.w);
            acc.x = fmaf(w2, bf_lo(v2.x), acc.x);
            acc.y = fmaf(w2, bf_hi(v2.x), acc.y);
            acc.z = fmaf(w2, bf_lo(v2.y), acc.z);
            acc.w = fmaf(w2, bf_hi(v2.y), acc.w);
            acc.x = fmaf(w3, bf_lo(v3.x), acc.x);
            acc.y = fmaf(w3, bf_hi(v3.x), acc.y);
            acc.z = fmaf(w3, bf_lo(v3.y), acc.z);
            acc.w = fmaf(w3, bf_hi(v3.y), acc.w);
        }
        for (; j < m; ++j) {
            unsigned e0 = __shfl(a, j, 32);
            uint2 v0 = *reinterpret_cast<const uint2*>(linbf + (size_t)(e0 >> 16) * (HD/2) + lane * 2);
            float w0 = h2f(e0);
            acc.x = fmaf(w0, bf_lo(v0.x), acc.x);
            acc.y = fmaf(w0, bf_hi(v0.x), acc.y);
            acc.z = fmaf(w0, bf_lo(v0.y), acc.z);
            acc.w = fmaf(w0, bf_hi(v0.y), acc.w);
        }
    }
    float dn = dis[n];
    float4 bv = reinterpret_cast<const float4*>(b)[lane];
    float4 o;
    o.x = fmaf(dn, acc.x, bv.x);
    o.y = fmaf(dn, acc.y, bv.y);
    o.z = fmaf(dn, acc.z, bv.z);
    o.w = fmaf(dn, acc.w, bv.w);
    *(reinterpret_cast<float4*>(out + (size_t)n * HD) + lane) = o;
}

// ---------------- pool partials (relu fused), atomic-free ----------------
__global__ __launch_bounds__(128) void k_pool(
    const float* __restrict__ h, float* __restrict__ part, int N)
{
    int c = threadIdx.x;
    float acc = 0.f;
    for (int r = blockIdx.x; r < N; r += 128)
        acc += fmaxf(h[(size_t)r * HD + c], 0.f);
    part[blockIdx.x * HD + c] = acc;
}

// ---------------- head: out = (colsum(part)/N) @ Wh + bh ----------------
__global__ __launch_bounds__(128) void k_head(
    const float* __restrict__ part, const float* __restrict__ Wh,
    const float* __restrict__ bh, float* __restrict__ out, float invN)
{
    __shared__ float col[HD];
    int t = threadIdx.x;
    float s = 0.f;
    for (int k = 0; k < 128; ++k)
        s += part[k * HD + t];
    col[t] = s * invN;
    __syncthreads();
    if (t < OUTD) {
        float acc = bh[t];
        for (int k = 0; k < HD; ++k)
            acc = fmaf(col[k], Wh[k * OUTD + t], acc);
        out[t] = acc;
    }
}

extern "C" void kernel_launch(void* const* d_in, const int* in_sizes, int n_in,
                              void* d_out, int out_size, void* d_ws, size_t ws_size,
                              hipStream_t stream)
{
    const float* x         = (const float*)d_in[0];
    const int*   ei        = (const int*)  d_in[1];
    const float* edge_attr = (const float*)d_in[2];
    const float* We1       = (const float*)d_in[3];
    const float* be1       = (const float*)d_in[4];
    const float* We2       = (const float*)d_in[5];
    const float* be2       = (const float*)d_in[6];
    const float* W1        = (const float*)d_in[7];
    const float* b1        = (const float*)d_in[8];
    const float* W2        = (const float*)d_in[9];
    const float* b2        = (const float*)d_in[10];
    const float* W3        = (const float*)d_in[11];
    const float* b3        = (const float*)d_in[12];
    const float* Wh        = (const float*)d_in[13];
    const float* bh        = (const float*)d_in[14];

    const int N = in_sizes[0] / HD;
    const int E = in_sizes[2] / EAD;
    const int* srcp = ei;
    const int* dstp = ei + E;

    // workspace partition
    char* w = (char*)d_ws;
    float*    ew   = (float*)w;    w += (size_t)E * sizeof(float);
    float*    dis  = (float*)w;    w += (size_t)N * sizeof(float);
    float*    B    = (float*)w;    w += (size_t)N * HD * sizeof(float);
    unsigned* Abf  = (unsigned*)w; w += (size_t)N * (HD/2) * sizeof(unsigned);
    float*    part = (float*)w;    w += 128 * HD * sizeof(float);
    int*      cnt  = (int*)w;      w += (size_t)(N + 2) * sizeof(int);
    int*      rp   = (int*)w;      w += (size_t)(N + 2) * sizeof(int);
    int*      bsum = (int*)w;      w += 256 * sizeof(int);
    w = (char*)(((uintptr_t)w + 15) & ~(uintptr_t)15);
    unsigned* adj  = (unsigned*)w; w += (size_t)E * sizeof(unsigned);

    const int gE  = ceil_div(E, 256);
    const int gN  = ceil_div(N, 256);
    const int gGe = ceil_div(N, 8);
    const int nbScan = ceil_div(N, SCAN_CHUNK);

    // cnt = 0, then edge MLP (MFMA) with fused dst-count
    hipMemsetAsync(cnt, 0, (size_t)(N + 1) * sizeof(int), stream);
    k_edge_mlp<<<1024, 256, 0, stream>>>(edge_attr, dstp, We1, be1, We2, be2, ew, cnt, E);

    // exclusive scan: cnt -> rp (cursor copy into cnt)
    k_scan_local<<<nbScan, 256, 0, stream>>>(cnt, rp, bsum, N);
    k_scan_bsum <<<1, 256, 0, stream>>>(bsum, rp, N, nbScan);
    k_scan_add  <<<gN, 256, 0, stream>>>(rp, bsum, cnt, N);

    // adjacency fill (packed) then degrees from rows
    k_fill   <<<gE, 256, 0, stream>>>(srcp, dstp, ew, cnt, adj, E);
    k_row_dis<<<gGe, 256, 0, stream>>>(rp, adj, dis, N);

    // layer 1
    k_gemm<false><<<gGe, 256, 0, stream>>>(x, W1, dis, Abf, N);
    k_gather     <<<gGe, 256, 0, stream>>>(rp, adj, Abf, dis, b1, B, N);
    // layer 2
    k_gemm<true> <<<gGe, 256, 0, stream>>>(B, W2, dis, Abf, N);
    k_gather     <<<gGe, 256, 0, stream>>>(rp, adj, Abf, dis, b2, B, N);
    // layer 3
    k_gemm<true> <<<gGe, 256, 0, stream>>>(B, W3, dis, Abf, N);
    k_gather     <<<gGe, 256, 0, stream>>>(rp, adj, Abf, dis, b3, B, N);

    // pool + head
    k_pool<<<128, 128, 0, stream>>>(B, part, N);
    k_head<<<1, 128, 0, stream>>>(part, Wh, bh, (float*)d_out, 1.0f / (float)N);
}

// Round 8
// 730.866 us; speedup vs baseline: 11.6561x; 1.1336x over previous
//
#include <hip/hip_runtime.h>

// GraphGCN forward. Round 7: atomic-free CSR build via 2-level counting sort
// (coarse 256-node buckets -> per-bucket LDS sort). No per-edge global atomics
// anywhere. MFMA edge MLP, bf16 gather rows, packed 4B adjacency.
// N=50000 nodes, E=1600000 edges, IN=H=128, EA=16, OUT=10.
//
// ws: ew[E] f32 | dis[N] f32 | B[N*128] f32 | Abf[N*64] u32 | part[128*128] f32
//     | rp[N+2] i32 | batom[256] i32 | boff[257] i32 | bcur[256] i32
//     | bbuf[E] uint2 | adj[E] u32        (~65 MB)

#define HD   128
#define EAD  16
#define OUTD 10
#define PCHUNK 4096            // edges per k_part / k_bcount block

typedef short bf16x8 __attribute__((ext_vector_type(8)));
typedef float f32x16 __attribute__((ext_vector_type(16)));

static inline int ceil_div(long long a, long long b){ return (int)((a + b - 1) / b); }

__device__ inline unsigned f2bf(float f) {           // RNE f32 -> bf16
    unsigned u = __float_as_uint(f);
    return (u + 0x7fffu + ((u >> 16) & 1u)) >> 16;
}
__device__ inline float bf_lo(unsigned w) { return __uint_as_float(w << 16); }
__device__ inline float bf_hi(unsigned w) { return __uint_as_float(w & 0xffff0000u); }

__device__ inline unsigned short f2h(float f) {
    _Float16 h = (_Float16)f;
    return __builtin_bit_cast(unsigned short, h);
}
__device__ inline float h2f(unsigned u) {            // low 16 bits = f16
    _Float16 h = __builtin_bit_cast(_Float16, (unsigned short)(u & 0xffffu));
    return (float)h;
}

// ---------------- edge MLP via MFMA (no atomics) ----------------
__global__ __launch_bounds__(256) void k_edge_mlp(
    const float* __restrict__ edge_attr,
    const float* __restrict__ We1, const float* __restrict__ be1,
    const float* __restrict__ We2, const float* __restrict__ be2,
    float* __restrict__ ew, int E)
{
    const int lane = threadIdx.x & 63;
    const int half = lane >> 5;
    const int lc   = lane & 31;
    const int wid  = blockIdx.x * 4 + (threadIdx.x >> 6);
    const int nw   = gridDim.x * 4;
    const int G    = (E + 31) >> 5;

    bf16x8 bfr[4];
    float  we2v[4], be1v[4];
#pragma unroll
    for (int t = 0; t < 4; ++t) {
#pragma unroll
        for (int j = 0; j < 8; ++j) {
            int krow = 4 * half + (j & 3) + 8 * (j >> 2);
            bfr[t][j] = (short)f2bf(We1[krow * HD + t * 32 + lc]);
        }
        we2v[t] = We2[t * 32 + lc];
        be1v[t] = be1[t * 32 + lc];
    }
    const float be2v = be2[0];

    for (int g = wid; g < G; g += nw) {
        int eb = g << 5;
        int edge = eb + lc;
        int eload = edge < E ? edge : E - 1;
        const float4* rowp = reinterpret_cast<const float4*>(edge_attr + (size_t)eload * EAD);
        float4 a0 = rowp[half];
        float4 a1 = rowp[2 + half];
        bf16x8 af;
        af[0] = (short)f2bf(a0.x); af[1] = (short)f2bf(a0.y);
        af[2] = (short)f2bf(a0.z); af[3] = (short)f2bf(a0.w);
        af[4] = (short)f2bf(a1.x); af[5] = (short)f2bf(a1.y);
        af[6] = (short)f2bf(a1.z); af[7] = (short)f2bf(a1.w);

        f32x16 acc0, acc1, acc2, acc3;
#pragma unroll
        for (int i = 0; i < 16; ++i) { acc0[i]=0.f; acc1[i]=0.f; acc2[i]=0.f; acc3[i]=0.f; }
        acc0 = __builtin_amdgcn_mfma_f32_32x32x16_bf16(af, bfr[0], acc0, 0, 0, 0);
        acc1 = __builtin_amdgcn_mfma_f32_32x32x16_bf16(af, bfr[1], acc1, 0, 0, 0);
        acc2 = __builtin_amdgcn_mfma_f32_32x32x16_bf16(af, bfr[2], acc2, 0, 0, 0);
        acc3 = __builtin_amdgcn_mfma_f32_32x32x16_bf16(af, bfr[3], acc3, 0, 0, 0);

        float p[16];
#pragma unroll
        for (int r = 0; r < 16; ++r) {
            float s;
            s = fmaxf(acc0[r] + be1v[0], 0.f) * we2v[0];
            s = fmaf(fmaxf(acc1[r] + be1v[1], 0.f), we2v[1], s);
            s = fmaf(fmaxf(acc2[r] + be1v[2], 0.f), we2v[2], s);
            s = fmaf(fmaxf(acc3[r] + be1v[3], 0.f), we2v[3], s);
            p[r] = s;
        }
#pragma unroll
        for (int r = 0; r < 16; ++r) {
#pragma unroll
            for (int off = 1; off < 32; off <<= 1)
                p[r] += __shfl_xor(p[r], off, 64);
        }
        if (lc < 16) {
            int q = lc;
            float mine = p[0];
#pragma unroll
            for (int r = 1; r < 16; ++r) mine = (q == r) ? p[r] : mine;
            int row = (q & 3) + 8 * (q >> 2) + 4 * half;
            int e2 = eb + row;
            if (e2 < E) {
                float v  = mine + be2v;
                ew[e2] = fmaxf(v, 0.f) + log1pf(expf(-fabsf(v)));
            }
        }
    }
}

// ---------------- coarse bucket count (bucket = dst >> 8) ----------------
__global__ __launch_bounds__(256) void k_bcount(
    const int* __restrict__ dst, int* __restrict__ batom, int E, int NB)
{
    __shared__ int hist[256];
    int t = threadIdx.x;
    hist[t] = 0;
    __syncthreads();
    int base = blockIdx.x * PCHUNK;
#pragma unroll
    for (int k = 0; k < PCHUNK / 256; ++k) {
        int e = base + k * 256 + t;
        if (e < E) atomicAdd(&hist[dst[e] >> 8], 1);
    }
    __syncthreads();
    if (t < NB && hist[t]) atomicAdd(&batom[t], hist[t]);
}

// ---------------- scan bucket counts -> boff (exclusive), bcur copy -----------
__global__ __launch_bounds__(256) void k_bscan(
    const int* __restrict__ batom, int* __restrict__ boff,
    int* __restrict__ bcur, int NB)
{
    __shared__ int sh[256];
    int t = threadIdx.x;
    int v = (t < NB) ? batom[t] : 0;
    sh[t] = v;
    __syncthreads();
    for (int off = 1; off < 256; off <<= 1) {
        int add = (t >= off) ? sh[t - off] : 0;
        __syncthreads();
        sh[t] += add;
        __syncthreads();
    }
    if (t < NB) { boff[t] = sh[t] - v; bcur[t] = sh[t] - v; }
    if (t == NB - 1) boff[NB] = sh[t];
}

// ---------------- partition edges into coarse buckets ----------------
// entry: x = (src<<16) | f16(ew), y = dst & 255
__global__ __launch_bounds__(256) void k_part(
    const int* __restrict__ src, const int* __restrict__ dst,
    const float* __restrict__ ew, int* __restrict__ bcur,
    uint2* __restrict__ bbuf, int E, int NB)
{
    __shared__ int hist[256];
    __shared__ int base[256];
    __shared__ int cur[256];
    int t = threadIdx.x;
    hist[t] = 0; cur[t] = 0;
    __syncthreads();
    int eb = blockIdx.x * PCHUNK;
#pragma unroll
    for (int k = 0; k < PCHUNK / 256; ++k) {
        int e = eb + k * 256 + t;
        if (e < E) atomicAdd(&hist[dst[e] >> 8], 1);
    }
    __syncthreads();
    if (t < NB && hist[t]) base[t] = atomicAdd(&bcur[t], hist[t]);
    __syncthreads();
#pragma unroll
    for (int k = 0; k < PCHUNK / 256; ++k) {
        int e = eb + k * 256 + t;
        if (e >= E) continue;
        int d = dst[e];
        int bkt = d >> 8;
        int pos = base[bkt] + atomicAdd(&cur[bkt], 1);
        bbuf[pos] = make_uint2(((unsigned)src[e] << 16) | f2h(ew[e]),
                               (unsigned)(d & 255));
    }
}

// ---------------- per-bucket counting sort: rp, dis, adj ----------------
__global__ __launch_bounds__(256) void k_bucket(
    const int* __restrict__ boff, const uint2* __restrict__ bbuf,
    int* __restrict__ rp, float* __restrict__ dis,
    unsigned* __restrict__ adj, int N, int E, int NB)
{
    __shared__ int   hcnt[256];
    __shared__ int   hexc[256];
    __shared__ int   cur[256];
    __shared__ float degs[256];
    int b = blockIdx.x;
    int t = threadIdx.x;
    hcnt[t] = 0; cur[t] = 0; degs[t] = 0.f;
    __syncthreads();
    int beg = boff[b], end = boff[b + 1];
    // pass 1: per-node counts + degree sums
    for (int i = beg + t; i < end; i += 256) {
        uint2 ent = bbuf[i];
        int dl = (int)ent.y;
        atomicAdd(&hcnt[dl], 1);
        atomicAdd(&degs[dl], h2f(ent.x));
    }
    __syncthreads();
    // scan hcnt -> hexc (exclusive)
    {
        int v = hcnt[t];
        hexc[t] = v;
        __syncthreads();
        for (int off = 1; off < 256; off <<= 1) {
            int add = (t >= off) ? hexc[t - off] : 0;
            __syncthreads();
            hexc[t] += add;
            __syncthreads();
        }
        hexc[t] -= v;
    }
    // write rp & dis
    int n = (b << 8) + t;
    if (n < N) {
        rp[n]  = beg + hexc[t];
        dis[n] = rsqrtf(fmaxf(1.0f + degs[t], 1e-12f));
    }
    if (b == NB - 1 && t == 0) rp[N] = E;
    __syncthreads();
    // pass 2: place entries (node-sorted within bucket)
    for (int i = beg + t; i < end; i += 256) {
        uint2 ent = bbuf[i];
        int dl = (int)ent.y;
        int pos = beg + hexc[dl] + atomicAdd(&cur[dl], 1);
        adj[pos] = ent.x;
    }
}

// ------- GEMM: Ybf[row] = bf16( dis[row] * (relu?)X[row] @ W ) ----------------
template <bool RELU_IN>
__global__ __launch_bounds__(256) void k_gemm(
    const float* __restrict__ X, const float* __restrict__ W,
    const float* __restrict__ dis, unsigned* __restrict__ Ybf, int N)
{
    __shared__ float xs[8][HD];
    int rb = blockIdx.x * 8;
    int t  = threadIdx.x;
    {
        int r  = t >> 5;
        int c4 = (t & 31) * 4;
        int row = rb + r;
        float4 v = make_float4(0.f, 0.f, 0.f, 0.f);
        if (row < N) v = *reinterpret_cast<const float4*>(X + (size_t)row * HD + c4);
        if (RELU_IN) {
            v.x = fmaxf(v.x, 0.f); v.y = fmaxf(v.y, 0.f);
            v.z = fmaxf(v.z, 0.f); v.w = fmaxf(v.w, 0.f);
        }
        *reinterpret_cast<float4*>(&xs[r][c4]) = v;
    }
    __syncthreads();
    int r  = t >> 5;
    int c4 = (t & 31) * 4;
    int row = rb + r;
    if (row >= N) return;
    float4 acc = make_float4(0.f, 0.f, 0.f, 0.f);
#pragma unroll 8
    for (int k = 0; k < HD; ++k) {
        float xv = xs[r][k];
        float4 wv = *reinterpret_cast<const float4*>(W + k * HD + c4);
        acc.x = fmaf(xv, wv.x, acc.x);
        acc.y = fmaf(xv, wv.y, acc.y);
        acc.z = fmaf(xv, wv.z, acc.z);
        acc.w = fmaf(xv, wv.w, acc.w);
    }
    float dn = dis[row];
    unsigned w0 = f2bf(acc.x * dn) | (f2bf(acc.y * dn) << 16);
    unsigned w1 = f2bf(acc.z * dn) | (f2bf(acc.w * dn) << 16);
    *reinterpret_cast<uint2*>(Ybf + (size_t)row * (HD/2) + (t & 31) * 2) = make_uint2(w0, w1);
}

// --- gather: out[n] = b + dis[n] * ( linbf[n] + sum_row ew * linbf[src] ) ------
__global__ __launch_bounds__(256) void k_gather(
    const int* __restrict__ rp, const unsigned* __restrict__ adj,
    const unsigned* __restrict__ linbf, const float* __restrict__ dis,
    const float* __restrict__ b, float* __restrict__ out, int N)
{
    int n = blockIdx.x * 8 + (threadIdx.x >> 5);
    if (n >= N) return;
    int lane = threadIdx.x & 31;
    uint2 sw = *reinterpret_cast<const uint2*>(linbf + (size_t)n * (HD/2) + lane * 2);
    float4 acc;
    acc.x = bf_lo(sw.x); acc.y = bf_hi(sw.x);
    acc.z = bf_lo(sw.y); acc.w = bf_hi(sw.y);
    int beg = rp[n], end = rp[n + 1];
    for (int i0 = beg; i0 < end; i0 += 32) {
        int m = end - i0; if (m > 32) m = 32;
        unsigned a = 0;
        if (lane < m) a = adj[i0 + lane];
        int j = 0;
        for (; j + 4 <= m; j += 4) {
            unsigned e0 = __shfl(a, j,     32);
            unsigned e1 = __shfl(a, j + 1, 32);
            unsigned e2 = __shfl(a, j + 2, 32);
            unsigned e3 = __shfl(a, j + 3, 32);
            uint2 v0 = *reinterpret_cast<const uint2*>(linbf + (size_t)(e0 >> 16) * (HD/2) + lane * 2);
            uint2 v1 = *reinterpret_cast<const uint2*>(linbf + (size_t)(e1 >> 16) * (HD/2) + lane * 2);
            uint2 v2 = *reinterpret_cast<const uint2*>(linbf + (size_t)(e2 >> 16) * (HD/2) + lane * 2);
            uint2 v3 = *reinterpret_cast<const uint2*>(linbf + (size_t)(e3 >> 16) * (HD/2) + lane * 2);
            float w0 = h2f(e0), w1 = h2f(e1), w2 = h2f(e2), w3 = h2f(e3);
            acc.x = fmaf(w0, bf_lo(v0.x), acc.x);
            acc.y = fmaf(w0, bf_hi(v0.x), acc.y);
            acc.z = fmaf(w0, bf_lo(v0.y), acc.z);
            acc.w = fmaf(w0, bf_hi(v0.y), acc.w);
            acc.x = fmaf(w1, bf_lo(v1.x), acc.x);
            acc.y = fmaf(w1, bf_hi(v1.x), acc.y);
            acc.z = fmaf(w1, bf_lo(v1.y), acc.z);
            acc.w = fmaf(w1, bf_hi(v1.y), acc.w);
            acc.x = fmaf(w2, bf_lo(v2.x), acc.x);
            acc.y = fmaf(w2, bf_hi(v2.x), acc.y);
            acc.z = fmaf(w2, bf_lo(v2.y), acc.z);
            acc.w = fmaf(w2, bf_hi(v2.y), acc.w);
            acc.x = fmaf(w3, bf_lo(v3.x), acc.x);
            acc.y = fmaf(w3, bf_hi(v3.x), acc.y);
            acc.z = fmaf(w3, bf_lo(v3.y), acc.z);
            acc.w = fmaf(w3, bf_hi(v3.y), acc.w);
        }
        for (; j < m; ++j) {
            unsigned e0 = __shfl(a, j, 32);
            uint2 v0 = *reinterpret_cast<const uint2*>(linbf + (size_t)(e0 >> 16) * (HD/2) + lane * 2);
            float w0 = h2f(e0);
            acc.x = fmaf(w0, bf_lo(v0.x), acc.x);
            acc.y = fmaf(w0, bf_hi(v0.x), acc.y);
            acc.z = fmaf(w0, bf_lo(v0.y), acc.z);
            acc.w = fmaf(w0, bf_hi(v0.y), acc.w);
        }
    }
    float dn = dis[n];
    float4 bv = reinterpret_cast<const float4*>(b)[lane];
    float4 o;
    o.x = fmaf(dn, acc.x, bv.x);
    o.y = fmaf(dn, acc.y, bv.y);
    o.z = fmaf(dn, acc.z, bv.z);
    o.w = fmaf(dn, acc.w, bv.w);
    *(reinterpret_cast<float4*>(out + (size_t)n * HD) + lane) = o;
}

// ---------------- pool partials (relu fused), atomic-free ----------------
__global__ __launch_bounds__(128) void k_pool(
    const float* __restrict__ h, float* __restrict__ part, int N)
{
    int c = threadIdx.x;
    float acc = 0.f;
    for (int r = blockIdx.x; r < N; r += 128)
        acc += fmaxf(h[(size_t)r * HD + c], 0.f);
    part[blockIdx.x * HD + c] = acc;
}

// ---------------- head: out = (colsum(part)/N) @ Wh + bh ----------------
__global__ __launch_bounds__(128) void k_head(
    const float* __restrict__ part, const float* __restrict__ Wh,
    const float* __restrict__ bh, float* __restrict__ out, float invN)
{
    __shared__ float col[HD];
    int t = threadIdx.x;
    float s = 0.f;
    for (int k = 0; k < 128; ++k)
        s += part[k * HD + t];
    col[t] = s * invN;
    __syncthreads();
    if (t < OUTD) {
        float acc = bh[t];
        for (int k = 0; k < HD; ++k)
            acc = fmaf(col[k], Wh[k * OUTD + t], acc);
        out[t] = acc;
    }
}

extern "C" void kernel_launch(void* const* d_in, const int* in_sizes, int n_in,
                              void* d_out, int out_size, void* d_ws, size_t ws_size,
                              hipStream_t stream)
{
    const float* x         = (const float*)d_in[0];
    const int*   ei        = (const int*)  d_in[1];
    const float* edge_attr = (const float*)d_in[2];
    const float* We1       = (const float*)d_in[3];
    const float* be1       = (const float*)d_in[4];
    const float* We2       = (const float*)d_in[5];
    const float* be2       = (const float*)d_in[6];
    const float* W1        = (const float*)d_in[7];
    const float* b1        = (const float*)d_in[8];
    const float* W2        = (const float*)d_in[9];
    const float* b2        = (const float*)d_in[10];
    const float* W3        = (const float*)d_in[11];
    const float* b3        = (const float*)d_in[12];
    const float* Wh        = (const float*)d_in[13];
    const float* bh        = (const float*)d_in[14];

    const int N = in_sizes[0] / HD;
    const int E = in_sizes[2] / EAD;
    const int NB = (N + 255) >> 8;            // coarse buckets (196 for 50k)
    const int* srcp = ei;
    const int* dstp = ei + E;

    // workspace partition
    char* w = (char*)d_ws;
    float*    ew   = (float*)w;    w += (size_t)E * sizeof(float);
    float*    dis  = (float*)w;    w += (size_t)N * sizeof(float);
    float*    B    = (float*)w;    w += (size_t)N * HD * sizeof(float);
    unsigned* Abf  = (unsigned*)w; w += (size_t)N * (HD/2) * sizeof(unsigned);
    float*    part = (float*)w;    w += 128 * HD * sizeof(float);
    int*      rp   = (int*)w;      w += (size_t)(N + 2) * sizeof(int);
    int*      batom= (int*)w;      w += 256 * sizeof(int);
    int*      boff = (int*)w;      w += 260 * sizeof(int);
    int*      bcur = (int*)w;      w += 256 * sizeof(int);
    w = (char*)(((uintptr_t)w + 15) & ~(uintptr_t)15);
    uint2*    bbuf = (uint2*)w;    w += (size_t)E * sizeof(uint2);
    unsigned* adj  = (unsigned*)w; w += (size_t)E * sizeof(unsigned);

    const int gGe   = ceil_div(N, 8);
    const int gPart = ceil_div(E, PCHUNK);

    // edge weights (MFMA MLP, atomic-free)
    k_edge_mlp<<<1024, 256, 0, stream>>>(edge_attr, We1, be1, We2, be2, ew, E);

    // CSR build: bucket count -> scan -> partition -> per-bucket sort
    hipMemsetAsync(batom, 0, 256 * sizeof(int), stream);
    k_bcount<<<gPart, 256, 0, stream>>>(dstp, batom, E, NB);
    k_bscan <<<1, 256, 0, stream>>>(batom, boff, bcur, NB);
    k_part  <<<gPart, 256, 0, stream>>>(srcp, dstp, ew, bcur, bbuf, E, NB);
    k_bucket<<<NB, 256, 0, stream>>>(boff, bbuf, rp, dis, adj, N, E, NB);

    // layer 1
    k_gemm<false><<<gGe, 256, 0, stream>>>(x, W1, dis, Abf, N);
    k_gather     <<<gGe, 256, 0, stream>>>(rp, adj, Abf, dis, b1, B, N);
    // layer 2
    k_gemm<true> <<<gGe, 256, 0, stream>>>(B, W2, dis, Abf, N);
    k_gather     <<<gGe, 256, 0, stream>>>(rp, adj, Abf, dis, b2, B, N);
    // layer 3
    k_gemm<true> <<<gGe, 256, 0, stream>>>(B, W3, dis, Abf, N);
    k_gather     <<<gGe, 256, 0, stream>>>(rp, adj, Abf, dis, b3, B, N);

    // pool + head
    k_pool<<<128, 128, 0, stream>>>(B, part, N);
    k_head<<<1, 128, 0, stream>>>(part, Wh, bh, (float*)d_out, 1.0f / (float)N);
}

// Round 9
// 492.489 us; speedup vs baseline: 17.2980x; 1.4840x over previous
//
#include <hip/hip_runtime.h>

// GraphGCN forward. Round 8: MFMA bf16 GEMMs (W^T staged in LDS), bf16 h-buffer
// end-to-end, atomic-free CSR build (2-level counting sort), MFMA edge MLP.
// N=50000 nodes, E=1600000 edges, IN=H=128, EA=16, OUT=10.
//
// ws: ew[E] f32 | dis[N] f32 | Bbf[N*128] u16 | Abf[N*64] u32 | part[128*128] f32
//     | rp[N+2] i32 | batom[256] i32 | boff[257] i32 | bcur[256] i32
//     | bbuf[E] uint2 | adj[E] u32

#define HD   128
#define EAD  16
#define OUTD 10
#define PCHUNK 4096

typedef short bf16x8 __attribute__((ext_vector_type(8)));
typedef float f32x16 __attribute__((ext_vector_type(16)));

static inline int ceil_div(long long a, long long b){ return (int)((a + b - 1) / b); }

__device__ inline unsigned f2bf(float f) {           // RNE f32 -> bf16
    unsigned u = __float_as_uint(f);
    return (u + 0x7fffu + ((u >> 16) & 1u)) >> 16;
}
__device__ inline float bf_lo(unsigned w) { return __uint_as_float(w << 16); }
__device__ inline float bf_hi(unsigned w) { return __uint_as_float(w & 0xffff0000u); }
__device__ inline float bf1(unsigned short u) { return __uint_as_float(((unsigned)u) << 16); }

__device__ inline unsigned short f2h(float f) {
    _Float16 h = (_Float16)f;
    return __builtin_bit_cast(unsigned short, h);
}
__device__ inline float h2f(unsigned u) {            // low 16 bits = f16
    _Float16 h = __builtin_bit_cast(_Float16, (unsigned short)(u & 0xffffu));
    return (float)h;
}
__device__ inline unsigned cvtpk(float lo, float hi) {   // 2xf32 -> packed bf16
    unsigned r;
    asm volatile("v_cvt_pk_bf16_f32 %0, %1, %2" : "=v"(r) : "v"(lo), "v"(hi));
    return r;
}
__device__ inline unsigned relu_pk(unsigned w) {     // relu on packed 2xbf16
    return w & ~(((w >> 15) & 0x10001u) * 0xFFFFu);
}

// ---------------- edge MLP via MFMA (no atomics) ----------------
__global__ __launch_bounds__(256) void k_edge_mlp(
    const float* __restrict__ edge_attr,
    const float* __restrict__ We1, const float* __restrict__ be1,
    const float* __restrict__ We2, const float* __restrict__ be2,
    float* __restrict__ ew, int E)
{
    const int lane = threadIdx.x & 63;
    const int half = lane >> 5;
    const int lc   = lane & 31;
    const int wid  = blockIdx.x * 4 + (threadIdx.x >> 6);
    const int nw   = gridDim.x * 4;
    const int G    = (E + 31) >> 5;

    bf16x8 bfr[4];
    float  we2v[4], be1v[4];
#pragma unroll
    for (int t = 0; t < 4; ++t) {
#pragma unroll
        for (int j = 0; j < 8; ++j) {
            int krow = 4 * half + (j & 3) + 8 * (j >> 2);
            bfr[t][j] = (short)f2bf(We1[krow * HD + t * 32 + lc]);
        }
        we2v[t] = We2[t * 32 + lc];
        be1v[t] = be1[t * 32 + lc];
    }
    const float be2v = be2[0];

    for (int g = wid; g < G; g += nw) {
        int eb = g << 5;
        int edge = eb + lc;
        int eload = edge < E ? edge : E - 1;
        const float4* rowp = reinterpret_cast<const float4*>(edge_attr + (size_t)eload * EAD);
        float4 a0 = rowp[half];
        float4 a1 = rowp[2 + half];
        bf16x8 af;
        af[0] = (short)f2bf(a0.x); af[1] = (short)f2bf(a0.y);
        af[2] = (short)f2bf(a0.z); af[3] = (short)f2bf(a0.w);
        af[4] = (short)f2bf(a1.x); af[5] = (short)f2bf(a1.y);
        af[6] = (short)f2bf(a1.z); af[7] = (short)f2bf(a1.w);

        f32x16 acc0, acc1, acc2, acc3;
#pragma unroll
        for (int i = 0; i < 16; ++i) { acc0[i]=0.f; acc1[i]=0.f; acc2[i]=0.f; acc3[i]=0.f; }
        acc0 = __builtin_amdgcn_mfma_f32_32x32x16_bf16(af, bfr[0], acc0, 0, 0, 0);
        acc1 = __builtin_amdgcn_mfma_f32_32x32x16_bf16(af, bfr[1], acc1, 0, 0, 0);
        acc2 = __builtin_amdgcn_mfma_f32_32x32x16_bf16(af, bfr[2], acc2, 0, 0, 0);
        acc3 = __builtin_amdgcn_mfma_f32_32x32x16_bf16(af, bfr[3], acc3, 0, 0, 0);

        float p[16];
#pragma unroll
        for (int r = 0; r < 16; ++r) {
            float s;
            s = fmaxf(acc0[r] + be1v[0], 0.f) * we2v[0];
            s = fmaf(fmaxf(acc1[r] + be1v[1], 0.f), we2v[1], s);
            s = fmaf(fmaxf(acc2[r] + be1v[2], 0.f), we2v[2], s);
            s = fmaf(fmaxf(acc3[r] + be1v[3], 0.f), we2v[3], s);
            p[r] = s;
        }
#pragma unroll
        for (int r = 0; r < 16; ++r) {
#pragma unroll
            for (int off = 1; off < 32; off <<= 1)
                p[r] += __shfl_xor(p[r], off, 64);
        }
        if (lc < 16) {
            int q = lc;
            float mine = p[0];
#pragma unroll
            for (int r = 1; r < 16; ++r) mine = (q == r) ? p[r] : mine;
            int row = (q & 3) + 8 * (q >> 2) + 4 * half;
            int e2 = eb + row;
            if (e2 < E) {
                float v  = mine + be2v;
                ew[e2] = fmaxf(v, 0.f) + log1pf(expf(-fabsf(v)));
            }
        }
    }
}

// ---------------- coarse bucket count (bucket = dst >> 8) ----------------
__global__ __launch_bounds__(256) void k_bcount(
    const int* __restrict__ dst, int* __restrict__ batom, int E, int NB)
{
    __shared__ int hist[256];
    int t = threadIdx.x;
    hist[t] = 0;
    __syncthreads();
    int base = blockIdx.x * PCHUNK;
#pragma unroll
    for (int k = 0; k < PCHUNK / 256; ++k) {
        int e = base + k * 256 + t;
        if (e < E) atomicAdd(&hist[dst[e] >> 8], 1);
    }
    __syncthreads();
    if (t < NB && hist[t]) atomicAdd(&batom[t], hist[t]);
}

// ---------------- scan bucket counts -> boff (exclusive), bcur copy -----------
__global__ __launch_bounds__(256) void k_bscan(
    const int* __restrict__ batom, int* __restrict__ boff,
    int* __restrict__ bcur, int NB)
{
    __shared__ int sh[256];
    int t = threadIdx.x;
    int v = (t < NB) ? batom[t] : 0;
    sh[t] = v;
    __syncthreads();
    for (int off = 1; off < 256; off <<= 1) {
        int add = (t >= off) ? sh[t - off] : 0;
        __syncthreads();
        sh[t] += add;
        __syncthreads();
    }
    if (t < NB) { boff[t] = sh[t] - v; bcur[t] = sh[t] - v; }
    if (t == NB - 1) boff[NB] = sh[t];
}

// ---------------- partition edges into coarse buckets ----------------
__global__ __launch_bounds__(256) void k_part(
    const int* __restrict__ src, const int* __restrict__ dst,
    const float* __restrict__ ew, int* __restrict__ bcur,
    uint2* __restrict__ bbuf, int E, int NB)
{
    __shared__ int hist[256];
    __shared__ int base[256];
    __shared__ int cur[256];
    int t = threadIdx.x;
    hist[t] = 0; cur[t] = 0;
    __syncthreads();
    int eb = blockIdx.x * PCHUNK;
#pragma unroll
    for (int k = 0; k < PCHUNK / 256; ++k) {
        int e = eb + k * 256 + t;
        if (e < E) atomicAdd(&hist[dst[e] >> 8], 1);
    }
    __syncthreads();
    if (t < NB && hist[t]) base[t] = atomicAdd(&bcur[t], hist[t]);
    __syncthreads();
#pragma unroll
    for (int k = 0; k < PCHUNK / 256; ++k) {
        int e = eb + k * 256 + t;
        if (e >= E) continue;
        int d = dst[e];
        int bkt = d >> 8;
        int pos = base[bkt] + atomicAdd(&cur[bkt], 1);
        bbuf[pos] = make_uint2(((unsigned)src[e] << 16) | f2h(ew[e]),
                               (unsigned)(d & 255));
    }
}

// ---------------- per-bucket counting sort: rp, dis, adj ----------------
__global__ __launch_bounds__(256) void k_bucket(
    const int* __restrict__ boff, const uint2* __restrict__ bbuf,
    int* __restrict__ rp, float* __restrict__ dis,
    unsigned* __restrict__ adj, int N, int E, int NB)
{
    __shared__ int   hcnt[256];
    __shared__ int   hexc[256];
    __shared__ int   cur[256];
    __shared__ float degs[256];
    int b = blockIdx.x;
    int t = threadIdx.x;
    hcnt[t] = 0; cur[t] = 0; degs[t] = 0.f;
    __syncthreads();
    int beg = boff[b], end = boff[b + 1];
    for (int i = beg + t; i < end; i += 256) {
        uint2 ent = bbuf[i];
        int dl = (int)ent.y;
        atomicAdd(&hcnt[dl], 1);
        atomicAdd(&degs[dl], h2f(ent.x));
    }
    __syncthreads();
    {
        int v = hcnt[t];
        hexc[t] = v;
        __syncthreads();
        for (int off = 1; off < 256; off <<= 1) {
            int add = (t >= off) ? hexc[t - off] : 0;
            __syncthreads();
            hexc[t] += add;
            __syncthreads();
        }
        hexc[t] -= v;
    }
    int n = (b << 8) + t;
    if (n < N) {
        rp[n]  = beg + hexc[t];
        dis[n] = rsqrtf(fmaxf(1.0f + degs[t], 1e-12f));
    }
    if (b == NB - 1 && t == 0) rp[N] = E;
    __syncthreads();
    for (int i = beg + t; i < end; i += 256) {
        uint2 ent = bbuf[i];
        int dl = (int)ent.y;
        int pos = beg + hexc[dl] + atomicAdd(&cur[dl], 1);
        adj[pos] = ent.x;
    }
}

// ------- MFMA GEMM: Abf[row] = bf16( dis[row] * (relu?)X[row] @ W ) ----------
// W^T staged to LDS as bf16 [128][132] (pad 4 -> 2-way bank alias, free).
// Per wave: one 32-row tile, 4 col-tiles of 32, K=128 in 8 steps of 16.
template <bool BF16IN, bool RELU>
__global__ __launch_bounds__(256) void k_gemm(
    const void* __restrict__ Xv, const float* __restrict__ W,
    const float* __restrict__ dis, unsigned short* __restrict__ Ybf, int N)
{
    __shared__ unsigned short Wt[128][132];
    int t = threadIdx.x;
#pragma unroll
    for (int i = 0; i < 64; ++i) {           // stage W^T (16384 elems / 256 thr)
        int e = i * 256 + t;
        int k = e >> 7, n = e & 127;
        Wt[n][k] = (unsigned short)f2bf(W[e]);
    }
    __syncthreads();

    const int lane = t & 63;
    const int half = lane >> 5;
    const int lc   = lane & 31;
    const int wid  = blockIdx.x * 4 + (t >> 6);
    const int nw   = gridDim.x * 4;
    const int T    = (N + 31) >> 5;

    for (int tile = wid; tile < T; tile += nw) {
        int rbase = tile << 5;
        int arow  = rbase + lc; if (arow >= N) arow = N - 1;

        f32x16 acc[4];
#pragma unroll
        for (int tb = 0; tb < 4; ++tb)
#pragma unroll
            for (int i = 0; i < 16; ++i) acc[tb][i] = 0.f;

#pragma unroll
        for (int kk = 0; kk < 8; ++kk) {
            // ---- A fragment: rows of X, k = kk*16 + 4*half + {0..3, 8..11} ----
            union { uint2 u[2]; bf16x8 v; } af;
            if (BF16IN) {
                const unsigned short* Xb = (const unsigned short*)Xv;
                const unsigned short* rp = Xb + (size_t)arow * HD + kk * 16 + 4 * half;
                uint2 lo = *reinterpret_cast<const uint2*>(rp);
                uint2 hi = *reinterpret_cast<const uint2*>(rp + 8);
                if (RELU) {
                    lo.x = relu_pk(lo.x); lo.y = relu_pk(lo.y);
                    hi.x = relu_pk(hi.x); hi.y = relu_pk(hi.y);
                }
                af.u[0] = lo; af.u[1] = hi;
            } else {
                const float* Xf = (const float*)Xv;
                const float* rp = Xf + (size_t)arow * HD + kk * 16 + 4 * half;
                float4 lo = *reinterpret_cast<const float4*>(rp);
                float4 hi = *reinterpret_cast<const float4*>(rp + 8);
                af.u[0] = make_uint2(cvtpk(lo.x, lo.y), cvtpk(lo.z, lo.w));
                af.u[1] = make_uint2(cvtpk(hi.x, hi.y), cvtpk(hi.z, hi.w));
            }
            // ---- B fragments from LDS + MFMA ----
#pragma unroll
            for (int tb = 0; tb < 4; ++tb) {
                const unsigned short* wp = &Wt[tb * 32 + lc][kk * 16 + 4 * half];
                union { uint2 u[2]; bf16x8 v; } bf_;
                bf_.u[0] = *reinterpret_cast<const uint2*>(wp);
                bf_.u[1] = *reinterpret_cast<const uint2*>(wp + 8);
                acc[tb] = __builtin_amdgcn_mfma_f32_32x32x16_bf16(af.v, bf_.v, acc[tb], 0, 0, 0);
            }
        }

        // ---- epilogue: scale by dis[row], store bf16 ----
        float disv = dis[arow];
#pragma unroll
        for (int r = 0; r < 16; ++r) {
            int rofs = (r & 3) + 8 * (r >> 2) + 4 * half;
            int grow = rbase + rofs;
            float d = __shfl(disv, rofs, 32);
            if (grow < N) {
#pragma unroll
                for (int tb = 0; tb < 4; ++tb)
                    Ybf[(size_t)grow * HD + tb * 32 + lc] =
                        (unsigned short)f2bf(acc[tb][r] * d);
            }
        }
    }
}

// --- gather: out[n] = bf16( b + dis[n] * (linbf[n] + sum ew*linbf[src]) ) -----
__global__ __launch_bounds__(256) void k_gather(
    const int* __restrict__ rp, const unsigned* __restrict__ adj,
    const unsigned* __restrict__ linbf, const float* __restrict__ dis,
    const float* __restrict__ b, unsigned short* __restrict__ out, int N)
{
    int n = blockIdx.x * 8 + (threadIdx.x >> 5);
    if (n >= N) return;
    int lane = threadIdx.x & 31;
    uint2 sw = *reinterpret_cast<const uint2*>(linbf + (size_t)n * (HD/2) + lane * 2);
    float4 acc;
    acc.x = bf_lo(sw.x); acc.y = bf_hi(sw.x);
    acc.z = bf_lo(sw.y); acc.w = bf_hi(sw.y);
    int beg = rp[n], end = rp[n + 1];
    for (int i0 = beg; i0 < end; i0 += 32) {
        int m = end - i0; if (m > 32) m = 32;
        unsigned a = 0;
        if (lane < m) a = adj[i0 + lane];
        int j = 0;
        for (; j + 4 <= m; j += 4) {
            unsigned e0 = __shfl(a, j,     32);
            unsigned e1 = __shfl(a, j + 1, 32);
            unsigned e2 = __shfl(a, j + 2, 32);
            unsigned e3 = __shfl(a, j + 3, 32);
            uint2 v0 = *reinterpret_cast<const uint2*>(linbf + (size_t)(e0 >> 16) * (HD/2) + lane * 2);
            uint2 v1 = *reinterpret_cast<const uint2*>(linbf + (size_t)(e1 >> 16) * (HD/2) + lane * 2);
            uint2 v2 = *reinterpret_cast<const uint2*>(linbf + (size_t)(e2 >> 16) * (HD/2) + lane * 2);
            uint2 v3 = *reinterpret_cast<const uint2*>(linbf + (size_t)(e3 >> 16) * (HD/2) + lane * 2);
            float w0 = h2f(e0), w1 = h2f(e1), w2 = h2f(e2), w3 = h2f(e3);
            acc.x = fmaf(w0, bf_lo(v0.x), acc.x);
            acc.y = fmaf(w0, bf_hi(v0.x), acc.y);
            acc.z = fmaf(w0, bf_lo(v0.y), acc.z);
            acc.w = fmaf(w0, bf_hi(v0.y), acc.w);
            acc.x = fmaf(w1, bf_lo(v1.x), acc.x);
            acc.y = fmaf(w1, bf_hi(v1.x), acc.y);
            acc.z = fmaf(w1, bf_lo(v1.y), acc.z);
            acc.w = fmaf(w1, bf_hi(v1.y), acc.w);
            acc.x = fmaf(w2, bf_lo(v2.x), acc.x);
            acc.y = fmaf(w2, bf_hi(v2.x), acc.y);
            acc.z = fmaf(w2, bf_lo(v2.y), acc.z);
            acc.w = fmaf(w2, bf_hi(v2.y), acc.w);
            acc.x = fmaf(w3, bf_lo(v3.x), acc.x);
            acc.y = fmaf(w3, bf_hi(v3.x), acc.y);
            acc.z = fmaf(w3, bf_lo(v3.y), acc.z);
            acc.w = fmaf(w3, bf_hi(v3.y), acc.w);
        }
        for (; j < m; ++j) {
            unsigned e0 = __shfl(a, j, 32);
            uint2 v0 = *reinterpret_cast<const uint2*>(linbf + (size_t)(e0 >> 16) * (HD/2) + lane * 2);
            float w0 = h2f(e0);
            acc.x = fmaf(w0, bf_lo(v0.x), acc.x);
            acc.y = fmaf(w0, bf_hi(v0.x), acc.y);
            acc.z = fmaf(w0, bf_lo(v0.y), acc.z);
            acc.w = fmaf(w0, bf_hi(v0.y), acc.w);
        }
    }
    float dn = dis[n];
    float4 bv = reinterpret_cast<const float4*>(b)[lane];
    unsigned w0 = cvtpk(fmaf(dn, acc.x, bv.x), fmaf(dn, acc.y, bv.y));
    unsigned w1 = cvtpk(fmaf(dn, acc.z, bv.z), fmaf(dn, acc.w, bv.w));
    *reinterpret_cast<uint2*>(out + (size_t)n * HD + lane * 4) = make_uint2(w0, w1);
}

// ---------------- pool partials (relu fused), bf16 input ----------------
__global__ __launch_bounds__(128) void k_pool(
    const unsigned short* __restrict__ h, float* __restrict__ part, int N)
{
    int c = threadIdx.x;
    float acc = 0.f;
    for (int r = blockIdx.x; r < N; r += 128)
        acc += fmaxf(bf1(h[(size_t)r * HD + c]), 0.f);
    part[blockIdx.x * HD + c] = acc;
}

// ---------------- head: out = (colsum(part)/N) @ Wh + bh ----------------
__global__ __launch_bounds__(128) void k_head(
    const float* __restrict__ part, const float* __restrict__ Wh,
    const float* __restrict__ bh, float* __restrict__ out, float invN)
{
    __shared__ float col[HD];
    int t = threadIdx.x;
    float s = 0.f;
    for (int k = 0; k < 128; ++k)
        s += part[k * HD + t];
    col[t] = s * invN;
    __syncthreads();
    if (t < OUTD) {
        float acc = bh[t];
        for (int k = 0; k < HD; ++k)
            acc = fmaf(col[k], Wh[k * OUTD + t], acc);
        out[t] = acc;
    }
}

extern "C" void kernel_launch(void* const* d_in, const int* in_sizes, int n_in,
                              void* d_out, int out_size, void* d_ws, size_t ws_size,
                              hipStream_t stream)
{
    const float* x         = (const float*)d_in[0];
    const int*   ei        = (const int*)  d_in[1];
    const float* edge_attr = (const float*)d_in[2];
    const float* We1       = (const float*)d_in[3];
    const float* be1       = (const float*)d_in[4];
    const float* We2       = (const float*)d_in[5];
    const float* be2       = (const float*)d_in[6];
    const float* W1        = (const float*)d_in[7];
    const float* b1        = (const float*)d_in[8];
    const float* W2        = (const float*)d_in[9];
    const float* b2        = (const float*)d_in[10];
    const float* W3        = (const float*)d_in[11];
    const float* b3        = (const float*)d_in[12];
    const float* Wh        = (const float*)d_in[13];
    const float* bh        = (const float*)d_in[14];

    const int N = in_sizes[0] / HD;
    const int E = in_sizes[2] / EAD;
    const int NB = (N + 255) >> 8;
    const int* srcp = ei;
    const int* dstp = ei + E;

    // workspace partition
    char* w = (char*)d_ws;
    float*          ew   = (float*)w;          w += (size_t)E * sizeof(float);
    float*          dis  = (float*)w;          w += (size_t)N * sizeof(float);
    unsigned short* Bbf  = (unsigned short*)w; w += (size_t)N * HD * sizeof(unsigned short);
    unsigned*       Abf  = (unsigned*)w;       w += (size_t)N * (HD/2) * sizeof(unsigned);
    float*          part = (float*)w;          w += 128 * HD * sizeof(float);
    int*            rp   = (int*)w;            w += (size_t)(N + 2) * sizeof(int);
    int*            batom= (int*)w;            w += 256 * sizeof(int);
    int*            boff = (int*)w;            w += 260 * sizeof(int);
    int*            bcur = (int*)w;            w += 256 * sizeof(int);
    w = (char*)(((uintptr_t)w + 15) & ~(uintptr_t)15);
    uint2*          bbuf = (uint2*)w;          w += (size_t)E * sizeof(uint2);
    unsigned*       adj  = (unsigned*)w;       w += (size_t)E * sizeof(unsigned);

    const int gGe   = ceil_div(N, 8);
    const int gPart = ceil_div(E, PCHUNK);
    const int gGemm = 196;                     // 784 waves, ~2 row-tiles each

    // edge weights (MFMA MLP, atomic-free)
    k_edge_mlp<<<1024, 256, 0, stream>>>(edge_attr, We1, be1, We2, be2, ew, E);

    // CSR build: bucket count -> scan -> partition -> per-bucket sort
    hipMemsetAsync(batom, 0, 256 * sizeof(int), stream);
    k_bcount<<<gPart, 256, 0, stream>>>(dstp, batom, E, NB);
    k_bscan <<<1, 256, 0, stream>>>(batom, boff, bcur, NB);
    k_part  <<<gPart, 256, 0, stream>>>(srcp, dstp, ew, bcur, bbuf, E, NB);
    k_bucket<<<NB, 256, 0, stream>>>(boff, bbuf, rp, dis, adj, N, E, NB);

    // layer 1 (x is f32, no relu)
    k_gemm<false, false><<<gGemm, 256, 0, stream>>>(x, W1, dis, (unsigned short*)Abf, N);
    k_gather<<<gGe, 256, 0, stream>>>(rp, adj, Abf, dis, b1, Bbf, N);
    // layer 2 (bf16 input, relu)
    k_gemm<true, true><<<gGemm, 256, 0, stream>>>(Bbf, W2, dis, (unsigned short*)Abf, N);
    k_gather<<<gGe, 256, 0, stream>>>(rp, adj, Abf, dis, b2, Bbf, N);
    // layer 3
    k_gemm<true, true><<<gGemm, 256, 0, stream>>>(Bbf, W3, dis, (unsigned short*)Abf, N);
    k_gather<<<gGe, 256, 0, stream>>>(rp, adj, Abf, dis, b3, Bbf, N);

    // pool + head
    k_pool<<<128, 128, 0, stream>>>(Bbf, part, N);
    k_head<<<1, 128, 0, stream>>>(part, Wh, bh, (float*)d_out, 1.0f / (float)N);
}

// Round 10
// 487.618 us; speedup vs baseline: 17.4708x; 1.0100x over previous
//
#include <hip/hip_runtime.h>

// GraphGCN forward. Round 9: parallel vectorized pool (was 2.4% occupancy),
// gather inner loop unrolled x8 for MLP. Otherwise round-8 structure:
// MFMA bf16 GEMMs, bf16 h-buffer, atomic-free CSR build, MFMA edge MLP.
// N=50000 nodes, E=1600000 edges, IN=H=128, EA=16, OUT=10.

#define HD   128
#define EAD  16
#define OUTD 10
#define PCHUNK 4096
#define PBLK 400              // pool partial blocks

typedef short bf16x8 __attribute__((ext_vector_type(8)));
typedef float f32x16 __attribute__((ext_vector_type(16)));

static inline int ceil_div(long long a, long long b){ return (int)((a + b - 1) / b); }

__device__ inline unsigned f2bf(float f) {           // RNE f32 -> bf16
    unsigned u = __float_as_uint(f);
    return (u + 0x7fffu + ((u >> 16) & 1u)) >> 16;
}
__device__ inline float bf_lo(unsigned w) { return __uint_as_float(w << 16); }
__device__ inline float bf_hi(unsigned w) { return __uint_as_float(w & 0xffff0000u); }

__device__ inline unsigned short f2h(float f) {
    _Float16 h = (_Float16)f;
    return __builtin_bit_cast(unsigned short, h);
}
__device__ inline float h2f(unsigned u) {            // low 16 bits = f16
    _Float16 h = __builtin_bit_cast(_Float16, (unsigned short)(u & 0xffffu));
    return (float)h;
}
__device__ inline unsigned cvtpk(float lo, float hi) {   // 2xf32 -> packed bf16
    unsigned r;
    asm volatile("v_cvt_pk_bf16_f32 %0, %1, %2" : "=v"(r) : "v"(lo), "v"(hi));
    return r;
}
__device__ inline unsigned relu_pk(unsigned w) {     // relu on packed 2xbf16
    return w & ~(((w >> 15) & 0x10001u) * 0xFFFFu);
}

// ---------------- edge MLP via MFMA (no atomics) ----------------
__global__ __launch_bounds__(256) void k_edge_mlp(
    const float* __restrict__ edge_attr,
    const float* __restrict__ We1, const float* __restrict__ be1,
    const float* __restrict__ We2, const float* __restrict__ be2,
    float* __restrict__ ew, int E)
{
    const int lane = threadIdx.x & 63;
    const int half = lane >> 5;
    const int lc   = lane & 31;
    const int wid  = blockIdx.x * 4 + (threadIdx.x >> 6);
    const int nw   = gridDim.x * 4;
    const int G    = (E + 31) >> 5;

    bf16x8 bfr[4];
    float  we2v[4], be1v[4];
#pragma unroll
    for (int t = 0; t < 4; ++t) {
#pragma unroll
        for (int j = 0; j < 8; ++j) {
            int krow = 4 * half + (j & 3) + 8 * (j >> 2);
            bfr[t][j] = (short)f2bf(We1[krow * HD + t * 32 + lc]);
        }
        we2v[t] = We2[t * 32 + lc];
        be1v[t] = be1[t * 32 + lc];
    }
    const float be2v = be2[0];

    for (int g = wid; g < G; g += nw) {
        int eb = g << 5;
        int edge = eb + lc;
        int eload = edge < E ? edge : E - 1;
        const float4* rowp = reinterpret_cast<const float4*>(edge_attr + (size_t)eload * EAD);
        float4 a0 = rowp[half];
        float4 a1 = rowp[2 + half];
        bf16x8 af;
        af[0] = (short)f2bf(a0.x); af[1] = (short)f2bf(a0.y);
        af[2] = (short)f2bf(a0.z); af[3] = (short)f2bf(a0.w);
        af[4] = (short)f2bf(a1.x); af[5] = (short)f2bf(a1.y);
        af[6] = (short)f2bf(a1.z); af[7] = (short)f2bf(a1.w);

        f32x16 acc0, acc1, acc2, acc3;
#pragma unroll
        for (int i = 0; i < 16; ++i) { acc0[i]=0.f; acc1[i]=0.f; acc2[i]=0.f; acc3[i]=0.f; }
        acc0 = __builtin_amdgcn_mfma_f32_32x32x16_bf16(af, bfr[0], acc0, 0, 0, 0);
        acc1 = __builtin_amdgcn_mfma_f32_32x32x16_bf16(af, bfr[1], acc1, 0, 0, 0);
        acc2 = __builtin_amdgcn_mfma_f32_32x32x16_bf16(af, bfr[2], acc2, 0, 0, 0);
        acc3 = __builtin_amdgcn_mfma_f32_32x32x16_bf16(af, bfr[3], acc3, 0, 0, 0);

        float p[16];
#pragma unroll
        for (int r = 0; r < 16; ++r) {
            float s;
            s = fmaxf(acc0[r] + be1v[0], 0.f) * we2v[0];
            s = fmaf(fmaxf(acc1[r] + be1v[1], 0.f), we2v[1], s);
            s = fmaf(fmaxf(acc2[r] + be1v[2], 0.f), we2v[2], s);
            s = fmaf(fmaxf(acc3[r] + be1v[3], 0.f), we2v[3], s);
            p[r] = s;
        }
#pragma unroll
        for (int r = 0; r < 16; ++r) {
#pragma unroll
            for (int off = 1; off < 32; off <<= 1)
                p[r] += __shfl_xor(p[r], off, 64);
        }
        if (lc < 16) {
            int q = lc;
            float mine = p[0];
#pragma unroll
            for (int r = 1; r < 16; ++r) mine = (q == r) ? p[r] : mine;
            int row = (q & 3) + 8 * (q >> 2) + 4 * half;
            int e2 = eb + row;
            if (e2 < E) {
                float v  = mine + be2v;
                ew[e2] = fmaxf(v, 0.f) + log1pf(expf(-fabsf(v)));
            }
        }
    }
}

// ---------------- coarse bucket count (bucket = dst >> 8) ----------------
__global__ __launch_bounds__(256) void k_bcount(
    const int* __restrict__ dst, int* __restrict__ batom, int E, int NB)
{
    __shared__ int hist[256];
    int t = threadIdx.x;
    hist[t] = 0;
    __syncthreads();
    int base = blockIdx.x * PCHUNK;
#pragma unroll
    for (int k = 0; k < PCHUNK / 256; ++k) {
        int e = base + k * 256 + t;
        if (e < E) atomicAdd(&hist[dst[e] >> 8], 1);
    }
    __syncthreads();
    if (t < NB && hist[t]) atomicAdd(&batom[t], hist[t]);
}

// ---------------- scan bucket counts -> boff (exclusive), bcur copy -----------
__global__ __launch_bounds__(256) void k_bscan(
    const int* __restrict__ batom, int* __restrict__ boff,
    int* __restrict__ bcur, int NB)
{
    __shared__ int sh[256];
    int t = threadIdx.x;
    int v = (t < NB) ? batom[t] : 0;
    sh[t] = v;
    __syncthreads();
    for (int off = 1; off < 256; off <<= 1) {
        int add = (t >= off) ? sh[t - off] : 0;
        __syncthreads();
        sh[t] += add;
        __syncthreads();
    }
    if (t < NB) { boff[t] = sh[t] - v; bcur[t] = sh[t] - v; }
    if (t == NB - 1) boff[NB] = sh[t];
}

// ---------------- partition edges into coarse buckets ----------------
__global__ __launch_bounds__(256) void k_part(
    const int* __restrict__ src, const int* __restrict__ dst,
    const float* __restrict__ ew, int* __restrict__ bcur,
    uint2* __restrict__ bbuf, int E, int NB)
{
    __shared__ int hist[256];
    __shared__ int base[256];
    __shared__ int cur[256];
    int t = threadIdx.x;
    hist[t] = 0; cur[t] = 0;
    __syncthreads();
    int eb = blockIdx.x * PCHUNK;
#pragma unroll
    for (int k = 0; k < PCHUNK / 256; ++k) {
        int e = eb + k * 256 + t;
        if (e < E) atomicAdd(&hist[dst[e] >> 8], 1);
    }
    __syncthreads();
    if (t < NB && hist[t]) base[t] = atomicAdd(&bcur[t], hist[t]);
    __syncthreads();
#pragma unroll
    for (int k = 0; k < PCHUNK / 256; ++k) {
        int e = eb + k * 256 + t;
        if (e >= E) continue;
        int d = dst[e];
        int bkt = d >> 8;
        int pos = base[bkt] + atomicAdd(&cur[bkt], 1);
        bbuf[pos] = make_uint2(((unsigned)src[e] << 16) | f2h(ew[e]),
                               (unsigned)(d & 255));
    }
}

// ---------------- per-bucket counting sort: rp, dis, adj ----------------
__global__ __launch_bounds__(256) void k_bucket(
    const int* __restrict__ boff, const uint2* __restrict__ bbuf,
    int* __restrict__ rp, float* __restrict__ dis,
    unsigned* __restrict__ adj, int N, int E, int NB)
{
    __shared__ int   hcnt[256];
    __shared__ int   hexc[256];
    __shared__ int   cur[256];
    __shared__ float degs[256];
    int b = blockIdx.x;
    int t = threadIdx.x;
    hcnt[t] = 0; cur[t] = 0; degs[t] = 0.f;
    __syncthreads();
    int beg = boff[b], end = boff[b + 1];
    for (int i = beg + t; i < end; i += 256) {
        uint2 ent = bbuf[i];
        int dl = (int)ent.y;
        atomicAdd(&hcnt[dl], 1);
        atomicAdd(&degs[dl], h2f(ent.x));
    }
    __syncthreads();
    {
        int v = hcnt[t];
        hexc[t] = v;
        __syncthreads();
        for (int off = 1; off < 256; off <<= 1) {
            int add = (t >= off) ? hexc[t - off] : 0;
            __syncthreads();
            hexc[t] += add;
            __syncthreads();
        }
        hexc[t] -= v;
    }
    int n = (b << 8) + t;
    if (n < N) {
        rp[n]  = beg + hexc[t];
        dis[n] = rsqrtf(fmaxf(1.0f + degs[t], 1e-12f));
    }
    if (b == NB - 1 && t == 0) rp[N] = E;
    __syncthreads();
    for (int i = beg + t; i < end; i += 256) {
        uint2 ent = bbuf[i];
        int dl = (int)ent.y;
        int pos = beg + hexc[dl] + atomicAdd(&cur[dl], 1);
        adj[pos] = ent.x;
    }
}

// ------- MFMA GEMM: Ybf[row] = bf16( dis[row] * (relu?)X[row] @ W ) ----------
template <bool BF16IN, bool RELU>
__global__ __launch_bounds__(256) void k_gemm(
    const void* __restrict__ Xv, const float* __restrict__ W,
    const float* __restrict__ dis, unsigned short* __restrict__ Ybf, int N)
{
    __shared__ unsigned short Wt[128][132];
    int t = threadIdx.x;
#pragma unroll
    for (int i = 0; i < 64; ++i) {
        int e = i * 256 + t;
        int k = e >> 7, n = e & 127;
        Wt[n][k] = (unsigned short)f2bf(W[e]);
    }
    __syncthreads();

    const int lane = t & 63;
    const int half = lane >> 5;
    const int lc   = lane & 31;
    const int wid  = blockIdx.x * 4 + (t >> 6);
    const int nw   = gridDim.x * 4;
    const int T    = (N + 31) >> 5;

    for (int tile = wid; tile < T; tile += nw) {
        int rbase = tile << 5;
        int arow  = rbase + lc; if (arow >= N) arow = N - 1;

        f32x16 acc[4];
#pragma unroll
        for (int tb = 0; tb < 4; ++tb)
#pragma unroll
            for (int i = 0; i < 16; ++i) acc[tb][i] = 0.f;

#pragma unroll
        for (int kk = 0; kk < 8; ++kk) {
            union { uint2 u[2]; bf16x8 v; } af;
            if (BF16IN) {
                const unsigned short* Xb = (const unsigned short*)Xv;
                const unsigned short* rp = Xb + (size_t)arow * HD + kk * 16 + 4 * half;
                uint2 lo = *reinterpret_cast<const uint2*>(rp);
                uint2 hi = *reinterpret_cast<const uint2*>(rp + 8);
                if (RELU) {
                    lo.x = relu_pk(lo.x); lo.y = relu_pk(lo.y);
                    hi.x = relu_pk(hi.x); hi.y = relu_pk(hi.y);
                }
                af.u[0] = lo; af.u[1] = hi;
            } else {
                const float* Xf = (const float*)Xv;
                const float* rp = Xf + (size_t)arow * HD + kk * 16 + 4 * half;
                float4 lo = *reinterpret_cast<const float4*>(rp);
                float4 hi = *reinterpret_cast<const float4*>(rp + 8);
                af.u[0] = make_uint2(cvtpk(lo.x, lo.y), cvtpk(lo.z, lo.w));
                af.u[1] = make_uint2(cvtpk(hi.x, hi.y), cvtpk(hi.z, hi.w));
            }
#pragma unroll
            for (int tb = 0; tb < 4; ++tb) {
                const unsigned short* wp = &Wt[tb * 32 + lc][kk * 16 + 4 * half];
                union { uint2 u[2]; bf16x8 v; } bf_;
                bf_.u[0] = *reinterpret_cast<const uint2*>(wp);
                bf_.u[1] = *reinterpret_cast<const uint2*>(wp + 8);
                acc[tb] = __builtin_amdgcn_mfma_f32_32x32x16_bf16(af.v, bf_.v, acc[tb], 0, 0, 0);
            }
        }

        float disv = dis[arow];
#pragma unroll
        for (int r = 0; r < 16; ++r) {
            int rofs = (r & 3) + 8 * (r >> 2) + 4 * half;
            int grow = rbase + rofs;
            float d = __shfl(disv, rofs, 32);
            if (grow < N) {
#pragma unroll
                for (int tb = 0; tb < 4; ++tb)
                    Ybf[(size_t)grow * HD + tb * 32 + lc] =
                        (unsigned short)f2bf(acc[tb][r] * d);
            }
        }
    }
}

// --- gather: out[n] = bf16( b + dis[n] * (linbf[n] + sum ew*linbf[src]) ) -----
__global__ __launch_bounds__(256) void k_gather(
    const int* __restrict__ rp, const unsigned* __restrict__ adj,
    const unsigned* __restrict__ linbf, const float* __restrict__ dis,
    const float* __restrict__ b, unsigned short* __restrict__ out, int N)
{
    int n = blockIdx.x * 8 + (threadIdx.x >> 5);
    if (n >= N) return;
    int lane = threadIdx.x & 31;
    uint2 sw = *reinterpret_cast<const uint2*>(linbf + (size_t)n * (HD/2) + lane * 2);
    float4 acc;
    acc.x = bf_lo(sw.x); acc.y = bf_hi(sw.x);
    acc.z = bf_lo(sw.y); acc.w = bf_hi(sw.y);
    int beg = rp[n], end = rp[n + 1];
    for (int i0 = beg; i0 < end; i0 += 32) {
        int m = end - i0; if (m > 32) m = 32;
        unsigned a = 0;
        if (lane < m) a = adj[i0 + lane];
        int j = 0;
        for (; j + 8 <= m; j += 8) {
            unsigned ee[8]; uint2 vv[8];
#pragma unroll
            for (int q = 0; q < 8; ++q) ee[q] = __shfl(a, j + q, 32);
#pragma unroll
            for (int q = 0; q < 8; ++q)
                vv[q] = *reinterpret_cast<const uint2*>(linbf + (size_t)(ee[q] >> 16) * (HD/2) + lane * 2);
#pragma unroll
            for (int q = 0; q < 8; ++q) {
                float wq = h2f(ee[q]);
                acc.x = fmaf(wq, bf_lo(vv[q].x), acc.x);
                acc.y = fmaf(wq, bf_hi(vv[q].x), acc.y);
                acc.z = fmaf(wq, bf_lo(vv[q].y), acc.z);
                acc.w = fmaf(wq, bf_hi(vv[q].y), acc.w);
            }
        }
        for (; j < m; ++j) {
            unsigned e0 = __shfl(a, j, 32);
            uint2 v0 = *reinterpret_cast<const uint2*>(linbf + (size_t)(e0 >> 16) * (HD/2) + lane * 2);
            float w0 = h2f(e0);
            acc.x = fmaf(w0, bf_lo(v0.x), acc.x);
            acc.y = fmaf(w0, bf_hi(v0.x), acc.y);
            acc.z = fmaf(w0, bf_lo(v0.y), acc.z);
            acc.w = fmaf(w0, bf_hi(v0.y), acc.w);
        }
    }
    float dn = dis[n];
    float4 bv = reinterpret_cast<const float4*>(b)[lane];
    unsigned w0 = cvtpk(fmaf(dn, acc.x, bv.x), fmaf(dn, acc.y, bv.y));
    unsigned w1 = cvtpk(fmaf(dn, acc.z, bv.z), fmaf(dn, acc.w, bv.w));
    *reinterpret_cast<uint2*>(out + (size_t)n * HD + lane * 4) = make_uint2(w0, w1);
}

// ---------------- pool partials: 16 rows x 16 chunks per block-iter ----------
__global__ __launch_bounds__(256) void k_pool(
    const unsigned short* __restrict__ h, float* __restrict__ part, int N)
{
    __shared__ float sm[16][128];
    int t  = threadIdx.x;
    int cg = t & 15;              // uint4 chunk (8 bf16) within row
    int rs = t >> 4;              // row slot 0..15
    float acc[8];
#pragma unroll
    for (int i = 0; i < 8; ++i) acc[i] = 0.f;
    for (int r = blockIdx.x * 16 + rs; r < N; r += gridDim.x * 16) {
        uint4 v = *reinterpret_cast<const uint4*>(h + (size_t)r * HD + cg * 8);
        acc[0] += fmaxf(bf_lo(v.x), 0.f);
        acc[1] += fmaxf(bf_hi(v.x), 0.f);
        acc[2] += fmaxf(bf_lo(v.y), 0.f);
        acc[3] += fmaxf(bf_hi(v.y), 0.f);
        acc[4] += fmaxf(bf_lo(v.z), 0.f);
        acc[5] += fmaxf(bf_hi(v.z), 0.f);
        acc[6] += fmaxf(bf_lo(v.w), 0.f);
        acc[7] += fmaxf(bf_hi(v.w), 0.f);
    }
#pragma unroll
    for (int i = 0; i < 8; ++i) sm[rs][cg * 8 + i] = acc[i];
    __syncthreads();
    if (t < 128) {
        float s = 0.f;
#pragma unroll
        for (int k = 0; k < 16; ++k) s += sm[k][t];
        part[blockIdx.x * HD + t] = s;
    }
}

// ---------------- head: out = (colsum(part)/N) @ Wh + bh ----------------
__global__ __launch_bounds__(128) void k_head(
    const float* __restrict__ part, const float* __restrict__ Wh,
    const float* __restrict__ bh, float* __restrict__ out,
    float invN, int kparts)
{
    __shared__ float col[HD];
    int t = threadIdx.x;
    float s = 0.f;
    for (int k = 0; k < kparts; ++k)
        s += part[k * HD + t];
    col[t] = s * invN;
    __syncthreads();
    if (t < OUTD) {
        float acc = bh[t];
        for (int k = 0; k < HD; ++k)
            acc = fmaf(col[k], Wh[k * OUTD + t], acc);
        out[t] = acc;
    }
}

extern "C" void kernel_launch(void* const* d_in, const int* in_sizes, int n_in,
                              void* d_out, int out_size, void* d_ws, size_t ws_size,
                              hipStream_t stream)
{
    const float* x         = (const float*)d_in[0];
    const int*   ei        = (const int*)  d_in[1];
    const float* edge_attr = (const float*)d_in[2];
    const float* We1       = (const float*)d_in[3];
    const float* be1       = (const float*)d_in[4];
    const float* We2       = (const float*)d_in[5];
    const float* be2       = (const float*)d_in[6];
    const float* W1        = (const float*)d_in[7];
    const float* b1        = (const float*)d_in[8];
    const float* W2        = (const float*)d_in[9];
    const float* b2        = (const float*)d_in[10];
    const float* W3        = (const float*)d_in[11];
    const float* b3        = (const float*)d_in[12];
    const float* Wh        = (const float*)d_in[13];
    const float* bh        = (const float*)d_in[14];

    const int N = in_sizes[0] / HD;
    const int E = in_sizes[2] / EAD;
    const int NB = (N + 255) >> 8;
    const int* srcp = ei;
    const int* dstp = ei + E;

    // workspace partition
    char* w = (char*)d_ws;
    float*          ew   = (float*)w;          w += (size_t)E * sizeof(float);
    float*          dis  = (float*)w;          w += (size_t)N * sizeof(float);
    unsigned short* Bbf  = (unsigned short*)w; w += (size_t)N * HD * sizeof(unsigned short);
    unsigned*       Abf  = (unsigned*)w;       w += (size_t)N * (HD/2) * sizeof(unsigned);
    float*          part = (float*)w;          w += (size_t)PBLK * HD * sizeof(float);
    int*            rp   = (int*)w;            w += (size_t)(N + 2) * sizeof(int);
    int*            batom= (int*)w;            w += 256 * sizeof(int);
    int*            boff = (int*)w;            w += 260 * sizeof(int);
    int*            bcur = (int*)w;            w += 256 * sizeof(int);
    w = (char*)(((uintptr_t)w + 15) & ~(uintptr_t)15);
    uint2*          bbuf = (uint2*)w;          w += (size_t)E * sizeof(uint2);
    unsigned*       adj  = (unsigned*)w;       w += (size_t)E * sizeof(unsigned);

    const int gGe   = ceil_div(N, 8);
    const int gPart = ceil_div(E, PCHUNK);
    const int gGemm = 196;

    // edge weights (MFMA MLP, atomic-free)
    k_edge_mlp<<<1024, 256, 0, stream>>>(edge_attr, We1, be1, We2, be2, ew, E);

    // CSR build: bucket count -> scan -> partition -> per-bucket sort
    hipMemsetAsync(batom, 0, 256 * sizeof(int), stream);
    k_bcount<<<gPart, 256, 0, stream>>>(dstp, batom, E, NB);
    k_bscan <<<1, 256, 0, stream>>>(batom, boff, bcur, NB);
    k_part  <<<gPart, 256, 0, stream>>>(srcp, dstp, ew, bcur, bbuf, E, NB);
    k_bucket<<<NB, 256, 0, stream>>>(boff, bbuf, rp, dis, adj, N, E, NB);

    // layer 1 (x is f32, no relu)
    k_gemm<false, false><<<gGemm, 256, 0, stream>>>(x, W1, dis, (unsigned short*)Abf, N);
    k_gather<<<gGe, 256, 0, stream>>>(rp, adj, Abf, dis, b1, Bbf, N);
    // layer 2 (bf16 input, relu)
    k_gemm<true, true><<<gGemm, 256, 0, stream>>>(Bbf, W2, dis, (unsigned short*)Abf, N);
    k_gather<<<gGe, 256, 0, stream>>>(rp, adj, Abf, dis, b2, Bbf, N);
    // layer 3
    k_gemm<true, true><<<gGemm, 256, 0, stream>>>(Bbf, W3, dis, (unsigned short*)Abf, N);
    k_gather<<<gGe, 256, 0, stream>>>(rp, adj, Abf, dis, b3, Bbf, N);

    // pool + head
    k_pool<<<PBLK, 256, 0, stream>>>(Bbf, part, N);
    k_head<<<1, 128, 0, stream>>>(part, Wh, bh, (float*)d_out, 1.0f / (float)N, PBLK);
}

// Round 11
// 392.898 us; speedup vs baseline: 21.6827x; 1.2411x over previous
//
#include <hip/hip_runtime.h>

// GraphGCN forward. Round 10: parallel k_head (was 1-block/400-serial-load,
// 103us). Round-9 structure otherwise: MFMA bf16 GEMMs, bf16 h-buffer,
// atomic-free CSR build, MFMA edge MLP, vectorized pool.
// N=50000 nodes, E=1600000 edges, IN=H=128, EA=16, OUT=10.

#define HD   128
#define EAD  16
#define OUTD 10
#define PCHUNK 4096
#define PBLK 400              // pool partial blocks (8 chunks x 50 in k_head)

typedef short bf16x8 __attribute__((ext_vector_type(8)));
typedef float f32x16 __attribute__((ext_vector_type(16)));

static inline int ceil_div(long long a, long long b){ return (int)((a + b - 1) / b); }

__device__ inline unsigned f2bf(float f) {           // RNE f32 -> bf16
    unsigned u = __float_as_uint(f);
    return (u + 0x7fffu + ((u >> 16) & 1u)) >> 16;
}
__device__ inline float bf_lo(unsigned w) { return __uint_as_float(w << 16); }
__device__ inline float bf_hi(unsigned w) { return __uint_as_float(w & 0xffff0000u); }

__device__ inline unsigned short f2h(float f) {
    _Float16 h = (_Float16)f;
    return __builtin_bit_cast(unsigned short, h);
}
__device__ inline float h2f(unsigned u) {            // low 16 bits = f16
    _Float16 h = __builtin_bit_cast(_Float16, (unsigned short)(u & 0xffffu));
    return (float)h;
}
__device__ inline unsigned cvtpk(float lo, float hi) {   // 2xf32 -> packed bf16
    unsigned r;
    asm volatile("v_cvt_pk_bf16_f32 %0, %1, %2" : "=v"(r) : "v"(lo), "v"(hi));
    return r;
}
__device__ inline unsigned relu_pk(unsigned w) {     // relu on packed 2xbf16
    return w & ~(((w >> 15) & 0x10001u) * 0xFFFFu);
}

// ---------------- edge MLP via MFMA (no atomics) ----------------
__global__ __launch_bounds__(256) void k_edge_mlp(
    const float* __restrict__ edge_attr,
    const float* __restrict__ We1, const float* __restrict__ be1,
    const float* __restrict__ We2, const float* __restrict__ be2,
    float* __restrict__ ew, int E)
{
    const int lane = threadIdx.x & 63;
    const int half = lane >> 5;
    const int lc   = lane & 31;
    const int wid  = blockIdx.x * 4 + (threadIdx.x >> 6);
    const int nw   = gridDim.x * 4;
    const int G    = (E + 31) >> 5;

    bf16x8 bfr[4];
    float  we2v[4], be1v[4];
#pragma unroll
    for (int t = 0; t < 4; ++t) {
#pragma unroll
        for (int j = 0; j < 8; ++j) {
            int krow = 4 * half + (j & 3) + 8 * (j >> 2);
            bfr[t][j] = (short)f2bf(We1[krow * HD + t * 32 + lc]);
        }
        we2v[t] = We2[t * 32 + lc];
        be1v[t] = be1[t * 32 + lc];
    }
    const float be2v = be2[0];

    for (int g = wid; g < G; g += nw) {
        int eb = g << 5;
        int edge = eb + lc;
        int eload = edge < E ? edge : E - 1;
        const float4* rowp = reinterpret_cast<const float4*>(edge_attr + (size_t)eload * EAD);
        float4 a0 = rowp[half];
        float4 a1 = rowp[2 + half];
        bf16x8 af;
        af[0] = (short)f2bf(a0.x); af[1] = (short)f2bf(a0.y);
        af[2] = (short)f2bf(a0.z); af[3] = (short)f2bf(a0.w);
        af[4] = (short)f2bf(a1.x); af[5] = (short)f2bf(a1.y);
        af[6] = (short)f2bf(a1.z); af[7] = (short)f2bf(a1.w);

        f32x16 acc0, acc1, acc2, acc3;
#pragma unroll
        for (int i = 0; i < 16; ++i) { acc0[i]=0.f; acc1[i]=0.f; acc2[i]=0.f; acc3[i]=0.f; }
        acc0 = __builtin_amdgcn_mfma_f32_32x32x16_bf16(af, bfr[0], acc0, 0, 0, 0);
        acc1 = __builtin_amdgcn_mfma_f32_32x32x16_bf16(af, bfr[1], acc1, 0, 0, 0);
        acc2 = __builtin_amdgcn_mfma_f32_32x32x16_bf16(af, bfr[2], acc2, 0, 0, 0);
        acc3 = __builtin_amdgcn_mfma_f32_32x32x16_bf16(af, bfr[3], acc3, 0, 0, 0);

        float p[16];
#pragma unroll
        for (int r = 0; r < 16; ++r) {
            float s;
            s = fmaxf(acc0[r] + be1v[0], 0.f) * we2v[0];
            s = fmaf(fmaxf(acc1[r] + be1v[1], 0.f), we2v[1], s);
            s = fmaf(fmaxf(acc2[r] + be1v[2], 0.f), we2v[2], s);
            s = fmaf(fmaxf(acc3[r] + be1v[3], 0.f), we2v[3], s);
            p[r] = s;
        }
#pragma unroll
        for (int r = 0; r < 16; ++r) {
#pragma unroll
            for (int off = 1; off < 32; off <<= 1)
                p[r] += __shfl_xor(p[r], off, 64);
        }
        if (lc < 16) {
            int q = lc;
            float mine = p[0];
#pragma unroll
            for (int r = 1; r < 16; ++r) mine = (q == r) ? p[r] : mine;
            int row = (q & 3) + 8 * (q >> 2) + 4 * half;
            int e2 = eb + row;
            if (e2 < E) {
                float v  = mine + be2v;
                ew[e2] = fmaxf(v, 0.f) + log1pf(expf(-fabsf(v)));
            }
        }
    }
}

// ---------------- coarse bucket count (bucket = dst >> 8) ----------------
__global__ __launch_bounds__(256) void k_bcount(
    const int* __restrict__ dst, int* __restrict__ batom, int E, int NB)
{
    __shared__ int hist[256];
    int t = threadIdx.x;
    hist[t] = 0;
    __syncthreads();
    int base = blockIdx.x * PCHUNK;
#pragma unroll
    for (int k = 0; k < PCHUNK / 256; ++k) {
        int e = base + k * 256 + t;
        if (e < E) atomicAdd(&hist[dst[e] >> 8], 1);
    }
    __syncthreads();
    if (t < NB && hist[t]) atomicAdd(&batom[t], hist[t]);
}

// ---------------- scan bucket counts -> boff (exclusive), bcur copy -----------
__global__ __launch_bounds__(256) void k_bscan(
    const int* __restrict__ batom, int* __restrict__ boff,
    int* __restrict__ bcur, int NB)
{
    __shared__ int sh[256];
    int t = threadIdx.x;
    int v = (t < NB) ? batom[t] : 0;
    sh[t] = v;
    __syncthreads();
    for (int off = 1; off < 256; off <<= 1) {
        int add = (t >= off) ? sh[t - off] : 0;
        __syncthreads();
        sh[t] += add;
        __syncthreads();
    }
    if (t < NB) { boff[t] = sh[t] - v; bcur[t] = sh[t] - v; }
    if (t == NB - 1) boff[NB] = sh[t];
}

// ---------------- partition edges into coarse buckets ----------------
__global__ __launch_bounds__(256) void k_part(
    const int* __restrict__ src, const int* __restrict__ dst,
    const float* __restrict__ ew, int* __restrict__ bcur,
    uint2* __restrict__ bbuf, int E, int NB)
{
    __shared__ int hist[256];
    __shared__ int base[256];
    __shared__ int cur[256];
    int t = threadIdx.x;
    hist[t] = 0; cur[t] = 0;
    __syncthreads();
    int eb = blockIdx.x * PCHUNK;
#pragma unroll
    for (int k = 0; k < PCHUNK / 256; ++k) {
        int e = eb + k * 256 + t;
        if (e < E) atomicAdd(&hist[dst[e] >> 8], 1);
    }
    __syncthreads();
    if (t < NB && hist[t]) base[t] = atomicAdd(&bcur[t], hist[t]);
    __syncthreads();
#pragma unroll
    for (int k = 0; k < PCHUNK / 256; ++k) {
        int e = eb + k * 256 + t;
        if (e >= E) continue;
        int d = dst[e];
        int bkt = d >> 8;
        int pos = base[bkt] + atomicAdd(&cur[bkt], 1);
        bbuf[pos] = make_uint2(((unsigned)src[e] << 16) | f2h(ew[e]),
                               (unsigned)(d & 255));
    }
}

// ---------------- per-bucket counting sort: rp, dis, adj ----------------
__global__ __launch_bounds__(256) void k_bucket(
    const int* __restrict__ boff, const uint2* __restrict__ bbuf,
    int* __restrict__ rp, float* __restrict__ dis,
    unsigned* __restrict__ adj, int N, int E, int NB)
{
    __shared__ int   hcnt[256];
    __shared__ int   hexc[256];
    __shared__ int   cur[256];
    __shared__ float degs[256];
    int b = blockIdx.x;
    int t = threadIdx.x;
    hcnt[t] = 0; cur[t] = 0; degs[t] = 0.f;
    __syncthreads();
    int beg = boff[b], end = boff[b + 1];
    for (int i = beg + t; i < end; i += 256) {
        uint2 ent = bbuf[i];
        int dl = (int)ent.y;
        atomicAdd(&hcnt[dl], 1);
        atomicAdd(&degs[dl], h2f(ent.x));
    }
    __syncthreads();
    {
        int v = hcnt[t];
        hexc[t] = v;
        __syncthreads();
        for (int off = 1; off < 256; off <<= 1) {
            int add = (t >= off) ? hexc[t - off] : 0;
            __syncthreads();
            hexc[t] += add;
            __syncthreads();
        }
        hexc[t] -= v;
    }
    int n = (b << 8) + t;
    if (n < N) {
        rp[n]  = beg + hexc[t];
        dis[n] = rsqrtf(fmaxf(1.0f + degs[t], 1e-12f));
    }
    if (b == NB - 1 && t == 0) rp[N] = E;
    __syncthreads();
    for (int i = beg + t; i < end; i += 256) {
        uint2 ent = bbuf[i];
        int dl = (int)ent.y;
        int pos = beg + hexc[dl] + atomicAdd(&cur[dl], 1);
        adj[pos] = ent.x;
    }
}

// ------- MFMA GEMM: Ybf[row] = bf16( dis[row] * (relu?)X[row] @ W ) ----------
template <bool BF16IN, bool RELU>
__global__ __launch_bounds__(256) void k_gemm(
    const void* __restrict__ Xv, const float* __restrict__ W,
    const float* __restrict__ dis, unsigned short* __restrict__ Ybf, int N)
{
    __shared__ unsigned short Wt[128][132];
    int t = threadIdx.x;
#pragma unroll
    for (int i = 0; i < 64; ++i) {
        int e = i * 256 + t;
        int k = e >> 7, n = e & 127;
        Wt[n][k] = (unsigned short)f2bf(W[e]);
    }
    __syncthreads();

    const int lane = t & 63;
    const int half = lane >> 5;
    const int lc   = lane & 31;
    const int wid  = blockIdx.x * 4 + (t >> 6);
    const int nw   = gridDim.x * 4;
    const int T    = (N + 31) >> 5;

    for (int tile = wid; tile < T; tile += nw) {
        int rbase = tile << 5;
        int arow  = rbase + lc; if (arow >= N) arow = N - 1;

        f32x16 acc[4];
#pragma unroll
        for (int tb = 0; tb < 4; ++tb)
#pragma unroll
            for (int i = 0; i < 16; ++i) acc[tb][i] = 0.f;

#pragma unroll
        for (int kk = 0; kk < 8; ++kk) {
            union { uint2 u[2]; bf16x8 v; } af;
            if (BF16IN) {
                const unsigned short* Xb = (const unsigned short*)Xv;
                const unsigned short* rp = Xb + (size_t)arow * HD + kk * 16 + 4 * half;
                uint2 lo = *reinterpret_cast<const uint2*>(rp);
                uint2 hi = *reinterpret_cast<const uint2*>(rp + 8);
                if (RELU) {
                    lo.x = relu_pk(lo.x); lo.y = relu_pk(lo.y);
                    hi.x = relu_pk(hi.x); hi.y = relu_pk(hi.y);
                }
                af.u[0] = lo; af.u[1] = hi;
            } else {
                const float* Xf = (const float*)Xv;
                const float* rp = Xf + (size_t)arow * HD + kk * 16 + 4 * half;
                float4 lo = *reinterpret_cast<const float4*>(rp);
                float4 hi = *reinterpret_cast<const float4*>(rp + 8);
                af.u[0] = make_uint2(cvtpk(lo.x, lo.y), cvtpk(lo.z, lo.w));
                af.u[1] = make_uint2(cvtpk(hi.x, hi.y), cvtpk(hi.z, hi.w));
            }
#pragma unroll
            for (int tb = 0; tb < 4; ++tb) {
                const unsigned short* wp = &Wt[tb * 32 + lc][kk * 16 + 4 * half];
                union { uint2 u[2]; bf16x8 v; } bf_;
                bf_.u[0] = *reinterpret_cast<const uint2*>(wp);
                bf_.u[1] = *reinterpret_cast<const uint2*>(wp + 8);
                acc[tb] = __builtin_amdgcn_mfma_f32_32x32x16_bf16(af.v, bf_.v, acc[tb], 0, 0, 0);
            }
        }

        float disv = dis[arow];
#pragma unroll
        for (int r = 0; r < 16; ++r) {
            int rofs = (r & 3) + 8 * (r >> 2) + 4 * half;
            int grow = rbase + rofs;
            float d = __shfl(disv, rofs, 32);
            if (grow < N) {
#pragma unroll
                for (int tb = 0; tb < 4; ++tb)
                    Ybf[(size_t)grow * HD + tb * 32 + lc] =
                        (unsigned short)f2bf(acc[tb][r] * d);
            }
        }
    }
}

// --- gather: out[n] = bf16( b + dis[n] * (linbf[n] + sum ew*linbf[src]) ) -----
__global__ __launch_bounds__(256) void k_gather(
    const int* __restrict__ rp, const unsigned* __restrict__ adj,
    const unsigned* __restrict__ linbf, const float* __restrict__ dis,
    const float* __restrict__ b, unsigned short* __restrict__ out, int N)
{
    int n = blockIdx.x * 8 + (threadIdx.x >> 5);
    if (n >= N) return;
    int lane = threadIdx.x & 31;
    uint2 sw = *reinterpret_cast<const uint2*>(linbf + (size_t)n * (HD/2) + lane * 2);
    float4 acc;
    acc.x = bf_lo(sw.x); acc.y = bf_hi(sw.x);
    acc.z = bf_lo(sw.y); acc.w = bf_hi(sw.y);
    int beg = rp[n], end = rp[n + 1];
    for (int i0 = beg; i0 < end; i0 += 32) {
        int m = end - i0; if (m > 32) m = 32;
        unsigned a = 0;
        if (lane < m) a = adj[i0 + lane];
        int j = 0;
        for (; j + 8 <= m; j += 8) {
            unsigned ee[8]; uint2 vv[8];
#pragma unroll
            for (int q = 0; q < 8; ++q) ee[q] = __shfl(a, j + q, 32);
#pragma unroll
            for (int q = 0; q < 8; ++q)
                vv[q] = *reinterpret_cast<const uint2*>(linbf + (size_t)(ee[q] >> 16) * (HD/2) + lane * 2);
#pragma unroll
            for (int q = 0; q < 8; ++q) {
                float wq = h2f(ee[q]);
                acc.x = fmaf(wq, bf_lo(vv[q].x), acc.x);
                acc.y = fmaf(wq, bf_hi(vv[q].x), acc.y);
                acc.z = fmaf(wq, bf_lo(vv[q].y), acc.z);
                acc.w = fmaf(wq, bf_hi(vv[q].y), acc.w);
            }
        }
        for (; j < m; ++j) {
            unsigned e0 = __shfl(a, j, 32);
            uint2 v0 = *reinterpret_cast<const uint2*>(linbf + (size_t)(e0 >> 16) * (HD/2) + lane * 2);
            float w0 = h2f(e0);
            acc.x = fmaf(w0, bf_lo(v0.x), acc.x);
            acc.y = fmaf(w0, bf_hi(v0.x), acc.y);
            acc.z = fmaf(w0, bf_lo(v0.y), acc.z);
            acc.w = fmaf(w0, bf_hi(v0.y), acc.w);
        }
    }
    float dn = dis[n];
    float4 bv = reinterpret_cast<const float4*>(b)[lane];
    unsigned w0 = cvtpk(fmaf(dn, acc.x, bv.x), fmaf(dn, acc.y, bv.y));
    unsigned w1 = cvtpk(fmaf(dn, acc.z, bv.z), fmaf(dn, acc.w, bv.w));
    *reinterpret_cast<uint2*>(out + (size_t)n * HD + lane * 4) = make_uint2(w0, w1);
}

// ---------------- pool partials: 16 rows x 16 chunks per block-iter ----------
__global__ __launch_bounds__(256) void k_pool(
    const unsigned short* __restrict__ h, float* __restrict__ part, int N)
{
    __shared__ float sm[16][128];
    int t  = threadIdx.x;
    int cg = t & 15;              // uint4 chunk (8 bf16) within row
    int rs = t >> 4;              // row slot 0..15
    float acc[8];
#pragma unroll
    for (int i = 0; i < 8; ++i) acc[i] = 0.f;
    for (int r = blockIdx.x * 16 + rs; r < N; r += gridDim.x * 16) {
        uint4 v = *reinterpret_cast<const uint4*>(h + (size_t)r * HD + cg * 8);
        acc[0] += fmaxf(bf_lo(v.x), 0.f);
        acc[1] += fmaxf(bf_hi(v.x), 0.f);
        acc[2] += fmaxf(bf_lo(v.y), 0.f);
        acc[3] += fmaxf(bf_hi(v.y), 0.f);
        acc[4] += fmaxf(bf_lo(v.z), 0.f);
        acc[5] += fmaxf(bf_hi(v.z), 0.f);
        acc[6] += fmaxf(bf_lo(v.w), 0.f);
        acc[7] += fmaxf(bf_hi(v.w), 0.f);
    }
#pragma unroll
    for (int i = 0; i < 8; ++i) sm[rs][cg * 8 + i] = acc[i];
    __syncthreads();
    if (t < 128) {
        float s = 0.f;
#pragma unroll
        for (int k = 0; k < 16; ++k) s += sm[k][t];
        part[blockIdx.x * HD + t] = s;
    }
}

// ---- head: parallel partial-sum (8 chunks x 50) + wave-parallel GEMV --------
__global__ __launch_bounds__(1024) void k_head(
    const float* __restrict__ part, const float* __restrict__ Wh,
    const float* __restrict__ bh, float* __restrict__ out, float invN)
{
    __shared__ float smc[8][128];
    __shared__ float col[HD];
    int t = threadIdx.x;
    {
        int c  = t & 127;             // column
        int ch = t >> 7;              // chunk 0..7 (50 partials each)
        float s0 = 0.f, s1 = 0.f;
        int k0 = ch * 50;
#pragma unroll
        for (int k = 0; k < 50; k += 2) {
            s0 += part[(k0 + k)     * HD + c];
            s1 += part[(k0 + k + 1) * HD + c];
        }
        smc[ch][c] = s0 + s1;
    }
    __syncthreads();
    if (t < 128) {
        float s = 0.f;
#pragma unroll
        for (int k = 0; k < 8; ++k) s += smc[k][t];
        col[t] = s * invN;
    }
    __syncthreads();
    {
        int o = t >> 6;               // output index (only o<OUTD active)
        int l = t & 63;
        if (o < OUTD) {
            float acc = col[l] * Wh[l * OUTD + o]
                      + col[l + 64] * Wh[(l + 64) * OUTD + o];
#pragma unroll
            for (int off = 1; off < 64; off <<= 1)
                acc += __shfl_xor(acc, off, 64);
            if (l == 0) out[o] = acc + bh[o];
        }
    }
}

extern "C" void kernel_launch(void* const* d_in, const int* in_sizes, int n_in,
                              void* d_out, int out_size, void* d_ws, size_t ws_size,
                              hipStream_t stream)
{
    const float* x         = (const float*)d_in[0];
    const int*   ei        = (const int*)  d_in[1];
    const float* edge_attr = (const float*)d_in[2];
    const float* We1       = (const float*)d_in[3];
    const float* be1       = (const float*)d_in[4];
    const float* We2       = (const float*)d_in[5];
    const float* be2       = (const float*)d_in[6];
    const float* W1        = (const float*)d_in[7];
    const float* b1        = (const float*)d_in[8];
    const float* W2        = (const float*)d_in[9];
    const float* b2        = (const float*)d_in[10];
    const float* W3        = (const float*)d_in[11];
    const float* b3        = (const float*)d_in[12];
    const float* Wh        = (const float*)d_in[13];
    const float* bh        = (const float*)d_in[14];

    const int N = in_sizes[0] / HD;
    const int E = in_sizes[2] / EAD;
    const int NB = (N + 255) >> 8;
    const int* srcp = ei;
    const int* dstp = ei + E;

    // workspace partition
    char* w = (char*)d_ws;
    float*          ew   = (float*)w;          w += (size_t)E * sizeof(float);
    float*          dis  = (float*)w;          w += (size_t)N * sizeof(float);
    unsigned short* Bbf  = (unsigned short*)w; w += (size_t)N * HD * sizeof(unsigned short);
    unsigned*       Abf  = (unsigned*)w;       w += (size_t)N * (HD/2) * sizeof(unsigned);
    float*          part = (float*)w;          w += (size_t)PBLK * HD * sizeof(float);
    int*            rp   = (int*)w;            w += (size_t)(N + 2) * sizeof(int);
    int*            batom= (int*)w;            w += 256 * sizeof(int);
    int*            boff = (int*)w;            w += 260 * sizeof(int);
    int*            bcur = (int*)w;            w += 256 * sizeof(int);
    w = (char*)(((uintptr_t)w + 15) & ~(uintptr_t)15);
    uint2*          bbuf = (uint2*)w;          w += (size_t)E * sizeof(uint2);
    unsigned*       adj  = (unsigned*)w;       w += (size_t)E * sizeof(unsigned);

    const int gGe   = ceil_div(N, 8);
    const int gPart = ceil_div(E, PCHUNK);
    const int gGemm = 196;

    // edge weights (MFMA MLP, atomic-free)
    k_edge_mlp<<<1024, 256, 0, stream>>>(edge_attr, We1, be1, We2, be2, ew, E);

    // CSR build: bucket count -> scan -> partition -> per-bucket sort
    hipMemsetAsync(batom, 0, 256 * sizeof(int), stream);
    k_bcount<<<gPart, 256, 0, stream>>>(dstp, batom, E, NB);
    k_bscan <<<1, 256, 0, stream>>>(batom, boff, bcur, NB);
    k_part  <<<gPart, 256, 0, stream>>>(srcp, dstp, ew, bcur, bbuf, E, NB);
    k_bucket<<<NB, 256, 0, stream>>>(boff, bbuf, rp, dis, adj, N, E, NB);

    // layer 1 (x is f32, no relu)
    k_gemm<false, false><<<gGemm, 256, 0, stream>>>(x, W1, dis, (unsigned short*)Abf, N);
    k_gather<<<gGe, 256, 0, stream>>>(rp, adj, Abf, dis, b1, Bbf, N);
    // layer 2 (bf16 input, relu)
    k_gemm<true, true><<<gGemm, 256, 0, stream>>>(Bbf, W2, dis, (unsigned short*)Abf, N);
    k_gather<<<gGe, 256, 0, stream>>>(rp, adj, Abf, dis, b2, Bbf, N);
    // layer 3
    k_gemm<true, true><<<gGemm, 256, 0, stream>>>(Bbf, W3, dis, (unsigned short*)Abf, N);
    k_gather<<<gGe, 256, 0, stream>>>(rp, adj, Abf, dis, b3, Bbf, N);

    // pool + head
    k_pool<<<PBLK, 256, 0, stream>>>(Bbf, part, N);
    k_head<<<1, 1024, 0, stream>>>(part, Wh, bh, (float*)d_out, 1.0f / (float)N);
}

// Round 12
// 376.762 us; speedup vs baseline: 22.6113x; 1.0428x over previous
//
#include <hip/hip_runtime.h>

// GraphGCN forward. Round 11: edge MLP restructured — swapped-operand MFMA
// (C cols = edges), bias via rank-1 MFMA, layer-2 reduce via MFMA (zero shfl),
// dst bucket-count fused in. Round-10 structure otherwise.
// N=50000 nodes, E=1600000 edges, IN=H=128, EA=16, OUT=10.

#define HD   128
#define EAD  16
#define OUTD 10
#define PCHUNK 4096
#define PBLK 400              // pool partial blocks (8 chunks x 50 in k_head)

typedef short bf16x8 __attribute__((ext_vector_type(8)));
typedef float f32x16 __attribute__((ext_vector_type(16)));

static inline int ceil_div(long long a, long long b){ return (int)((a + b - 1) / b); }

__device__ inline unsigned f2bf(float f) {           // RNE f32 -> bf16
    unsigned u = __float_as_uint(f);
    return (u + 0x7fffu + ((u >> 16) & 1u)) >> 16;
}
__device__ inline float bf_lo(unsigned w) { return __uint_as_float(w << 16); }
__device__ inline float bf_hi(unsigned w) { return __uint_as_float(w & 0xffff0000u); }

__device__ inline unsigned short f2h(float f) {
    _Float16 h = (_Float16)f;
    return __builtin_bit_cast(unsigned short, h);
}
__device__ inline float h2f(unsigned u) {            // low 16 bits = f16
    _Float16 h = __builtin_bit_cast(_Float16, (unsigned short)(u & 0xffffu));
    return (float)h;
}
__device__ inline unsigned cvtpk(float lo, float hi) {   // 2xf32 -> packed bf16
    unsigned r;
    asm volatile("v_cvt_pk_bf16_f32 %0, %1, %2" : "=v"(r) : "v"(lo), "v"(hi));
    return r;
}
__device__ inline unsigned relu_pk(unsigned w) {     // relu on packed 2xbf16
    return w & ~(((w >> 15) & 0x10001u) * 0xFFFFu);
}

// ---------------- edge MLP via swapped MFMA + MFMA reduce --------------------
// C1_t[hid_row][edge_col] = (We1^T @ ea^T)_t + be1 (rank-1 MFMA).
// pre = sum_t mfma(We2-slice-as-A, relu(C1_t))  -> every lane reg0 = pre[edge].
// Fused: LDS histogram of dst>>8 -> batom.
__global__ __launch_bounds__(256) void k_edge_mlp(
    const float* __restrict__ edge_attr, const int* __restrict__ dst,
    const float* __restrict__ We1, const float* __restrict__ be1,
    const float* __restrict__ We2, const float* __restrict__ be2,
    float* __restrict__ ew, int* __restrict__ batom, int E, int NB)
{
    __shared__ int hist[256];
    const int tid = threadIdx.x;
    hist[tid] = 0;
    __syncthreads();

    const int lane = tid & 63;
    const int half = lane >> 5;
    const int lc   = lane & 31;
    const int wid  = blockIdx.x * 4 + (tid >> 6);
    const int nw   = gridDim.x * 4;
    const int G    = (E + 31) >> 5;

    // wave-invariant fragments
    bf16x8 bfr[4];    // A: We1^T block t -> A[row=hid (lc)][k=attr]
    bf16x8 abias[4];  // A: be1 column (k==0 only)
    bf16x8 bones;     // B: ones row (k==0 only)
    bf16x8 we2A[8];   // A: We2 16-slices, all 32 rows equal
#pragma unroll
    for (int t = 0; t < 4; ++t) {
#pragma unroll
        for (int j = 0; j < 8; ++j) {
            int k = 4 * half + (j & 3) + 8 * (j >> 2);
            bfr[t][j]   = (short)f2bf(We1[k * HD + t * 32 + lc]);
            abias[t][j] = (half == 0 && j == 0) ? (short)f2bf(be1[t * 32 + lc]) : (short)0;
        }
    }
#pragma unroll
    for (int j = 0; j < 8; ++j)
        bones[j] = (half == 0 && j == 0) ? (short)0x3F80 : (short)0;
#pragma unroll
    for (int s = 0; s < 8; ++s)
#pragma unroll
        for (int j = 0; j < 8; ++j) {
            int k = 4 * half + (j & 3) + 8 * (j >> 2);
            we2A[s][j] = (short)f2bf(We2[s * 16 + k]);
        }
    const float be2v = be2[0];

    for (int g = wid; g < G; g += nw) {
        int eb = g << 5;
        int edge = eb + lc;
        int eload = edge < E ? edge : E - 1;
        bool owner = (half == 0) && (edge < E);
        if (owner) atomicAdd(&hist[((unsigned)dst[edge]) >> 8], 1);

        // B fragment: ea^T — lane col = edge, k = 4*half + {0..3, 8..11}
        const float4* rowp = reinterpret_cast<const float4*>(edge_attr + (size_t)eload * EAD);
        float4 a0 = rowp[half];
        float4 a1 = rowp[2 + half];
        union { uint2 u[2]; bf16x8 v; } af;
        af.u[0] = make_uint2(cvtpk(a0.x, a0.y), cvtpk(a0.z, a0.w));
        af.u[1] = make_uint2(cvtpk(a1.x, a1.y), cvtpk(a1.z, a1.w));

        f32x16 pre;
#pragma unroll
        for (int i = 0; i < 16; ++i) pre[i] = 0.f;
#pragma unroll
        for (int t = 0; t < 4; ++t) {
            f32x16 acc;
#pragma unroll
            for (int i = 0; i < 16; ++i) acc[i] = 0.f;
            acc = __builtin_amdgcn_mfma_f32_32x32x16_bf16(abias[t], bones, acc, 0, 0, 0);
            acc = __builtin_amdgcn_mfma_f32_32x32x16_bf16(bfr[t], af.v, acc, 0, 0, 0);
            // relu + pack: C regs r=0..7 -> B-frag rows 0..15; r=8..15 -> rows 16..31
            union { uint2 u[2]; bf16x8 v; } plo, phi;
            plo.u[0] = make_uint2(cvtpk(fmaxf(acc[0], 0.f),  fmaxf(acc[1], 0.f)),
                                  cvtpk(fmaxf(acc[2], 0.f),  fmaxf(acc[3], 0.f)));
            plo.u[1] = make_uint2(cvtpk(fmaxf(acc[4], 0.f),  fmaxf(acc[5], 0.f)),
                                  cvtpk(fmaxf(acc[6], 0.f),  fmaxf(acc[7], 0.f)));
            phi.u[0] = make_uint2(cvtpk(fmaxf(acc[8], 0.f),  fmaxf(acc[9], 0.f)),
                                  cvtpk(fmaxf(acc[10], 0.f), fmaxf(acc[11], 0.f)));
            phi.u[1] = make_uint2(cvtpk(fmaxf(acc[12], 0.f), fmaxf(acc[13], 0.f)),
                                  cvtpk(fmaxf(acc[14], 0.f), fmaxf(acc[15], 0.f)));
            pre = __builtin_amdgcn_mfma_f32_32x32x16_bf16(we2A[2*t],     plo.v, pre, 0, 0, 0);
            pre = __builtin_amdgcn_mfma_f32_32x32x16_bf16(we2A[2*t + 1], phi.v, pre, 0, 0, 0);
        }
        // all C2 rows identical -> every lane's reg0 = pre[edge = eb + lc]
        float v  = pre[0] + be2v;
        float sp = fmaxf(v, 0.f) + log1pf(expf(-fabsf(v)));
        if (owner) ew[edge] = sp;
    }
    __syncthreads();
    if (tid < NB && hist[tid]) atomicAdd(&batom[tid], hist[tid]);
}

// ---------------- scan bucket counts -> boff (exclusive), bcur copy -----------
__global__ __launch_bounds__(256) void k_bscan(
    const int* __restrict__ batom, int* __restrict__ boff,
    int* __restrict__ bcur, int NB)
{
    __shared__ int sh[256];
    int t = threadIdx.x;
    int v = (t < NB) ? batom[t] : 0;
    sh[t] = v;
    __syncthreads();
    for (int off = 1; off < 256; off <<= 1) {
        int add = (t >= off) ? sh[t - off] : 0;
        __syncthreads();
        sh[t] += add;
        __syncthreads();
    }
    if (t < NB) { boff[t] = sh[t] - v; bcur[t] = sh[t] - v; }
    if (t == NB - 1) boff[NB] = sh[t];
}

// ---------------- partition edges into coarse buckets ----------------
__global__ __launch_bounds__(256) void k_part(
    const int* __restrict__ src, const int* __restrict__ dst,
    const float* __restrict__ ew, int* __restrict__ bcur,
    uint2* __restrict__ bbuf, int E, int NB)
{
    __shared__ int hist[256];
    __shared__ int base[256];
    __shared__ int cur[256];
    int t = threadIdx.x;
    hist[t] = 0; cur[t] = 0;
    __syncthreads();
    int eb = blockIdx.x * PCHUNK;
#pragma unroll
    for (int k = 0; k < PCHUNK / 256; ++k) {
        int e = eb + k * 256 + t;
        if (e < E) atomicAdd(&hist[dst[e] >> 8], 1);
    }
    __syncthreads();
    if (t < NB && hist[t]) base[t] = atomicAdd(&bcur[t], hist[t]);
    __syncthreads();
#pragma unroll
    for (int k = 0; k < PCHUNK / 256; ++k) {
        int e = eb + k * 256 + t;
        if (e >= E) continue;
        int d = dst[e];
        int bkt = d >> 8;
        int pos = base[bkt] + atomicAdd(&cur[bkt], 1);
        bbuf[pos] = make_uint2(((unsigned)src[e] << 16) | f2h(ew[e]),
                               (unsigned)(d & 255));
    }
}

// ---------------- per-bucket counting sort: rp, dis, adj ----------------
__global__ __launch_bounds__(256) void k_bucket(
    const int* __restrict__ boff, const uint2* __restrict__ bbuf,
    int* __restrict__ rp, float* __restrict__ dis,
    unsigned* __restrict__ adj, int N, int E, int NB)
{
    __shared__ int   hcnt[256];
    __shared__ int   hexc[256];
    __shared__ int   cur[256];
    __shared__ float degs[256];
    int b = blockIdx.x;
    int t = threadIdx.x;
    hcnt[t] = 0; cur[t] = 0; degs[t] = 0.f;
    __syncthreads();
    int beg = boff[b], end = boff[b + 1];
    for (int i = beg + t; i < end; i += 256) {
        uint2 ent = bbuf[i];
        int dl = (int)ent.y;
        atomicAdd(&hcnt[dl], 1);
        atomicAdd(&degs[dl], h2f(ent.x));
    }
    __syncthreads();
    {
        int v = hcnt[t];
        hexc[t] = v;
        __syncthreads();
        for (int off = 1; off < 256; off <<= 1) {
            int add = (t >= off) ? hexc[t - off] : 0;
            __syncthreads();
            hexc[t] += add;
            __syncthreads();
        }
        hexc[t] -= v;
    }
    int n = (b << 8) + t;
    if (n < N) {
        rp[n]  = beg + hexc[t];
        dis[n] = rsqrtf(fmaxf(1.0f + degs[t], 1e-12f));
    }
    if (b == NB - 1 && t == 0) rp[N] = E;
    __syncthreads();
    for (int i = beg + t; i < end; i += 256) {
        uint2 ent = bbuf[i];
        int dl = (int)ent.y;
        int pos = beg + hexc[dl] + atomicAdd(&cur[dl], 1);
        adj[pos] = ent.x;
    }
}

// ------- MFMA GEMM: Ybf[row] = bf16( dis[row] * (relu?)X[row] @ W ) ----------
template <bool BF16IN, bool RELU>
__global__ __launch_bounds__(256) void k_gemm(
    const void* __restrict__ Xv, const float* __restrict__ W,
    const float* __restrict__ dis, unsigned short* __restrict__ Ybf, int N)
{
    __shared__ unsigned short Wt[128][132];
    int t = threadIdx.x;
#pragma unroll
    for (int i = 0; i < 64; ++i) {
        int e = i * 256 + t;
        int k = e >> 7, n = e & 127;
        Wt[n][k] = (unsigned short)f2bf(W[e]);
    }
    __syncthreads();

    const int lane = t & 63;
    const int half = lane >> 5;
    const int lc   = lane & 31;
    const int wid  = blockIdx.x * 4 + (t >> 6);
    const int nw   = gridDim.x * 4;
    const int T    = (N + 31) >> 5;

    for (int tile = wid; tile < T; tile += nw) {
        int rbase = tile << 5;
        int arow  = rbase + lc; if (arow >= N) arow = N - 1;

        f32x16 acc[4];
#pragma unroll
        for (int tb = 0; tb < 4; ++tb)
#pragma unroll
            for (int i = 0; i < 16; ++i) acc[tb][i] = 0.f;

#pragma unroll
        for (int kk = 0; kk < 8; ++kk) {
            union { uint2 u[2]; bf16x8 v; } af;
            if (BF16IN) {
                const unsigned short* Xb = (const unsigned short*)Xv;
                const unsigned short* rp = Xb + (size_t)arow * HD + kk * 16 + 4 * half;
                uint2 lo = *reinterpret_cast<const uint2*>(rp);
                uint2 hi = *reinterpret_cast<const uint2*>(rp + 8);
                if (RELU) {
                    lo.x = relu_pk(lo.x); lo.y = relu_pk(lo.y);
                    hi.x = relu_pk(hi.x); hi.y = relu_pk(hi.y);
                }
                af.u[0] = lo; af.u[1] = hi;
            } else {
                const float* Xf = (const float*)Xv;
                const float* rp = Xf + (size_t)arow * HD + kk * 16 + 4 * half;
                float4 lo = *reinterpret_cast<const float4*>(rp);
                float4 hi = *reinterpret_cast<const float4*>(rp + 8);
                af.u[0] = make_uint2(cvtpk(lo.x, lo.y), cvtpk(lo.z, lo.w));
                af.u[1] = make_uint2(cvtpk(hi.x, hi.y), cvtpk(hi.z, hi.w));
            }
#pragma unroll
            for (int tb = 0; tb < 4; ++tb) {
                const unsigned short* wp = &Wt[tb * 32 + lc][kk * 16 + 4 * half];
                union { uint2 u[2]; bf16x8 v; } bf_;
                bf_.u[0] = *reinterpret_cast<const uint2*>(wp);
                bf_.u[1] = *reinterpret_cast<const uint2*>(wp + 8);
                acc[tb] = __builtin_amdgcn_mfma_f32_32x32x16_bf16(af.v, bf_.v, acc[tb], 0, 0, 0);
            }
        }

        float disv = dis[arow];
#pragma unroll
        for (int r = 0; r < 16; ++r) {
            int rofs = (r & 3) + 8 * (r >> 2) + 4 * half;
            int grow = rbase + rofs;
            float d = __shfl(disv, rofs, 32);
            if (grow < N) {
#pragma unroll
                for (int tb = 0; tb < 4; ++tb)
                    Ybf[(size_t)grow * HD + tb * 32 + lc] =
                        (unsigned short)f2bf(acc[tb][r] * d);
            }
        }
    }
}

// --- gather: out[n] = bf16( b + dis[n] * (linbf[n] + sum ew*linbf[src]) ) -----
__global__ __launch_bounds__(256) void k_gather(
    const int* __restrict__ rp, const unsigned* __restrict__ adj,
    const unsigned* __restrict__ linbf, const float* __restrict__ dis,
    const float* __restrict__ b, unsigned short* __restrict__ out, int N)
{
    int n = blockIdx.x * 8 + (threadIdx.x >> 5);
    if (n >= N) return;
    int lane = threadIdx.x & 31;
    uint2 sw = *reinterpret_cast<const uint2*>(linbf + (size_t)n * (HD/2) + lane * 2);
    float4 acc;
    acc.x = bf_lo(sw.x); acc.y = bf_hi(sw.x);
    acc.z = bf_lo(sw.y); acc.w = bf_hi(sw.y);
    int beg = rp[n], end = rp[n + 1];
    for (int i0 = beg; i0 < end; i0 += 32) {
        int m = end - i0; if (m > 32) m = 32;
        unsigned a = 0;
        if (lane < m) a = adj[i0 + lane];
        int j = 0;
        for (; j + 8 <= m; j += 8) {
            unsigned ee[8]; uint2 vv[8];
#pragma unroll
            for (int q = 0; q < 8; ++q) ee[q] = __shfl(a, j + q, 32);
#pragma unroll
            for (int q = 0; q < 8; ++q)
                vv[q] = *reinterpret_cast<const uint2*>(linbf + (size_t)(ee[q] >> 16) * (HD/2) + lane * 2);
#pragma unroll
            for (int q = 0; q < 8; ++q) {
                float wq = h2f(ee[q]);
                acc.x = fmaf(wq, bf_lo(vv[q].x), acc.x);
                acc.y = fmaf(wq, bf_hi(vv[q].x), acc.y);
                acc.z = fmaf(wq, bf_lo(vv[q].y), acc.z);
                acc.w = fmaf(wq, bf_hi(vv[q].y), acc.w);
            }
        }
        for (; j < m; ++j) {
            unsigned e0 = __shfl(a, j, 32);
            uint2 v0 = *reinterpret_cast<const uint2*>(linbf + (size_t)(e0 >> 16) * (HD/2) + lane * 2);
            float w0 = h2f(e0);
            acc.x = fmaf(w0, bf_lo(v0.x), acc.x);
            acc.y = fmaf(w0, bf_hi(v0.x), acc.y);
            acc.z = fmaf(w0, bf_lo(v0.y), acc.z);
            acc.w = fmaf(w0, bf_hi(v0.y), acc.w);
        }
    }
    float dn = dis[n];
    float4 bv = reinterpret_cast<const float4*>(b)[lane];
    unsigned w0 = cvtpk(fmaf(dn, acc.x, bv.x), fmaf(dn, acc.y, bv.y));
    unsigned w1 = cvtpk(fmaf(dn, acc.z, bv.z), fmaf(dn, acc.w, bv.w));
    *reinterpret_cast<uint2*>(out + (size_t)n * HD + lane * 4) = make_uint2(w0, w1);
}

// ---------------- pool partials: 16 rows x 16 chunks per block-iter ----------
__global__ __launch_bounds__(256) void k_pool(
    const unsigned short* __restrict__ h, float* __restrict__ part, int N)
{
    __shared__ float sm[16][128];
    int t  = threadIdx.x;
    int cg = t & 15;              // uint4 chunk (8 bf16) within row
    int rs = t >> 4;              // row slot 0..15
    float acc[8];
#pragma unroll
    for (int i = 0; i < 8; ++i) acc[i] = 0.f;
    for (int r = blockIdx.x * 16 + rs; r < N; r += gridDim.x * 16) {
        uint4 v = *reinterpret_cast<const uint4*>(h + (size_t)r * HD + cg * 8);
        acc[0] += fmaxf(bf_lo(v.x), 0.f);
        acc[1] += fmaxf(bf_hi(v.x), 0.f);
        acc[2] += fmaxf(bf_lo(v.y), 0.f);
        acc[3] += fmaxf(bf_hi(v.y), 0.f);
        acc[4] += fmaxf(bf_lo(v.z), 0.f);
        acc[5] += fmaxf(bf_hi(v.z), 0.f);
        acc[6] += fmaxf(bf_lo(v.w), 0.f);
        acc[7] += fmaxf(bf_hi(v.w), 0.f);
    }
#pragma unroll
    for (int i = 0; i < 8; ++i) sm[rs][cg * 8 + i] = acc[i];
    __syncthreads();
    if (t < 128) {
        float s = 0.f;
#pragma unroll
        for (int k = 0; k < 16; ++k) s += sm[k][t];
        part[blockIdx.x * HD + t] = s;
    }
}

// ---- head: parallel partial-sum (8 chunks x 50) + wave-parallel GEMV --------
__global__ __launch_bounds__(1024) void k_head(
    const float* __restrict__ part, const float* __restrict__ Wh,
    const float* __restrict__ bh, float* __restrict__ out, float invN)
{
    __shared__ float smc[8][128];
    __shared__ float col[HD];
    int t = threadIdx.x;
    {
        int c  = t & 127;             // column
        int ch = t >> 7;              // chunk 0..7 (50 partials each)
        float s0 = 0.f, s1 = 0.f;
        int k0 = ch * 50;
#pragma unroll
        for (int k = 0; k < 50; k += 2) {
            s0 += part[(k0 + k)     * HD + c];
            s1 += part[(k0 + k + 1) * HD + c];
        }
        smc[ch][c] = s0 + s1;
    }
    __syncthreads();
    if (t < 128) {
        float s = 0.f;
#pragma unroll
        for (int k = 0; k < 8; ++k) s += smc[k][t];
        col[t] = s * invN;
    }
    __syncthreads();
    {
        int o = t >> 6;               // output index (only o<OUTD active)
        int l = t & 63;
        if (o < OUTD) {
            float acc = col[l] * Wh[l * OUTD + o]
                      + col[l + 64] * Wh[(l + 64) * OUTD + o];
#pragma unroll
            for (int off = 1; off < 64; off <<= 1)
                acc += __shfl_xor(acc, off, 64);
            if (l == 0) out[o] = acc + bh[o];
        }
    }
}

extern "C" void kernel_launch(void* const* d_in, const int* in_sizes, int n_in,
                              void* d_out, int out_size, void* d_ws, size_t ws_size,
                              hipStream_t stream)
{
    const float* x         = (const float*)d_in[0];
    const int*   ei        = (const int*)  d_in[1];
    const float* edge_attr = (const float*)d_in[2];
    const float* We1       = (const float*)d_in[3];
    const float* be1       = (const float*)d_in[4];
    const float* We2       = (const float*)d_in[5];
    const float* be2       = (const float*)d_in[6];
    const float* W1        = (const float*)d_in[7];
    const float* b1        = (const float*)d_in[8];
    const float* W2        = (const float*)d_in[9];
    const float* b2        = (const float*)d_in[10];
    const float* W3        = (const float*)d_in[11];
    const float* b3        = (const float*)d_in[12];
    const float* Wh        = (const float*)d_in[13];
    const float* bh        = (const float*)d_in[14];

    const int N = in_sizes[0] / HD;
    const int E = in_sizes[2] / EAD;
    const int NB = (N + 255) >> 8;
    const int* srcp = ei;
    const int* dstp = ei + E;

    // workspace partition
    char* w = (char*)d_ws;
    float*          ew   = (float*)w;          w += (size_t)E * sizeof(float);
    float*          dis  = (float*)w;          w += (size_t)N * sizeof(float);
    unsigned short* Bbf  = (unsigned short*)w; w += (size_t)N * HD * sizeof(unsigned short);
    unsigned*       Abf  = (unsigned*)w;       w += (size_t)N * (HD/2) * sizeof(unsigned);
    float*          part = (float*)w;          w += (size_t)PBLK * HD * sizeof(float);
    int*            rp   = (int*)w;            w += (size_t)(N + 2) * sizeof(int);
    int*            batom= (int*)w;            w += 256 * sizeof(int);
    int*            boff = (int*)w;            w += 260 * sizeof(int);
    int*            bcur = (int*)w;            w += 256 * sizeof(int);
    w = (char*)(((uintptr_t)w + 15) & ~(uintptr_t)15);
    uint2*          bbuf = (uint2*)w;          w += (size_t)E * sizeof(uint2);
    unsigned*       adj  = (unsigned*)w;       w += (size_t)E * sizeof(unsigned);

    const int gGe   = ceil_div(N, 8);
    const int gPart = ceil_div(E, PCHUNK);
    const int gGemm = 196;

    // batom = 0, then edge MLP (swapped MFMA, fused bucket count)
    hipMemsetAsync(batom, 0, 256 * sizeof(int), stream);
    k_edge_mlp<<<1024, 256, 0, stream>>>(edge_attr, dstp, We1, be1, We2, be2,
                                         ew, batom, E, NB);

    // CSR build: scan -> partition -> per-bucket sort
    k_bscan <<<1, 256, 0, stream>>>(batom, boff, bcur, NB);
    k_part  <<<gPart, 256, 0, stream>>>(srcp, dstp, ew, bcur, bbuf, E, NB);
    k_bucket<<<NB, 256, 0, stream>>>(boff, bbuf, rp, dis, adj, N, E, NB);

    // layer 1 (x is f32, no relu)
    k_gemm<false, false><<<gGemm, 256, 0, stream>>>(x, W1, dis, (unsigned short*)Abf, N);
    k_gather<<<gGe, 256, 0, stream>>>(rp, adj, Abf, dis, b1, Bbf, N);
    // layer 2 (bf16 input, relu)
    k_gemm<true, true><<<gGemm, 256, 0, stream>>>(Bbf, W2, dis, (unsigned short*)Abf, N);
    k_gather<<<gGe, 256, 0, stream>>>(rp, adj, Abf, dis, b2, Bbf, N);
    // layer 3
    k_gemm<true, true><<<gGemm, 256, 0, stream>>>(Bbf, W3, dis, (unsigned short*)Abf, N);
    k_gather<<<gGe, 256, 0, stream>>>(rp, adj, Abf, dis, b3, Bbf, N);

    // pool + head
    k_pool<<<PBLK, 256, 0, stream>>>(Bbf, part, N);
    k_head<<<1, 1024, 0, stream>>>(part, Wh, bh, (float*)d_out, 1.0f / (float)N);
}